// Round 7
// baseline (1246.611 us; speedup 1.0000x reference)
//
#include <hip/hip_runtime.h>
#include <math.h>

// SelfModifyingBlock (TTT inner loop) — round 11:
//  ROOT-CAUSE FIX of r9/r10 regressions: stride 42 u16 = 84B broke 16B alignment
//  of every LDS uint4 access (b128 ops split to b32: DS ops x4, VALUBusy 51->73%,
//  76->163us). Stride restored to 40 (80B, 16B-aligned, bank period 8).
//  NEW: all 3 k_gelu_fwd passes eliminated (~35-45us + 103MB each):
//   - Y-GEMM stages X from h1 with gn+gelu_fast on the fly (XGN=1); 'a' never stored
//   - dW2-wgrad stages Q from h1 with QGN=1
//   - final forward: EP_OUT stages from h1 with XGN=1 (also replaces k_out)
//  gelu_fast err 1e-3 < bf16 staging quantum 8e-3 -> bit-level impact ~1 ulp of a.

#define BB    16
#define CC    256
#define HWW   3136
#define NTOT  (BB*HWW)        // 50176
#define HIDD  512
#define NGRP  8
#define GMSZ  (64*HWW)        // 200704 elems per (b,group)
#define C4    64
#define LRATE 0.01f
#define SKW   32
#define CHUNK (NTOT/SKW)      // 1568
#define NV8   (HWW/8)         // 392 uint4 chunks per channel-row
#define FSTR  132             // fp32 LDS staging row stride (16B-aligned)

#define EP_STORE    0
#define EP_ADDFEAT  1
#define EP_T1H      2
#define EP_DYREC    3
#define EP_DT1      4
#define EP_DYFIN    5
#define EP_H1STAT   6
#define EP_YADDSTAT 7
#define EP_GNB1     8
#define EP_OUT      9

typedef unsigned short u16;
typedef __attribute__((ext_vector_type(8))) short bf16x8;
typedef __attribute__((ext_vector_type(4))) float f32x4;

__device__ __forceinline__ float bf2f(u16 u){
  return __uint_as_float(((unsigned)u)<<16);
}
__device__ __forceinline__ u16 f2bf(float f){
  unsigned u = __float_as_uint(f);
  u += 0x7FFFu + ((u>>16)&1u);
  return (u16)(u>>16);
}
// exact (gate only — tiny)
__device__ __forceinline__ float gelu_f(float x){
  return 0.5f*x*(1.0f+erff(x*0.70710678118654752f));
}
__device__ __forceinline__ float rcp_f(float x){ return __builtin_amdgcn_rcpf(x); }
// fast tanh-approx (max abs err ~1e-3 < bf16 quantum of O(1) values)
__device__ __forceinline__ float gelu_fast(float x){
  float x2 = x*x;
  float u = 0.7978845608f*x*fmaf(0.044715f, x2, 1.0f);
  float t = 1.0f - 2.0f*rcp_f(__expf(2.0f*u)+1.0f);
  return 0.5f*x*(1.0f+t);
}
__device__ __forceinline__ float gelu_g_fast(float x){
  float x2 = x*x;
  float u = 0.7978845608f*x*fmaf(0.044715f, x2, 1.0f);
  float t = 1.0f - 2.0f*rcp_f(__expf(2.0f*u)+1.0f);
  float du = 0.7978845608f*fmaf(0.134145f, x2, 1.0f);
  return fmaf(0.5f*x*(1.0f-t*t), du, 0.5f*(1.0f+t));
}
__device__ __forceinline__ float blk_sum(float v, float* sm){
  #pragma unroll
  for (int o=32;o>0;o>>=1) v += __shfl_down(v,o);
  if ((threadIdx.x & 63)==0) sm[threadIdx.x>>6] = v;
  __syncthreads();
  float r = sm[0]+sm[1]+sm[2]+sm[3];
  __syncthreads();
  return r;
}
__device__ __forceinline__ uint4 pack8(const ushort* e){
  uint4 v;
  v.x = (unsigned)e[0] | ((unsigned)e[1]<<16);
  v.y = (unsigned)e[2] | ((unsigned)e[3]<<16);
  v.z = (unsigned)e[4] | ((unsigned)e[5]<<16);
  v.w = (unsigned)e[6] | ((unsigned)e[7]<<16);
  return v;
}
__device__ __forceinline__ void up8(uint4 v, float* f){
  f[0]=bf2f((u16)(v.x&0xFFFFu)); f[1]=bf2f((u16)(v.x>>16));
  f[2]=bf2f((u16)(v.y&0xFFFFu)); f[3]=bf2f((u16)(v.y>>16));
  f[4]=bf2f((u16)(v.z&0xFFFFu)); f[5]=bf2f((u16)(v.z>>16));
  f[6]=bf2f((u16)(v.w&0xFFFFu)); f[7]=bf2f((u16)(v.w>>16));
}
__device__ __forceinline__ uint4 pk8(const float* f){
  uint4 v;
  v.x=(unsigned)f2bf(f[0])|((unsigned)f2bf(f[1])<<16);
  v.y=(unsigned)f2bf(f[2])|((unsigned)f2bf(f[3])<<16);
  v.z=(unsigned)f2bf(f[4])|((unsigned)f2bf(f[5])<<16);
  v.w=(unsigned)f2bf(f[6])|((unsigned)f2bf(f[7])<<16);
  return v;
}

// ---------- probes ----------
__global__ void k_detect_dtype(const u16* __restrict__ xs, int* flag){
  if (threadIdx.x || blockIdx.x) return;
  int plaus = 0;
  for (int i=0;i<256;i+=2){
    float f = bf2f(xs[i]);
    float a = fabsf(f);
    if (isfinite(f) && a < 32.0f && a > 1e-5f) plaus++;
  }
  *flag = (plaus >= 64) ? 1 : 0;   // 1 = bf16 inputs, 0 = fp32 inputs
}
__global__ void k_detect_mask(const unsigned char* __restrict__ m, int* flag){
  if (threadIdx.x || blockIdx.x) return;
  unsigned char mx=0; int nz0=0,nz1=0,nz2=0,nz3=0;
  for (int i=0;i<256;i++){
    unsigned char v=m[i]; if (v>mx) mx=v;
    if (v){ int r=i&3; if(r==0)nz0=1; else if(r==1)nz1=1; else if(r==2)nz2=1; else nz3=1; }
  }
  int f;
  if (mx<=1) f = (nz1|nz2|nz3) ? 0 : 1;
  else       f = (!nz0 && !nz1) ? 3 : 2;
  *flag=f;
}
__global__ void k_report(u16* out, float v){
  if (threadIdx.x==0 && blockIdx.x==0) out[0] = f2bf(v);
}

__global__ void k_cvt(const void* __restrict__ src, float* __restrict__ dst, int n,
                      const int* __restrict__ dtf){
  int i = blockIdx.x*256 + threadIdx.x;
  if (i>=n) return;
  if (*dtf) dst[i] = bf2f(((const u16*)src)[i]);
  else      dst[i] = ((const float*)src)[i];
}
__global__ void k_wcvt(const float* __restrict__ src, u16* __restrict__ d,
                       u16* __restrict__ dT, int R, int Cc){
  int i = blockIdx.x*256+threadIdx.x;
  if (i >= R*Cc) return;
  int r = i/Cc, c = i - r*Cc;
  u16 v = f2bf(src[i]);
  d[i] = v;
  if (dT) dT[(size_t)c*R + r] = v;
}

__global__ void k_expand(const unsigned char* __restrict__ mraw, const int* __restrict__ flag,
                         float* __restrict__ mf, float* __restrict__ zc){
  __shared__ float sm[4];
  int i = blockIdx.x*256 + threadIdx.x;     // grid 392 = 2*NTOT/256
  int f = *flag;
  float v;
  if (f==1)      v = (((const int*)mraw)[i] != 0) ? 1.f : 0.f;
  else if (f==0) v = (mraw[i] != 0) ? 1.f : 0.f;
  else if (f==2) v = (((const u16*)mraw)[i] != 0) ? 1.f : 0.f;
  else           v = (((const float*)mraw)[i] != 0.f) ? 1.f : 0.f;
  mf[i] = v;
  float S = blk_sum(1.f - v, sm);
  if (threadIdx.x==0) atomicAdd(&zc[blockIdx.x/196], S);
}

// ---------- MFMA GEMM: Out[m,n] = sum_k A[m,k]*X[k,n] ----------
// 64-row m-blocks, 128-col n-blocks, LDS stride 40 u16 (80B, 16B-aligned).
// XGN=1: apply gn+gelu_fast during X staging (X = h1; xmu = mu w/ rsig@+128,
// xpg = pg w/ pb@+512). Unified vectorized epilogue via LDS fp32 round-trip.
template<int MASKX,int EPI,int XDYN,int E0DYN,int XGN>
__global__ __launch_bounds__(256) void k_gemm_mfma(
    const u16* __restrict__ A, const void* __restrict__ Xv, u16* __restrict__ Out,
    int K, const int* __restrict__ xdt, const float* __restrict__ mf,
    const void* __restrict__ e0, const float* __restrict__ e1,
    const float* __restrict__ e2, u16* __restrict__ o2, float* __restrict__ o3,
    const float* __restrict__ xmu, const float* __restrict__ xpg)
{
  __shared__ __align__(16) u16 Ws[64*40];
  __shared__ __align__(16) u16 Xs[128*40];
  const int t = threadIdx.x;
  const int w = t >> 6, lane = t & 63;
  const int col = lane & 15, quad = lane >> 4;
  const int M = (int)gridDim.y << 6;
  const int m0 = blockIdx.y << 6, n0 = blockIdx.x << 7;
  const int isbx = XDYN ? *xdt : 1;
  const u16*   Xb = (const u16*)Xv;
  const float* Xf = (const float*)Xv;
  const int wrow = t >> 2, wkq = (t & 3) * 8;
  const int xn   = 2*(t & 63);
  const int xq   = t >> 6;
  const int gn0  = n0 + xn;
  const int xb_  = gn0 / HWW;
  const int xs_  = gn0 - xb_*HWW;

  f32x4 acc[4][2];
  #pragma unroll
  for (int i=0;i<4;i++){
    #pragma unroll
    for (int j=0;j<2;j++) acc[i][j] = (f32x4)(0.0f);
  }

  for (int k0=0; k0<K; k0+=32){
    {
      uint4 v = *(const uint4*)(A + (size_t)(m0+wrow)*K + k0 + wkq);
      *(uint4*)(Ws + wrow*40 + wkq) = v;
    }
    {
      ushort e[16];
      size_t base = ((size_t)xb_*K + k0 + xq*8)*HWW + xs_;
      if (isbx){
        #pragma unroll
        for (int j=0;j<8;j++){
          unsigned v = *(const unsigned*)(Xb + base + (size_t)j*HWW);
          if (XGN){
            const int o  = k0 + xq*8 + j;
            const int bg = xb_*NGRP + (o>>6);
            const float mu_ = xmu[bg], rs_ = xmu[128+bg];
            const float ga_ = xpg[o],  be_ = xpg[512+o];
            float f0 = bf2f((u16)(v & 0xFFFFu));
            float f1 = bf2f((u16)(v >> 16));
            f0 = gelu_fast(fmaf((f0-mu_)*rs_, ga_, be_));
            f1 = gelu_fast(fmaf((f1-mu_)*rs_, ga_, be_));
            e[j]   = f2bf(f0);
            e[8+j] = f2bf(f1);
          } else {
            e[j]   = (ushort)(v & 0xFFFFu);
            e[8+j] = (ushort)(v >> 16);
          }
        }
      } else {
        #pragma unroll
        for (int j=0;j<8;j++){
          float2 f = *(const float2*)(Xf + base + (size_t)j*HWW);
          e[j]   = f2bf(f.x);
          e[8+j] = f2bf(f.y);
        }
      }
      if (MASKX){
        if (mf[gn0]   == 0.f){
          #pragma unroll
          for (int j=0;j<8;j++) e[j] = 0;
        }
        if (mf[gn0+1] == 0.f){
          #pragma unroll
          for (int j=0;j<8;j++) e[8+j] = 0;
        }
      }
      *(uint4*)(Xs + xn*40     + xq*8) = pack8(e);
      *(uint4*)(Xs + (xn+1)*40 + xq*8) = pack8(e+8);
    }
    __syncthreads();
    bf16x8 af[4], bfr[2];
    #pragma unroll
    for (int mi=0;mi<4;mi++)
      af[mi] = *(const bf16x8*)(Ws + (mi*16+col)*40 + quad*8);
    #pragma unroll
    for (int nj=0;nj<2;nj++)
      bfr[nj] = *(const bf16x8*)(Xs + (w*32+nj*16+col)*40 + quad*8);
    #pragma unroll
    for (int mi=0;mi<4;mi++){
      #pragma unroll
      for (int nj=0;nj<2;nj++)
        acc[mi][nj] = __builtin_amdgcn_mfma_f32_16x16x32_bf16(af[mi], bfr[nj], acc[mi][nj], 0,0,0);
    }
    __syncthreads();
  }
  // ---- unified vectorized epilogue (Ws -> sred scratch, Xs -> fp32 staging) ----
  const int isb0 = E0DYN ? *xdt : 1;
  float* fst  = (float*)Xs;            // 16 x FSTR fp32 = 8448B <= 10240B
  float* sred = (float*)Ws;            // reduction scratch (<= 528B)
  const int row16 = t >> 4;            // 0..15
  const int cb    = (t & 15) * 8;      // 0..120
  const int nb8   = n0 + cb;
  const int b8    = nb8 / HWW;         // all 8 cols same b (HWW%8==0, cb 8-aligned)
  const int sb8   = nb8 - b8*HWW;
  const int bA    = n0 / HWW, bB = (n0+127)/HWW;
  const int g     = m0 >> 6;

  if (EPI==EP_H1STAT){ if (t<4) sred[t]=0.f; }
  if (EPI==EP_YADDSTAT){ for (int i=t;i<128;i+=256) sred[i]=0.f; }
  if (EPI==EP_GNB1){ for (int i=t;i<132;i+=256) sred[i]=0.f; }
  if (EPI==EP_H1STAT||EPI==EP_YADDSTAT||EPI==EP_GNB1) __syncthreads();

  float dscale=0.f, gmul=0.f, muT=0.f, rT=0.f;
  if (EPI==EP_DYREC) dscale = 2.0f / (e1[0]*(float)CC + 1e-8f);
  if (EPI==EP_OUT)   gmul = e2[0]*e1[b8];
  if (EPI==EP_GNB1){ muT = e1[b8*NGRP+g]; rT = e1[128+b8*NGRP+g]; }

  #pragma unroll
  for (int mi=0;mi<4;mi++){
    #pragma unroll
    for (int nj=0;nj<2;nj++){
      #pragma unroll
      for (int r=0;r<4;r++)
        fst[(quad*4+r)*FSTR + w*32 + nj*16 + col] = acc[mi][nj][r];
    }
    __syncthreads();
    const int m = m0 + mi*16 + row16;
    const size_t oidx = ((size_t)b8*M + m)*HWW + sb8;
    float v[8];
    {
      const float* frow = fst + row16*FSTR + cb;
      float4 p0 = *(const float4*)frow;
      float4 p1 = *(const float4*)(frow+4);
      v[0]=p0.x; v[1]=p0.y; v[2]=p0.z; v[3]=p0.w;
      v[4]=p1.x; v[5]=p1.y; v[6]=p1.z; v[7]=p1.w;
    }

    if (EPI==EP_STORE){
      *(uint4*)(Out+oidx) = pk8(v);
    }
    else if (EPI==EP_ADDFEAT){
      float xv[8];
      if (isb0) up8(*(const uint4*)((const u16*)e0+oidx), xv);
      else {
        float4 a0 = *(const float4*)((const float*)e0+oidx);
        float4 a1 = *(const float4*)((const float*)e0+oidx+4);
        xv[0]=a0.x; xv[1]=a0.y; xv[2]=a0.z; xv[3]=a0.w;
        xv[4]=a1.x; xv[5]=a1.y; xv[6]=a1.z; xv[7]=a1.w;
      }
      #pragma unroll
      for (int j=0;j<8;j++) v[j] += xv[j];
      *(uint4*)(Out+oidx) = pk8(v);
    }
    else if (EPI==EP_T1H){
      *(uint4*)(Out+oidx) = pk8(v);
      float gv[8];
      #pragma unroll
      for (int j=0;j<8;j++) gv[j] = gelu_fast(v[j]);
      *(uint4*)(o2+oidx) = pk8(gv);
    }
    else if (EPI==EP_DYREC){
      float yv[8], mfv[8];
      up8(*(const uint4*)((const u16*)e0+oidx), yv);
      float4 f0 = *(const float4*)(mf+nb8);
      float4 f1 = *(const float4*)(mf+nb8+4);
      mfv[0]=f0.x; mfv[1]=f0.y; mfv[2]=f0.z; mfv[3]=f0.w;
      mfv[4]=f1.x; mfv[5]=f1.y; mfv[6]=f1.z; mfv[7]=f1.w;
      #pragma unroll
      for (int j=0;j<8;j++) v[j] = (v[j]-yv[j])*(1.0f-mfv[j])*dscale;
      *(uint4*)(Out+oidx) = pk8(v);
    }
    else if (EPI==EP_DT1){
      float tv[8];
      up8(*(const uint4*)((const u16*)e0+oidx), tv);
      #pragma unroll
      for (int j=0;j<8;j++) v[j] = v[j]*gelu_g_fast(tv[j]);
      *(uint4*)(Out+oidx) = pk8(v);
    }
    else if (EPI==EP_DYFIN){
      float yv[8], dv[8], mfv[8];
      up8(*(const uint4*)((const u16*)e0+oidx), yv);
      up8(*(const uint4*)(Out+oidx), dv);
      float4 f0 = *(const float4*)(mf+nb8);
      float4 f1 = *(const float4*)(mf+nb8+4);
      mfv[0]=f0.x; mfv[1]=f0.y; mfv[2]=f0.z; mfv[3]=f0.w;
      mfv[4]=f1.x; mfv[5]=f1.y; mfv[6]=f1.z; mfv[7]=f1.w;
      const float c1 = e1[m], c2 = e2[m];
      #pragma unroll
      for (int j=0;j<8;j++) v[j] = mfv[j]*v[j] - dv[j] + c1 + c2*yv[j];
      *(uint4*)(Out+oidx) = pk8(v);
    }
    else if (EPI==EP_H1STAT){
      *(uint4*)(Out+oidx) = pk8(v);
      float s=0.f, q=0.f;
      #pragma unroll
      for (int j=0;j<8;j++){ s += v[j]; q = fmaf(v[j],v[j],q); }
      float s0 = (b8==bA)?s:0.f, q0 = (b8==bA)?q:0.f;
      float s1v = s-s0, q1v = q-q0;
      #pragma unroll
      for (int o=1;o<64;o<<=1){
        s0 += __shfl_xor(s0,o); q0 += __shfl_xor(q0,o);
        s1v += __shfl_xor(s1v,o); q1v += __shfl_xor(q1v,o);
      }
      if (lane==0){
        atomicAdd(&sred[0], s0); atomicAdd(&sred[1], q0);
        atomicAdd(&sred[2], s1v); atomicAdd(&sred[3], q1v);
      }
    }
    else if (EPI==EP_YADDSTAT){
      float xv[8];
      if (isb0) up8(*(const uint4*)((const u16*)e0+oidx), xv);
      else {
        float4 a0 = *(const float4*)((const float*)e0+oidx);
        float4 a1 = *(const float4*)((const float*)e0+oidx+4);
        xv[0]=a0.x; xv[1]=a0.y; xv[2]=a0.z; xv[3]=a0.w;
        xv[4]=a1.x; xv[5]=a1.y; xv[6]=a1.z; xv[7]=a1.w;
      }
      float s=0.f, q=0.f;
      #pragma unroll
      for (int j=0;j<8;j++){
        v[j] += xv[j];
        s += v[j]; q = fmaf(v[j],v[j],q);
      }
      *(uint4*)(Out+oidx) = pk8(v);
      #pragma unroll
      for (int o=1;o<16;o<<=1){ s += __shfl_xor(s,o); q += __shfl_xor(q,o); }
      if ((t&15)==0){
        atomicAdd(&sred[mi*16+row16],    s);
        atomicAdd(&sred[64+mi*16+row16], q);
      }
    }
    else if (EPI==EP_GNB1){
      float hv[8];
      up8(*(const uint4*)((const u16*)e0+oidx), hv);
      const float go = e2[m], beo = e2[HIDD+m];
      float dB=0.f, dG=0.f, sS=0.f, sQ=0.f;
      #pragma unroll
      for (int j=0;j<8;j++){
        float hn   = (hv[j]-muT)*rT;
        float ghat = fmaf(hn, go, beo);
        float dgh  = v[j]*gelu_g_fast(ghat);
        float dhn  = dgh*go;
        v[j] = dhn;
        dB += dgh; dG = fmaf(dgh,hn,dG);
        sS += dhn; sQ = fmaf(dhn,hn,sQ);
      }
      *(uint4*)(Out+oidx) = pk8(v);
      #pragma unroll
      for (int o=1;o<16;o<<=1){ dB += __shfl_xor(dB,o); dG += __shfl_xor(dG,o); }
      if ((t&15)==0){
        atomicAdd(&sred[mi*16+row16],    dB);
        atomicAdd(&sred[64+mi*16+row16], dG);
      }
      float s0 = (b8==bA)?sS:0.f, q0 = (b8==bA)?sQ:0.f;
      float s1v = sS-s0, q1v = sQ-q0;
      #pragma unroll
      for (int o=1;o<64;o<<=1){
        s0 += __shfl_xor(s0,o); q0 += __shfl_xor(q0,o);
        s1v += __shfl_xor(s1v,o); q1v += __shfl_xor(q1v,o);
      }
      if (lane==0){
        atomicAdd(&sred[128], s0); atomicAdd(&sred[129], q0);
        atomicAdd(&sred[130], s1v); atomicAdd(&sred[131], q1v);
      }
    }
    else if (EPI==EP_OUT){
      float xv[8];
      if (isb0){
        up8(*(const uint4*)((const u16*)e0+oidx), xv);
        #pragma unroll
        for (int j=0;j<8;j++) v[j] = xv[j] + gmul*v[j];
        *(uint4*)(Out+oidx) = pk8(v);
      } else {
        float4 a0 = *(const float4*)((const float*)e0+oidx);
        float4 a1 = *(const float4*)((const float*)e0+oidx+4);
        float4 r0, r1;
        r0.x = a0.x + gmul*v[0]; r0.y = a0.y + gmul*v[1];
        r0.z = a0.z + gmul*v[2]; r0.w = a0.w + gmul*v[3];
        r1.x = a1.x + gmul*v[4]; r1.y = a1.y + gmul*v[5];
        r1.z = a1.z + gmul*v[6]; r1.w = a1.w + gmul*v[7];
        *(float4*)((float*)Out+oidx)   = r0;
        *(float4*)((float*)Out+oidx+4) = r1;
      }
    }
    __syncthreads();
  }

  // final cross-block reductions
  if (EPI==EP_H1STAT){
    if (t==0){
      atomicAdd(&o3[bA*NGRP+g],     sred[0]);
      atomicAdd(&o3[128+bA*NGRP+g], sred[1]);
    }
    if (t==1 && bB!=bA){
      atomicAdd(&o3[bB*NGRP+g],     sred[2]);
      atomicAdd(&o3[128+bB*NGRP+g], sred[3]);
    }
  }
  if (EPI==EP_YADDSTAT){
    if (t<64){
      atomicAdd(&o3[m0+t],    sred[t]);
      atomicAdd(&o3[CC+m0+t], sred[64+t]);
    }
  }
  if (EPI==EP_GNB1){
    if (t<64){
      atomicAdd(&o3[m0+t],     sred[64+t]);   // dGa
      atomicAdd(&o3[512+m0+t], sred[t]);      // dBe
    }
    if (t==64){
      atomicAdd(&o3[1024+bA*NGRP+g], sred[128]);   // s1
      atomicAdd(&o3[1152+bA*NGRP+g], sred[129]);   // s2
    }
    if (t==65 && bB!=bA){
      atomicAdd(&o3[1024+bB*NGRP+g], sred[130]);
      atomicAdd(&o3[1152+bB*NGRP+g], sred[131]);
    }
  }
}

// ---------- MFMA weight-grad: flattened grid, XCD-chunk swizzle ----------
// GNB2=1: apply GN-backward stage-2 (dH1 = r*(dhn - a1 - hn*a2)) while staging P.
// QGN=1:  apply gn+gelu_fast while staging Q (Q = h1; musig = mu w/ rsig@+128,
//         qpg = pg w/ pb@+512) — replaces the k_gelu_fwd pass for the a-operand.
template<int QDYN, int GNB2, int QGN>
__global__ __launch_bounds__(256) void k_wgrad_mfma(
    const u16* __restrict__ P, const void* __restrict__ Qv, float* __restrict__ part,
    int CHP, int CHQ, const int* __restrict__ xdt, int ntx,
    const u16* __restrict__ h1, const float* __restrict__ musig,
    const float* __restrict__ red, const float* __restrict__ qpg)
{
  __shared__ __align__(16) u16 Ps[64*40];
  __shared__ __align__(16) u16 Qs[64*40];
  const int f = blockIdx.x;
  const int j = f >> 3;
  const int sk = (f & 7) + ((j >> 5) << 3);
  const int tile = j & 31;
  const int ty = tile / ntx;
  const int m0 = (tile - ty*ntx) << 6;
  const int n0 = ty << 6;
  const int t = threadIdx.x;
  const int w = t >> 6, lane = t & 63;
  const int col = lane & 15, quad = lane >> 4;
  const int isbq = QDYN ? *xdt : 1;
  const u16*   Qb = (const u16*)Qv;
  const float* Qf = (const float*)Qv;
  const int srow = (t & 127) >> 1;
  const int ssq  = ((t & 127) & 1) * 16;
  f32x4 acc[2][2];
  #pragma unroll
  for (int i=0;i<2;i++){
    #pragma unroll
    for (int jj=0;jj<2;jj++) acc[i][jj] = (f32x4)(0.0f);
  }
  const int mbase = (w & 1)*32, nbase = (w >> 1)*32;

  for (int kb = sk*CHUNK; kb < sk*CHUNK + CHUNK; kb += 32){
    const int b = kb / HWW;
    const int s = kb - b*HWW;
    if (t < 128){
      size_t off = ((size_t)b*CHP + m0+srow)*HWW + s + ssq;
      uint4 v0 = *(const uint4*)(P + off);
      uint4 v1 = *(const uint4*)(P + off + 8);
      if (GNB2){
        const int bg = b*NGRP + (m0>>6);
        const float mu_ = musig[bg], r_ = musig[128+bg];
        const float a1 = red[1024+bg]*(1.0f/GMSZ);
        const float a2 = red[1152+bg]*(1.0f/GMSZ);
        uint4 h0 = *(const uint4*)(h1 + off);
        uint4 h1v = *(const uint4*)(h1 + off + 8);
        float fd[8], fh[8];
        up8(v0, fd); up8(h0, fh);
        #pragma unroll
        for (int q2=0;q2<8;q2++){ float hn=(fh[q2]-mu_)*r_; fd[q2]=r_*(fd[q2]-a1-hn*a2); }
        v0 = pk8(fd);
        up8(v1, fd); up8(h1v, fh);
        #pragma unroll
        for (int q2=0;q2<8;q2++){ float hn=(fh[q2]-mu_)*r_; fd[q2]=r_*(fd[q2]-a1-hn*a2); }
        v1 = pk8(fd);
      }
      *(uint4*)(Ps + srow*40 + ssq)     = v0;
      *(uint4*)(Ps + srow*40 + ssq + 8) = v1;
    } else {
      size_t off = ((size_t)b*CHQ + n0+srow)*HWW + s + ssq;
      if (isbq){
        uint4 v0 = *(const uint4*)(Qb + off);
        uint4 v1 = *(const uint4*)(Qb + off + 8);
        if (QGN){
          const int o  = n0 + srow;
          const int bg = b*NGRP + (o>>6);
          const float mu_ = musig[bg], rs_ = musig[128+bg];
          const float ga_ = qpg[o], be_ = qpg[512+o];
          float fq[8];
          up8(v0, fq);
          #pragma unroll
          for (int q2=0;q2<8;q2++) fq[q2] = gelu_fast(fmaf((fq[q2]-mu_)*rs_, ga_, be_));
          v0 = pk8(fq);
          up8(v1, fq);
          #pragma unroll
          for (int q2=0;q2<8;q2++) fq[q2] = gelu_fast(fmaf((fq[q2]-mu_)*rs_, ga_, be_));
          v1 = pk8(fq);
        }
        *(uint4*)(Qs + srow*40 + ssq)     = v0;
        *(uint4*)(Qs + srow*40 + ssq + 8) = v1;
      } else {
        ushort e[16];
        #pragma unroll
        for (int g2=0; g2<4; g2++){
          float4 ff = *(const float4*)(Qf + off + g2*4);
          e[g2*4+0]=f2bf(ff.x); e[g2*4+1]=f2bf(ff.y); e[g2*4+2]=f2bf(ff.z); e[g2*4+3]=f2bf(ff.w);
        }
        *(uint4*)(Qs + srow*40 + ssq)     = pack8(e);
        *(uint4*)(Qs + srow*40 + ssq + 8) = pack8(e+8);
      }
    }
    __syncthreads();
    bf16x8 pa[2], qb[2];
    #pragma unroll
    for (int a=0;a<2;a++)
      pa[a] = *(const bf16x8*)(Ps + (mbase + a*16 + col)*40 + quad*8);
    #pragma unroll
    for (int bb=0;bb<2;bb++)
      qb[bb] = *(const bf16x8*)(Qs + (nbase + bb*16 + col)*40 + quad*8);
    #pragma unroll
    for (int a=0;a<2;a++){
      #pragma unroll
      for (int bb=0;bb<2;bb++)
        acc[a][bb] = __builtin_amdgcn_mfma_f32_16x16x32_bf16(pa[a], qb[bb], acc[a][bb], 0,0,0);
    }
    __syncthreads();
  }
  float* dst = part + (size_t)sk*CHP*CHQ;
  #pragma unroll
  for (int a=0;a<2;a++){
    #pragma unroll
    for (int bb=0;bb<2;bb++){
      #pragma unroll
      for (int r=0;r<4;r++){
        const int m = m0 + mbase + a*16 + quad*4 + r;
        const int n = n0 + nbase + bb*16 + col;
        dst[(size_t)m*CHQ + n] = acc[a][bb][r];
      }
    }
  }
}
__global__ void k_wgrad_reduce(const float* __restrict__ part, float* __restrict__ dW, int n){
  int i = blockIdx.x*256+threadIdx.x;
  if (i>=n) return;
  float s=0;
  #pragma unroll
  for (int k=0;k<SKW;k++) s += part[(size_t)k*n + i];
  dW[i]=s;
}

// ---------- GroupNorm fwd finalize + gelu (gelu pass = fallback only) ----------
__global__ void k_gn_finalize(const float* gsum, const float* gsumsq, float* mu, float* rsig){
  int i = threadIdx.x; if (i>=BB*NGRP) return;
  float m = gsum[i]*(1.0f/GMSZ);
  float v = gsumsq[i]*(1.0f/GMSZ) - m*m;
  v = fmaxf(v, 0.0f);
  mu[i]=m; rsig[i]=rsqrtf(v+1e-5f);
}
template<int FAST>
__global__ void k_gelu_fwd(const u16* __restrict__ src, u16* __restrict__ dst,
    const float* __restrict__ mu, const float* __restrict__ rsig,
    const float* __restrict__ pg, const float* __restrict__ pb){
  int bo = blockIdx.x;
  int b = bo>>9, o = bo&511, bg = b*NGRP + (o>>6);
  float m = mu[bg], r = rsig[bg], g = pg[o], be = pb[o];
  const uint4* ps = (const uint4*)(src + (size_t)bo*HWW);
  uint4* pd = (uint4*)(dst + (size_t)bo*HWW);
  for (int i=threadIdx.x;i<NV8;i+=256){
    float f[8]; up8(ps[i], f);
    #pragma unroll
    for (int j=0;j<8;j++){
      float gh = fmaf((f[j]-m)*r, g, be);
      f[j] = FAST ? gelu_fast(gh) : gelu_f(gh);
    }
    pd[i] = pk8(f);
  }
}

// ---------- y channel moments finalize ----------
__global__ void k_y_finalize(const float* cmsum, const float* cmsq,
    const float* rmf, const float* rvf, float* coefA, float* coefB){
  int c = threadIdx.x; if (c>=CC) return;
  float cm = cmsum[c]*(1.0f/NTOT);
  float cv = (cmsq[c] - (float)NTOT*cm*cm)*(1.0f/(NTOT-1));
  float rvp = rvf[c] + 1e-8f;
  float gcm = 0.2f*(cm - rmf[c])*(1.0f/CC);
  float gcv = 0.2f*(cv/rvp - 1.0f)/(rvp*(float)CC);
  coefA[c] = gcm*(1.0f/NTOT) - 2.0f*gcv*cm*(1.0f/(NTOT-1));
  coefB[c] = 2.0f*gcv*(1.0f/(NTOT-1));
}

// ---------- GroupNorm backward (fallback path only, when !h1p) ----------
__global__ void k_gn_bwd1(u16* __restrict__ dA, const u16* __restrict__ h1,
    const float* mu, const float* rsig, const float* pg, const float* pb,
    float* dGa, float* dBe, float* s1, float* s2){
  __shared__ float sm[4];
  int bo = blockIdx.x;
  int b = bo>>9, o = bo&511, bg = b*NGRP + (o>>6);
  float m = mu[bg], r = rsig[bg], g = pg[o], be = pb[o];
  uint4* pa = (uint4*)(dA + (size_t)bo*HWW);
  const uint4* ph = (const uint4*)(h1 + (size_t)bo*HWW);
  float sb=0, sg=0, t1=0, t2=0;
  for (int i=threadIdx.x;i<NV8;i+=256){
    float fa[8], fh[8]; up8(pa[i], fa); up8(ph[i], fh);
    #pragma unroll
    for (int j=0;j<8;j++){
      float hn = (fh[j]-m)*r;
      float ghat = fmaf(hn,g,be);
      float dgh = fa[j]*gelu_g_fast(ghat);
      float dhn = dgh*g;
      fa[j] = dhn;
      sb += dgh; sg = fmaf(dgh,hn,sg); t1 += dhn; t2 = fmaf(dhn,hn,t2);
    }
    pa[i] = pk8(fa);
  }
  float S;
  S = blk_sum(sb,sm); if (threadIdx.x==0) atomicAdd(&dBe[o], S);
  S = blk_sum(sg,sm); if (threadIdx.x==0) atomicAdd(&dGa[o], S);
  S = blk_sum(t1,sm); if (threadIdx.x==0) atomicAdd(&s1[bg], S);
  S = blk_sum(t2,sm); if (threadIdx.x==0) atomicAdd(&s2[bg], S);
}
__global__ void k_gn_bwd2(u16* __restrict__ dA, const u16* __restrict__ h1,
    const float* mu, const float* rsig, const float* s1, const float* s2){
  int bo = blockIdx.x;
  int b = bo>>9, o = bo&511, bg = b*NGRP + (o>>6);
  float m = mu[bg], r = rsig[bg];
  float a1 = s1[bg]*(1.0f/GMSZ), a2 = s2[bg]*(1.0f/GMSZ);
  uint4* pa = (uint4*)(dA + (size_t)bo*HWW);
  const uint4* ph = (const uint4*)(h1 + (size_t)bo*HWW);
  for (int i=threadIdx.x;i<NV8;i+=256){
    float fa[8], fh[8]; up8(pa[i], fa); up8(ph[i], fh);
    #pragma unroll
    for (int j=0;j<8;j++){
      float hn = (fh[j]-m)*r;
      fa[j] = r*(fa[j] - a1 - hn*a2);
    }
    pa[i] = pk8(fa);
  }
}

__global__ void k_update(float* pw1, float* pw2, float* pg, float* pb,
    const float* dW1, const float* dW2, const float* dGa, const float* dBe){
  int i = blockIdx.x*256+threadIdx.x;
  if (i < HIDD*CC){ pw1[i] -= LRATE*dW1[i]; pw2[i] -= LRATE*dW2[i]; }
  if (i < HIDD){ pg[i] -= LRATE*dGa[i]; pb[i] -= LRATE*dBe[i]; }
}

// ---------- gate ----------
__global__ void k_pool(const void* __restrict__ xv, const int* __restrict__ dtf, float* pooled){
  __shared__ float sm[4];
  int bc = blockIdx.x;
  int isb = *dtf;
  float s=0;
  if (isb){
    const uint4* p = (const uint4*)((const u16*)xv + (size_t)bc*HWW);
    for (int i=threadIdx.x;i<NV8;i+=256){
      float f[8]; up8(p[i], f);
      #pragma unroll
      for (int j=0;j<8;j++) s+=f[j];
    }
  } else {
    const float4* p = (const float4*)((const float*)xv + (size_t)bc*HWW);
    for (int i=threadIdx.x;i<HWW/4;i+=256){
      float4 f = p[i];
      s += f.x+f.y+f.z+f.w;
    }
  }
  float S = blk_sum(s,sm);
  if (threadIdx.x==0) pooled[bc]=S*(1.0f/HWW);
}
__global__ void k_gate(const float* __restrict__ pooled, const float* __restrict__ gw1,
    const float* __restrict__ gb1, const float* __restrict__ gw2, const float* __restrict__ gb2,
    float* gate){
  int b = blockIdx.x, j = threadIdx.x;      // 64 threads = 1 wave
  float acc = gb1[j];
  const float* pr = pooled + b*CC;
  for (int c=0;c<CC;c++) acc = fmaf(pr[c], gw1[j*CC+c], acc);
  float v = gelu_f(acc)*gw2[j];
  #pragma unroll
  for (int o=32;o>0;o>>=1) v += __shfl_down(v,o);
  if (j==0) gate[b] = 1.0f/(1.0f+expf(-(v+gb2[0])));
}

// =======================================================================
extern "C" void kernel_launch(void* const* d_in, const int* in_sizes, int n_in,
                              void* d_out, int out_size, void* d_ws, size_t ws_size,
                              hipStream_t stream)
{
  const void* x_in   = d_in[0];
  const void* w1_in  = d_in[1];
  const void* g_in   = d_in[2];
  const void* b_in   = d_in[3];
  const void* w2_in  = d_in[4];
  const void* rw1_in = d_in[5];
  const void* rw2_in = d_in[6];
  const void* gw1_in = d_in[7];
  const void* gb1_in = d_in[8];
  const void* gw2_in = d_in[9];
  const void* gb2_in = d_in[10];
  const void* rs_in  = d_in[11];
  const void* rm_in  = d_in[12];
  const void* rv_in  = d_in[13];
  const void* mk_in  = d_in[14];
  (void)in_sizes; (void)n_in; (void)out_size;

  char* base = (char*)d_ws;
  size_t off = 0;
  auto alloc = [&](size_t bytes)->char*{
    char* p = base+off; off = (off+bytes+255)&~(size_t)255; return p;
  };
  u16* ybuf = (u16*)alloc((size_t)CC*NTOT*2);     // 25.7 MB  y / h1rc-lo / wgrad part
  u16* dY   = (u16*)alloc((size_t)CC*NTOT*2);     // 25.7 MB  dY / h1rc-hi
  u16* Ab   = (u16*)alloc((size_t)HIDD*NTOT*2);   // 51.4 MB  (fallback a) / dhn / final h1
  u16* t1b  = (u16*)alloc((size_t)C4*NTOT*2);     // 6.4 MB   t1
  u16* hb   = (u16*)alloc((size_t)C4*NTOT*2);     // 6.4 MB   h / dT1
  u16* h1rc = ybuf;                               // recompute overlay (fallback path)
  float* part = (float*)ybuf;                     // SKW*131072*4 = 16.8MB <= ybuf
  float* mfb  = (float*)alloc((size_t)2*NTOT*4);
  float* pw1  = (float*)alloc(131072*4);
  float* pw2  = (float*)alloc(131072*4);
  float* dW1  = (float*)alloc(131072*4);
  float* dW2  = (float*)alloc(131072*4);
  u16* wb1   = (u16*)alloc(131072*2);
  u16* wb2   = (u16*)alloc(131072*2);
  u16* wb2T  = (u16*)alloc(131072*2);
  u16* rwb1  = (u16*)alloc(16384*2);
  u16* rwb1T = (u16*)alloc(16384*2);
  u16* rwb2  = (u16*)alloc(16384*2);
  u16* rwb2T = (u16*)alloc(16384*2);
  float* pg   = (float*)alloc(512*4);   // pg+pb contiguous (EP_GNB1 e2 / XGN-QGN pg)
  float* pb   = (float*)alloc(512*4);
  float* rw1f = (float*)alloc(16384*4);
  float* rw2f = (float*)alloc(16384*4);
  float* gw1f = (float*)alloc(16384*4);
  float* gb1f = (float*)alloc(64*4);
  float* gw2f = (float*)alloc(64*4);
  float* gb2f = (float*)alloc(256);
  float* rmf  = (float*)alloc(256*4);
  float* rvf  = (float*)alloc(256*4);
  float* rsf  = (float*)alloc(256);
  float* gsum   = (float*)alloc(512);   // gsum+gsumsq contiguous (EP_H1STAT o3)
  float* gsumsq = (float*)alloc(512);
  float* mu     = (float*)alloc(512);   // mu+rsig contiguous (GNB1 e1 / XGN-QGN mu)
  float* rsig   = (float*)alloc(512);
  float* cmsum  = (float*)alloc(1024);  // cmsum+cmsq contiguous (EP_YADDSTAT o3)
  float* cmsq   = (float*)alloc(1024);
  float* coefA  = (float*)alloc(1024);
  float* coefB  = (float*)alloc(1024);
  float* dGa    = (float*)alloc(2048);  // dGa+dBe+s1+s2 contiguous (GNB1 o3, wgrad red)
  float* dBe    = (float*)alloc(2048);
  float* s1     = (float*)alloc(512);
  float* s2     = (float*)alloc(512);
  float* pooled = (float*)alloc(16384);
  float* gate   = (float*)alloc(256);
  float* zc     = (float*)alloc(256);
  int*   dtf    = (int*)alloc(256);
  int*   mkf    = (int*)alloc(256);

  if (off > ws_size){
    k_report<<<1,64,0,stream>>>((u16*)d_out, (float)(ws_size>>20));
    return;
  }
  // adaptive: dedicated h1 buffer if ws allows (skips recompute GEMMs and
  // enables fused GNB1/GNB2/XGN/QGN paths). ws_size constant -> graph-safe.
  u16* h1p = nullptr;
  if (off + (size_t)HIDD*NTOT*2 <= ws_size)
    h1p = (u16*)alloc((size_t)HIDD*NTOT*2);       // +51.4 MB

  // ---- probes + param conversion ----
  k_detect_dtype<<<1,1,0,stream>>>((const u16*)x_in, dtf);
  k_detect_mask<<<1,1,0,stream>>>((const unsigned char*)mk_in, mkf);
  #define CVT(src,dst,n) k_cvt<<<((n)+255)/256,256,0,stream>>>(src,dst,(n),dtf)
  CVT(w1_in,  pw1,  131072);
  CVT(g_in,   pg,   512);
  CVT(b_in,   pb,   512);
  CVT(w2_in,  pw2,  131072);
  CVT(rw1_in, rw1f, 16384);
  CVT(rw2_in, rw2f, 16384);
  CVT(gw1_in, gw1f, 16384);
  CVT(gb1_in, gb1f, 64);
  CVT(gw2_in, gw2f, 64);
  CVT(gb2_in, gb2f, 1);
  CVT(rs_in,  rsf,  1);
  CVT(rm_in,  rmf,  256);
  CVT(rv_in,  rvf,  256);
  #undef CVT
  k_wcvt<<<512,256,0,stream>>>(pw1, wb1, 0,     HIDD, CC);
  k_wcvt<<<512,256,0,stream>>>(pw2, wb2, wb2T,  CC, HIDD);
  k_wcvt<<<64,256,0,stream>>>(rw1f, rwb1, rwb1T, C4, CC);
  k_wcvt<<<64,256,0,stream>>>(rw2f, rwb2, rwb2T, CC, C4);
  hipMemsetAsync(zc, 0, 8, stream);
  k_expand<<<392,256,0,stream>>>((const unsigned char*)mk_in, mkf, mfb, zc);

  // ---- 2 inner TTT steps ----
  for (int s=0; s<2; s++){
    const float* mfs = mfb + s*NTOT;
    u16* h1dst = h1p ? h1p : Ab;
    // h1 = w1 @ x  (+ fused GN stats)
    hipMemsetAsync(gsum, 0, 1024, stream);
    k_gemm_mfma<0,EP_H1STAT,1,0,0><<<dim3(392,8),256,0,stream>>>(wb1, x_in, h1dst, CC, dtf, 0,0,0,0,0, gsum, 0,0);
    k_gn_finalize<<<1,128,0,stream>>>(gsum, gsumsq, mu, rsig);
    hipMemsetAsync(cmsum, 0, 2048, stream);
    if (h1p){
      // y = w2 @ gelu(gn(h1)) + x — gn+gelu fused into X staging; 'a' never stored
      k_gemm_mfma<0,EP_YADDSTAT,0,1,1><<<dim3(392,4),256,0,stream>>>(wb2, h1p, ybuf, HIDD, dtf, 0, x_in, 0,0,0, cmsum, mu, pg);
    } else {
      k_gelu_fwd<1><<<BB*HIDD,256,0,stream>>>(Ab, Ab, mu, rsig, pg, pb);   // Ab = a (in place)
      k_gemm_mfma<0,EP_YADDSTAT,0,1,0><<<dim3(392,4),256,0,stream>>>(wb2, Ab, ybuf, HIDD, dtf, 0, x_in, 0,0,0, cmsum, 0,0);
    }
    k_y_finalize<<<1,256,0,stream>>>(cmsum, cmsq, rmf, rvf, coefA, coefB);
    // t1 = rw1 @ (y*mf); h = gelu(t1)
    k_gemm_mfma<1,EP_T1H,0,0,0><<<dim3(392,1),256,0,stream>>>(rwb1, ybuf, t1b, CC, dtf, mfs, 0,0,0, hb, 0, 0,0);
    // dY := g_rec = 2*(rec - y)*inv/D
    k_gemm_mfma<0,EP_DYREC,0,0,0><<<dim3(392,4),256,0,stream>>>(rwb2, hb, dY, C4, dtf, mfs, ybuf, zc+s, 0,0, 0, 0,0);
    // dT1 = (rw2^T @ g_rec) * gelu'(t1)
    k_gemm_mfma<0,EP_DT1,0,0,0><<<dim3(392,1),256,0,stream>>>(rwb2T, dY, hb, CC, dtf, 0, t1b, 0,0,0, 0, 0,0);
    // dY := mf*(rw1^T @ dT1) - g_rec + coefA + coefB*y
    k_gemm_mfma<0,EP_DYFIN,0,0,0><<<dim3(392,4),256,0,stream>>>(rwb1T, hb, dY, C4, dtf, mfs, ybuf, coefA, coefB, 0, 0, 0,0);
    // dW2[c,o] = sum_n dY[c,n]*a[o,n]   (part overlays ybuf: y dead)
    if (h1p){
      // a recomputed from h1 during Q staging (QGN=1)
      k_wgrad_mfma<0,0,1><<<dim3(32*SKW),256,0,stream>>>(dY, h1p, part, CC, HIDD, dtf, 4, 0, mu, 0, pg);
    } else {
      k_wgrad_mfma<0,0,0><<<dim3(32*SKW),256,0,stream>>>(dY, Ab, part, CC, HIDD, dtf, 4, 0,0,0,0);
    }
    k_wgrad_reduce<<<512,256,0,stream>>>(part, dW2, 131072);
    // dA = w2^T @ dY  (+ fused gn_bwd1 when h1 is resident)
    hipMemsetAsync(dGa, 0, 5120, stream);
    if (h1p){
      k_gemm_mfma<0,EP_GNB1,0,0,0><<<dim3(392,8),256,0,stream>>>(wb2T, dY, Ab, CC, dtf, 0, h1p, mu, pg, 0, dGa, 0,0);
      // dW1[o,c] = sum_n dH1[o,n]*x[c,n] with gn_bwd2 applied during staging
      k_wgrad_mfma<1,1,0><<<dim3(32*SKW),256,0,stream>>>(Ab, x_in, part, HIDD, CC, dtf, 8, h1p, mu, dGa, 0);
    } else {
      k_gemm_mfma<0,EP_STORE,0,0,0><<<dim3(392,8),256,0,stream>>>(wb2T, dY, Ab, CC, dtf, 0,0,0,0,0, 0, 0,0);
      k_gemm_mfma<0,EP_H1STAT,1,0,0><<<dim3(392,8),256,0,stream>>>(wb1, x_in, h1rc, CC, dtf, 0,0,0,0,0, gsum, 0,0);
      k_gn_bwd1<<<BB*HIDD,256,0,stream>>>(Ab, h1rc, mu, rsig, pg, pb, dGa, dBe, s1, s2);
      k_gn_bwd2<<<BB*HIDD,256,0,stream>>>(Ab, h1rc, mu, rsig, s1, s2);
      k_wgrad_mfma<1,0,0><<<dim3(32*SKW),256,0,stream>>>(Ab, x_in, part, HIDD, CC, dtf, 8, 0,0,0,0);
    }
    k_wgrad_reduce<<<512,256,0,stream>>>(part, dW1, 131072);
    // SGD update + refresh bf16 weight copies
    k_update<<<512,256,0,stream>>>(pw1, pw2, pg, pb, dW1, dW2, dGa, dBe);
    k_wcvt<<<512,256,0,stream>>>(pw1, wb1, 0,    HIDD, CC);
    k_wcvt<<<512,256,0,stream>>>(pw2, wb2, wb2T, CC, HIDD);
  }

  // ---- gate (x-only; hoisted before final GEMM for EP_OUT) ----
  k_pool<<<BB*CC,256,0,stream>>>(x_in, dtf, pooled);
  k_gate<<<BB,64,0,stream>>>(pooled, gw1f, gb1f, gw2f, gb2f, gate);

  // ---- final modifier forward with updated params ----
  hipMemsetAsync(gsum, 0, 1024, stream);
  k_gemm_mfma<0,EP_H1STAT,1,0,0><<<dim3(392,8),256,0,stream>>>(wb1, x_in, Ab, CC, dtf, 0,0,0,0,0, gsum, 0,0);
  k_gn_finalize<<<1,128,0,stream>>>(gsum, gsumsq, mu, rsig);
  // out = x + rsf*gate[b]*(w2 @ gelu(gn(h1)))  — gn+gelu fused into X staging,
  // residual merge fused into epilogue (no gelu pass, no k_out pass)
  k_gemm_mfma<0,EP_OUT,0,1,1><<<dim3(392,4),256,0,stream>>>(wb2, Ab, (u16*)d_out, HIDD, dtf, 0, x_in, gate, rsf, 0, 0, mu, pg);
}

// Round 8
// 1237.078 us; speedup vs baseline: 1.0077x; 1.0077x over previous
//
#include <hip/hip_runtime.h>
#include <math.h>

// SelfModifyingBlock (TTT inner loop) — round 12:
//  Round-7 structure (gelu passes fused into staging) with the XGN/QGN staging
//  parameter loads HOISTED: r7 loaded mu/rsig/gamma/beta per staged ELEMENT
//  (64 scalar VMEM per 16 elems, 8x the main loads). base=k0+xq*8 is 8-aligned
//  and never straddles a 64-group -> bg is block-constant; gamma/beta are 8
//  consecutive floats -> 2 scalar + 4x float4 loads. QGN: gamma/beta fully
//  k-loop-invariant, hoisted out of the loop.
//  (Cross-round note: r7's unchanged M=512 GEMMs read 124us vs r4's 76us with
//  identical code/counters-ratios — environment variance, not code.)

#define BB    16
#define CC    256
#define HWW   3136
#define NTOT  (BB*HWW)        // 50176
#define HIDD  512
#define NGRP  8
#define GMSZ  (64*HWW)        // 200704 elems per (b,group)
#define C4    64
#define LRATE 0.01f
#define SKW   32
#define CHUNK (NTOT/SKW)      // 1568
#define NV8   (HWW/8)         // 392 uint4 chunks per channel-row
#define FSTR  132             // fp32 LDS staging row stride (16B-aligned)

#define EP_STORE    0
#define EP_ADDFEAT  1
#define EP_T1H      2
#define EP_DYREC    3
#define EP_DT1      4
#define EP_DYFIN    5
#define EP_H1STAT   6
#define EP_YADDSTAT 7
#define EP_GNB1     8
#define EP_OUT      9

typedef unsigned short u16;
typedef __attribute__((ext_vector_type(8))) short bf16x8;
typedef __attribute__((ext_vector_type(4))) float f32x4;

__device__ __forceinline__ float bf2f(u16 u){
  return __uint_as_float(((unsigned)u)<<16);
}
__device__ __forceinline__ u16 f2bf(float f){
  unsigned u = __float_as_uint(f);
  u += 0x7FFFu + ((u>>16)&1u);
  return (u16)(u>>16);
}
// exact (gate only — tiny)
__device__ __forceinline__ float gelu_f(float x){
  return 0.5f*x*(1.0f+erff(x*0.70710678118654752f));
}
__device__ __forceinline__ float rcp_f(float x){ return __builtin_amdgcn_rcpf(x); }
// fast tanh-approx (max abs err ~1e-3 < bf16 quantum of O(1) values)
__device__ __forceinline__ float gelu_fast(float x){
  float x2 = x*x;
  float u = 0.7978845608f*x*fmaf(0.044715f, x2, 1.0f);
  float t = 1.0f - 2.0f*rcp_f(__expf(2.0f*u)+1.0f);
  return 0.5f*x*(1.0f+t);
}
__device__ __forceinline__ float gelu_g_fast(float x){
  float x2 = x*x;
  float u = 0.7978845608f*x*fmaf(0.044715f, x2, 1.0f);
  float t = 1.0f - 2.0f*rcp_f(__expf(2.0f*u)+1.0f);
  float du = 0.7978845608f*fmaf(0.134145f, x2, 1.0f);
  return fmaf(0.5f*x*(1.0f-t*t), du, 0.5f*(1.0f+t));
}
__device__ __forceinline__ float blk_sum(float v, float* sm){
  #pragma unroll
  for (int o=32;o>0;o>>=1) v += __shfl_down(v,o);
  if ((threadIdx.x & 63)==0) sm[threadIdx.x>>6] = v;
  __syncthreads();
  float r = sm[0]+sm[1]+sm[2]+sm[3];
  __syncthreads();
  return r;
}
__device__ __forceinline__ uint4 pack8(const ushort* e){
  uint4 v;
  v.x = (unsigned)e[0] | ((unsigned)e[1]<<16);
  v.y = (unsigned)e[2] | ((unsigned)e[3]<<16);
  v.z = (unsigned)e[4] | ((unsigned)e[5]<<16);
  v.w = (unsigned)e[6] | ((unsigned)e[7]<<16);
  return v;
}
__device__ __forceinline__ void up8(uint4 v, float* f){
  f[0]=bf2f((u16)(v.x&0xFFFFu)); f[1]=bf2f((u16)(v.x>>16));
  f[2]=bf2f((u16)(v.y&0xFFFFu)); f[3]=bf2f((u16)(v.y>>16));
  f[4]=bf2f((u16)(v.z&0xFFFFu)); f[5]=bf2f((u16)(v.z>>16));
  f[6]=bf2f((u16)(v.w&0xFFFFu)); f[7]=bf2f((u16)(v.w>>16));
}
__device__ __forceinline__ uint4 pk8(const float* f){
  uint4 v;
  v.x=(unsigned)f2bf(f[0])|((unsigned)f2bf(f[1])<<16);
  v.y=(unsigned)f2bf(f[2])|((unsigned)f2bf(f[3])<<16);
  v.z=(unsigned)f2bf(f[4])|((unsigned)f2bf(f[5])<<16);
  v.w=(unsigned)f2bf(f[6])|((unsigned)f2bf(f[7])<<16);
  return v;
}

// ---------- probes ----------
__global__ void k_detect_dtype(const u16* __restrict__ xs, int* flag){
  if (threadIdx.x || blockIdx.x) return;
  int plaus = 0;
  for (int i=0;i<256;i+=2){
    float f = bf2f(xs[i]);
    float a = fabsf(f);
    if (isfinite(f) && a < 32.0f && a > 1e-5f) plaus++;
  }
  *flag = (plaus >= 64) ? 1 : 0;   // 1 = bf16 inputs, 0 = fp32 inputs
}
__global__ void k_detect_mask(const unsigned char* __restrict__ m, int* flag){
  if (threadIdx.x || blockIdx.x) return;
  unsigned char mx=0; int nz0=0,nz1=0,nz2=0,nz3=0;
  for (int i=0;i<256;i++){
    unsigned char v=m[i]; if (v>mx) mx=v;
    if (v){ int r=i&3; if(r==0)nz0=1; else if(r==1)nz1=1; else if(r==2)nz2=1; else nz3=1; }
  }
  int f;
  if (mx<=1) f = (nz1|nz2|nz3) ? 0 : 1;
  else       f = (!nz0 && !nz1) ? 3 : 2;
  *flag=f;
}
__global__ void k_report(u16* out, float v){
  if (threadIdx.x==0 && blockIdx.x==0) out[0] = f2bf(v);
}

__global__ void k_cvt(const void* __restrict__ src, float* __restrict__ dst, int n,
                      const int* __restrict__ dtf){
  int i = blockIdx.x*256 + threadIdx.x;
  if (i>=n) return;
  if (*dtf) dst[i] = bf2f(((const u16*)src)[i]);
  else      dst[i] = ((const float*)src)[i];
}
__global__ void k_wcvt(const float* __restrict__ src, u16* __restrict__ d,
                       u16* __restrict__ dT, int R, int Cc){
  int i = blockIdx.x*256+threadIdx.x;
  if (i >= R*Cc) return;
  int r = i/Cc, c = i - r*Cc;
  u16 v = f2bf(src[i]);
  d[i] = v;
  if (dT) dT[(size_t)c*R + r] = v;
}

__global__ void k_expand(const unsigned char* __restrict__ mraw, const int* __restrict__ flag,
                         float* __restrict__ mf, float* __restrict__ zc){
  __shared__ float sm[4];
  int i = blockIdx.x*256 + threadIdx.x;     // grid 392 = 2*NTOT/256
  int f = *flag;
  float v;
  if (f==1)      v = (((const int*)mraw)[i] != 0) ? 1.f : 0.f;
  else if (f==0) v = (mraw[i] != 0) ? 1.f : 0.f;
  else if (f==2) v = (((const u16*)mraw)[i] != 0) ? 1.f : 0.f;
  else           v = (((const float*)mraw)[i] != 0.f) ? 1.f : 0.f;
  mf[i] = v;
  float S = blk_sum(1.f - v, sm);
  if (threadIdx.x==0) atomicAdd(&zc[blockIdx.x/196], S);
}

// ---------- MFMA GEMM: Out[m,n] = sum_k A[m,k]*X[k,n] ----------
// 64-row m-blocks, 128-col n-blocks, LDS stride 40 u16 (80B, 16B-aligned).
// XGN=1: apply gn+gelu_fast during X staging (X = h1; xmu = mu w/ rsig@+128,
// xpg = pg w/ pb@+512) with HOISTED param loads. Unified vectorized epilogue.
template<int MASKX,int EPI,int XDYN,int E0DYN,int XGN>
__global__ __launch_bounds__(256) void k_gemm_mfma(
    const u16* __restrict__ A, const void* __restrict__ Xv, u16* __restrict__ Out,
    int K, const int* __restrict__ xdt, const float* __restrict__ mf,
    const void* __restrict__ e0, const float* __restrict__ e1,
    const float* __restrict__ e2, u16* __restrict__ o2, float* __restrict__ o3,
    const float* __restrict__ xmu, const float* __restrict__ xpg)
{
  __shared__ __align__(16) u16 Ws[64*40];
  __shared__ __align__(16) u16 Xs[128*40];
  const int t = threadIdx.x;
  const int w = t >> 6, lane = t & 63;
  const int col = lane & 15, quad = lane >> 4;
  const int M = (int)gridDim.y << 6;
  const int m0 = blockIdx.y << 6, n0 = blockIdx.x << 7;
  const int isbx = XDYN ? *xdt : 1;
  const u16*   Xb = (const u16*)Xv;
  const float* Xf = (const float*)Xv;
  const int wrow = t >> 2, wkq = (t & 3) * 8;
  const int xn   = 2*(t & 63);
  const int xq   = t >> 6;
  const int gn0  = n0 + xn;
  const int xb_  = gn0 / HWW;
  const int xs_  = gn0 - xb_*HWW;

  f32x4 acc[4][2];
  #pragma unroll
  for (int i=0;i<4;i++){
    #pragma unroll
    for (int j=0;j<2;j++) acc[i][j] = (f32x4)(0.0f);
  }

  for (int k0=0; k0<K; k0+=32){
    {
      uint4 v = *(const uint4*)(A + (size_t)(m0+wrow)*K + k0 + wkq);
      *(uint4*)(Ws + wrow*40 + wkq) = v;
    }
    {
      ushort e[16];
      size_t base = ((size_t)xb_*K + k0 + xq*8)*HWW + xs_;
      if (isbx){
        if (XGN){
          // ob is 8-aligned and the 8-block never straddles a 64-group
          const int ob = k0 + xq*8;
          const int bg = xb_*NGRP + (ob>>6);
          const float mu_ = xmu[bg], rs_ = xmu[128+bg];
          float4 ga0 = *(const float4*)(xpg+ob);
          float4 ga1 = *(const float4*)(xpg+ob+4);
          float4 be0 = *(const float4*)(xpg+512+ob);
          float4 be1 = *(const float4*)(xpg+512+ob+4);
          float ga[8] = {ga0.x,ga0.y,ga0.z,ga0.w,ga1.x,ga1.y,ga1.z,ga1.w};
          float be[8] = {be0.x,be0.y,be0.z,be0.w,be1.x,be1.y,be1.z,be1.w};
          #pragma unroll
          for (int j=0;j<8;j++){
            unsigned v = *(const unsigned*)(Xb + base + (size_t)j*HWW);
            float f0 = bf2f((u16)(v & 0xFFFFu));
            float f1 = bf2f((u16)(v >> 16));
            f0 = gelu_fast(fmaf((f0-mu_)*rs_, ga[j], be[j]));
            f1 = gelu_fast(fmaf((f1-mu_)*rs_, ga[j], be[j]));
            e[j]   = f2bf(f0);
            e[8+j] = f2bf(f1);
          }
        } else {
          #pragma unroll
          for (int j=0;j<8;j++){
            unsigned v = *(const unsigned*)(Xb + base + (size_t)j*HWW);
            e[j]   = (ushort)(v & 0xFFFFu);
            e[8+j] = (ushort)(v >> 16);
          }
        }
      } else {
        #pragma unroll
        for (int j=0;j<8;j++){
          float2 f = *(const float2*)(Xf + base + (size_t)j*HWW);
          e[j]   = f2bf(f.x);
          e[8+j] = f2bf(f.y);
        }
      }
      if (MASKX){
        if (mf[gn0]   == 0.f){
          #pragma unroll
          for (int j=0;j<8;j++) e[j] = 0;
        }
        if (mf[gn0+1] == 0.f){
          #pragma unroll
          for (int j=0;j<8;j++) e[8+j] = 0;
        }
      }
      *(uint4*)(Xs + xn*40     + xq*8) = pack8(e);
      *(uint4*)(Xs + (xn+1)*40 + xq*8) = pack8(e+8);
    }
    __syncthreads();
    bf16x8 af[4], bfr[2];
    #pragma unroll
    for (int mi=0;mi<4;mi++)
      af[mi] = *(const bf16x8*)(Ws + (mi*16+col)*40 + quad*8);
    #pragma unroll
    for (int nj=0;nj<2;nj++)
      bfr[nj] = *(const bf16x8*)(Xs + (w*32+nj*16+col)*40 + quad*8);
    #pragma unroll
    for (int mi=0;mi<4;mi++){
      #pragma unroll
      for (int nj=0;nj<2;nj++)
        acc[mi][nj] = __builtin_amdgcn_mfma_f32_16x16x32_bf16(af[mi], bfr[nj], acc[mi][nj], 0,0,0);
    }
    __syncthreads();
  }
  // ---- unified vectorized epilogue (Ws -> sred scratch, Xs -> fp32 staging) ----
  const int isb0 = E0DYN ? *xdt : 1;
  float* fst  = (float*)Xs;            // 16 x FSTR fp32 = 8448B <= 10240B
  float* sred = (float*)Ws;            // reduction scratch (<= 528B)
  const int row16 = t >> 4;            // 0..15
  const int cb    = (t & 15) * 8;      // 0..120
  const int nb8   = n0 + cb;
  const int b8    = nb8 / HWW;         // all 8 cols same b (HWW%8==0, cb 8-aligned)
  const int sb8   = nb8 - b8*HWW;
  const int bA    = n0 / HWW, bB = (n0+127)/HWW;
  const int g     = m0 >> 6;

  if (EPI==EP_H1STAT){ if (t<4) sred[t]=0.f; }
  if (EPI==EP_YADDSTAT){ for (int i=t;i<128;i+=256) sred[i]=0.f; }
  if (EPI==EP_GNB1){ for (int i=t;i<132;i+=256) sred[i]=0.f; }
  if (EPI==EP_H1STAT||EPI==EP_YADDSTAT||EPI==EP_GNB1) __syncthreads();

  float dscale=0.f, gmul=0.f, muT=0.f, rT=0.f;
  if (EPI==EP_DYREC) dscale = 2.0f / (e1[0]*(float)CC + 1e-8f);
  if (EPI==EP_OUT)   gmul = e2[0]*e1[b8];
  if (EPI==EP_GNB1){ muT = e1[b8*NGRP+g]; rT = e1[128+b8*NGRP+g]; }

  #pragma unroll
  for (int mi=0;mi<4;mi++){
    #pragma unroll
    for (int nj=0;nj<2;nj++){
      #pragma unroll
      for (int r=0;r<4;r++)
        fst[(quad*4+r)*FSTR + w*32 + nj*16 + col] = acc[mi][nj][r];
    }
    __syncthreads();
    const int m = m0 + mi*16 + row16;
    const size_t oidx = ((size_t)b8*M + m)*HWW + sb8;
    float v[8];
    {
      const float* frow = fst + row16*FSTR + cb;
      float4 p0 = *(const float4*)frow;
      float4 p1 = *(const float4*)(frow+4);
      v[0]=p0.x; v[1]=p0.y; v[2]=p0.z; v[3]=p0.w;
      v[4]=p1.x; v[5]=p1.y; v[6]=p1.z; v[7]=p1.w;
    }

    if (EPI==EP_STORE){
      *(uint4*)(Out+oidx) = pk8(v);
    }
    else if (EPI==EP_ADDFEAT){
      float xv[8];
      if (isb0) up8(*(const uint4*)((const u16*)e0+oidx), xv);
      else {
        float4 a0 = *(const float4*)((const float*)e0+oidx);
        float4 a1 = *(const float4*)((const float*)e0+oidx+4);
        xv[0]=a0.x; xv[1]=a0.y; xv[2]=a0.z; xv[3]=a0.w;
        xv[4]=a1.x; xv[5]=a1.y; xv[6]=a1.z; xv[7]=a1.w;
      }
      #pragma unroll
      for (int j=0;j<8;j++) v[j] += xv[j];
      *(uint4*)(Out+oidx) = pk8(v);
    }
    else if (EPI==EP_T1H){
      *(uint4*)(Out+oidx) = pk8(v);
      float gv[8];
      #pragma unroll
      for (int j=0;j<8;j++) gv[j] = gelu_fast(v[j]);
      *(uint4*)(o2+oidx) = pk8(gv);
    }
    else if (EPI==EP_DYREC){
      float yv[8], mfv[8];
      up8(*(const uint4*)((const u16*)e0+oidx), yv);
      float4 f0 = *(const float4*)(mf+nb8);
      float4 f1 = *(const float4*)(mf+nb8+4);
      mfv[0]=f0.x; mfv[1]=f0.y; mfv[2]=f0.z; mfv[3]=f0.w;
      mfv[4]=f1.x; mfv[5]=f1.y; mfv[6]=f1.z; mfv[7]=f1.w;
      #pragma unroll
      for (int j=0;j<8;j++) v[j] = (v[j]-yv[j])*(1.0f-mfv[j])*dscale;
      *(uint4*)(Out+oidx) = pk8(v);
    }
    else if (EPI==EP_DT1){
      float tv[8];
      up8(*(const uint4*)((const u16*)e0+oidx), tv);
      #pragma unroll
      for (int j=0;j<8;j++) v[j] = v[j]*gelu_g_fast(tv[j]);
      *(uint4*)(Out+oidx) = pk8(v);
    }
    else if (EPI==EP_DYFIN){
      float yv[8], dv[8], mfv[8];
      up8(*(const uint4*)((const u16*)e0+oidx), yv);
      up8(*(const uint4*)(Out+oidx), dv);
      float4 f0 = *(const float4*)(mf+nb8);
      float4 f1 = *(const float4*)(mf+nb8+4);
      mfv[0]=f0.x; mfv[1]=f0.y; mfv[2]=f0.z; mfv[3]=f0.w;
      mfv[4]=f1.x; mfv[5]=f1.y; mfv[6]=f1.z; mfv[7]=f1.w;
      const float c1 = e1[m], c2 = e2[m];
      #pragma unroll
      for (int j=0;j<8;j++) v[j] = mfv[j]*v[j] - dv[j] + c1 + c2*yv[j];
      *(uint4*)(Out+oidx) = pk8(v);
    }
    else if (EPI==EP_H1STAT){
      *(uint4*)(Out+oidx) = pk8(v);
      float s=0.f, q=0.f;
      #pragma unroll
      for (int j=0;j<8;j++){ s += v[j]; q = fmaf(v[j],v[j],q); }
      float s0 = (b8==bA)?s:0.f, q0 = (b8==bA)?q:0.f;
      float s1v = s-s0, q1v = q-q0;
      #pragma unroll
      for (int o=1;o<64;o<<=1){
        s0 += __shfl_xor(s0,o); q0 += __shfl_xor(q0,o);
        s1v += __shfl_xor(s1v,o); q1v += __shfl_xor(q1v,o);
      }
      if (lane==0){
        atomicAdd(&sred[0], s0); atomicAdd(&sred[1], q0);
        atomicAdd(&sred[2], s1v); atomicAdd(&sred[3], q1v);
      }
    }
    else if (EPI==EP_YADDSTAT){
      float xv[8];
      if (isb0) up8(*(const uint4*)((const u16*)e0+oidx), xv);
      else {
        float4 a0 = *(const float4*)((const float*)e0+oidx);
        float4 a1 = *(const float4*)((const float*)e0+oidx+4);
        xv[0]=a0.x; xv[1]=a0.y; xv[2]=a0.z; xv[3]=a0.w;
        xv[4]=a1.x; xv[5]=a1.y; xv[6]=a1.z; xv[7]=a1.w;
      }
      float s=0.f, q=0.f;
      #pragma unroll
      for (int j=0;j<8;j++){
        v[j] += xv[j];
        s += v[j]; q = fmaf(v[j],v[j],q);
      }
      *(uint4*)(Out+oidx) = pk8(v);
      #pragma unroll
      for (int o=1;o<16;o<<=1){ s += __shfl_xor(s,o); q += __shfl_xor(q,o); }
      if ((t&15)==0){
        atomicAdd(&sred[mi*16+row16],    s);
        atomicAdd(&sred[64+mi*16+row16], q);
      }
    }
    else if (EPI==EP_GNB1){
      float hv[8];
      up8(*(const uint4*)((const u16*)e0+oidx), hv);
      const float go = e2[m], beo = e2[HIDD+m];
      float dB=0.f, dG=0.f, sS=0.f, sQ=0.f;
      #pragma unroll
      for (int j=0;j<8;j++){
        float hn   = (hv[j]-muT)*rT;
        float ghat = fmaf(hn, go, beo);
        float dgh  = v[j]*gelu_g_fast(ghat);
        float dhn  = dgh*go;
        v[j] = dhn;
        dB += dgh; dG = fmaf(dgh,hn,dG);
        sS += dhn; sQ = fmaf(dhn,hn,sQ);
      }
      *(uint4*)(Out+oidx) = pk8(v);
      #pragma unroll
      for (int o=1;o<16;o<<=1){ dB += __shfl_xor(dB,o); dG += __shfl_xor(dG,o); }
      if ((t&15)==0){
        atomicAdd(&sred[mi*16+row16],    dB);
        atomicAdd(&sred[64+mi*16+row16], dG);
      }
      float s0 = (b8==bA)?sS:0.f, q0 = (b8==bA)?sQ:0.f;
      float s1v = sS-s0, q1v = sQ-q0;
      #pragma unroll
      for (int o=1;o<64;o<<=1){
        s0 += __shfl_xor(s0,o); q0 += __shfl_xor(q0,o);
        s1v += __shfl_xor(s1v,o); q1v += __shfl_xor(q1v,o);
      }
      if (lane==0){
        atomicAdd(&sred[128], s0); atomicAdd(&sred[129], q0);
        atomicAdd(&sred[130], s1v); atomicAdd(&sred[131], q1v);
      }
    }
    else if (EPI==EP_OUT){
      float xv[8];
      if (isb0){
        up8(*(const uint4*)((const u16*)e0+oidx), xv);
        #pragma unroll
        for (int j=0;j<8;j++) v[j] = xv[j] + gmul*v[j];
        *(uint4*)(Out+oidx) = pk8(v);
      } else {
        float4 a0 = *(const float4*)((const float*)e0+oidx);
        float4 a1 = *(const float4*)((const float*)e0+oidx+4);
        float4 r0, r1;
        r0.x = a0.x + gmul*v[0]; r0.y = a0.y + gmul*v[1];
        r0.z = a0.z + gmul*v[2]; r0.w = a0.w + gmul*v[3];
        r1.x = a1.x + gmul*v[4]; r1.y = a1.y + gmul*v[5];
        r1.z = a1.z + gmul*v[6]; r1.w = a1.w + gmul*v[7];
        *(float4*)((float*)Out+oidx)   = r0;
        *(float4*)((float*)Out+oidx+4) = r1;
      }
    }
    __syncthreads();
  }

  // final cross-block reductions
  if (EPI==EP_H1STAT){
    if (t==0){
      atomicAdd(&o3[bA*NGRP+g],     sred[0]);
      atomicAdd(&o3[128+bA*NGRP+g], sred[1]);
    }
    if (t==1 && bB!=bA){
      atomicAdd(&o3[bB*NGRP+g],     sred[2]);
      atomicAdd(&o3[128+bB*NGRP+g], sred[3]);
    }
  }
  if (EPI==EP_YADDSTAT){
    if (t<64){
      atomicAdd(&o3[m0+t],    sred[t]);
      atomicAdd(&o3[CC+m0+t], sred[64+t]);
    }
  }
  if (EPI==EP_GNB1){
    if (t<64){
      atomicAdd(&o3[m0+t],     sred[64+t]);   // dGa
      atomicAdd(&o3[512+m0+t], sred[t]);      // dBe
    }
    if (t==64){
      atomicAdd(&o3[1024+bA*NGRP+g], sred[128]);   // s1
      atomicAdd(&o3[1152+bA*NGRP+g], sred[129]);   // s2
    }
    if (t==65 && bB!=bA){
      atomicAdd(&o3[1024+bB*NGRP+g], sred[130]);
      atomicAdd(&o3[1152+bB*NGRP+g], sred[131]);
    }
  }
}

// ---------- MFMA weight-grad: flattened grid, XCD-chunk swizzle ----------
// GNB2=1: apply GN-backward stage-2 (dH1 = r*(dhn - a1 - hn*a2)) while staging P.
// QGN=1:  apply gn+gelu_fast while staging Q (Q = h1; musig = mu w/ rsig@+128,
//         qpg = pg w/ pb@+512); gamma/beta hoisted out of the k-loop.
template<int QDYN, int GNB2, int QGN>
__global__ __launch_bounds__(256) void k_wgrad_mfma(
    const u16* __restrict__ P, const void* __restrict__ Qv, float* __restrict__ part,
    int CHP, int CHQ, const int* __restrict__ xdt, int ntx,
    const u16* __restrict__ h1, const float* __restrict__ musig,
    const float* __restrict__ red, const float* __restrict__ qpg)
{
  __shared__ __align__(16) u16 Ps[64*40];
  __shared__ __align__(16) u16 Qs[64*40];
  const int f = blockIdx.x;
  const int j = f >> 3;
  const int sk = (f & 7) + ((j >> 5) << 3);
  const int tile = j & 31;
  const int ty = tile / ntx;
  const int m0 = (tile - ty*ntx) << 6;
  const int n0 = ty << 6;
  const int t = threadIdx.x;
  const int w = t >> 6, lane = t & 63;
  const int col = lane & 15, quad = lane >> 4;
  const int isbq = QDYN ? *xdt : 1;
  const u16*   Qb = (const u16*)Qv;
  const float* Qf = (const float*)Qv;
  const int srow = (t & 127) >> 1;
  const int ssq  = ((t & 127) & 1) * 16;
  // QGN: per-thread row params, k-loop invariant
  float ga_q = 0.f, be_q = 0.f;
  if (QGN && t >= 128){
    ga_q = qpg[n0+srow];
    be_q = qpg[512+n0+srow];
  }
  f32x4 acc[2][2];
  #pragma unroll
  for (int i=0;i<2;i++){
    #pragma unroll
    for (int jj=0;jj<2;jj++) acc[i][jj] = (f32x4)(0.0f);
  }
  const int mbase = (w & 1)*32, nbase = (w >> 1)*32;

  for (int kb = sk*CHUNK; kb < sk*CHUNK + CHUNK; kb += 32){
    const int b = kb / HWW;
    const int s = kb - b*HWW;
    if (t < 128){
      size_t off = ((size_t)b*CHP + m0+srow)*HWW + s + ssq;
      uint4 v0 = *(const uint4*)(P + off);
      uint4 v1 = *(const uint4*)(P + off + 8);
      if (GNB2){
        const int bg = b*NGRP + (m0>>6);
        const float mu_ = musig[bg], r_ = musig[128+bg];
        const float a1 = red[1024+bg]*(1.0f/GMSZ);
        const float a2 = red[1152+bg]*(1.0f/GMSZ);
        uint4 h0 = *(const uint4*)(h1 + off);
        uint4 h1v = *(const uint4*)(h1 + off + 8);
        float fd[8], fh[8];
        up8(v0, fd); up8(h0, fh);
        #pragma unroll
        for (int q2=0;q2<8;q2++){ float hn=(fh[q2]-mu_)*r_; fd[q2]=r_*(fd[q2]-a1-hn*a2); }
        v0 = pk8(fd);
        up8(v1, fd); up8(h1v, fh);
        #pragma unroll
        for (int q2=0;q2<8;q2++){ float hn=(fh[q2]-mu_)*r_; fd[q2]=r_*(fd[q2]-a1-hn*a2); }
        v1 = pk8(fd);
      }
      *(uint4*)(Ps + srow*40 + ssq)     = v0;
      *(uint4*)(Ps + srow*40 + ssq + 8) = v1;
    } else {
      size_t off = ((size_t)b*CHQ + n0+srow)*HWW + s + ssq;
      if (isbq){
        uint4 v0 = *(const uint4*)(Qb + off);
        uint4 v1 = *(const uint4*)(Qb + off + 8);
        if (QGN){
          const int bg = b*NGRP + ((n0+srow)>>6);
          const float mu_ = musig[bg], rs_ = musig[128+bg];
          float fq[8];
          up8(v0, fq);
          #pragma unroll
          for (int q2=0;q2<8;q2++) fq[q2] = gelu_fast(fmaf((fq[q2]-mu_)*rs_, ga_q, be_q));
          v0 = pk8(fq);
          up8(v1, fq);
          #pragma unroll
          for (int q2=0;q2<8;q2++) fq[q2] = gelu_fast(fmaf((fq[q2]-mu_)*rs_, ga_q, be_q));
          v1 = pk8(fq);
        }
        *(uint4*)(Qs + srow*40 + ssq)     = v0;
        *(uint4*)(Qs + srow*40 + ssq + 8) = v1;
      } else {
        ushort e[16];
        #pragma unroll
        for (int g2=0; g2<4; g2++){
          float4 ff = *(const float4*)(Qf + off + g2*4);
          e[g2*4+0]=f2bf(ff.x); e[g2*4+1]=f2bf(ff.y); e[g2*4+2]=f2bf(ff.z); e[g2*4+3]=f2bf(ff.w);
        }
        *(uint4*)(Qs + srow*40 + ssq)     = pack8(e);
        *(uint4*)(Qs + srow*40 + ssq + 8) = pack8(e+8);
      }
    }
    __syncthreads();
    bf16x8 pa[2], qb[2];
    #pragma unroll
    for (int a=0;a<2;a++)
      pa[a] = *(const bf16x8*)(Ps + (mbase + a*16 + col)*40 + quad*8);
    #pragma unroll
    for (int bb=0;bb<2;bb++)
      qb[bb] = *(const bf16x8*)(Qs + (nbase + bb*16 + col)*40 + quad*8);
    #pragma unroll
    for (int a=0;a<2;a++){
      #pragma unroll
      for (int bb=0;bb<2;bb++)
        acc[a][bb] = __builtin_amdgcn_mfma_f32_16x16x32_bf16(pa[a], qb[bb], acc[a][bb], 0,0,0);
    }
    __syncthreads();
  }
  float* dst = part + (size_t)sk*CHP*CHQ;
  #pragma unroll
  for (int a=0;a<2;a++){
    #pragma unroll
    for (int bb=0;bb<2;bb++){
      #pragma unroll
      for (int r=0;r<4;r++){
        const int m = m0 + mbase + a*16 + quad*4 + r;
        const int n = n0 + nbase + bb*16 + col;
        dst[(size_t)m*CHQ + n] = acc[a][bb][r];
      }
    }
  }
}
__global__ void k_wgrad_reduce(const float* __restrict__ part, float* __restrict__ dW, int n){
  int i = blockIdx.x*256+threadIdx.x;
  if (i>=n) return;
  float s=0;
  #pragma unroll
  for (int k=0;k<SKW;k++) s += part[(size_t)k*n + i];
  dW[i]=s;
}

// ---------- GroupNorm fwd finalize + gelu (gelu pass = fallback only) ----------
__global__ void k_gn_finalize(const float* gsum, const float* gsumsq, float* mu, float* rsig){
  int i = threadIdx.x; if (i>=BB*NGRP) return;
  float m = gsum[i]*(1.0f/GMSZ);
  float v = gsumsq[i]*(1.0f/GMSZ) - m*m;
  v = fmaxf(v, 0.0f);
  mu[i]=m; rsig[i]=rsqrtf(v+1e-5f);
}
template<int FAST>
__global__ void k_gelu_fwd(const u16* __restrict__ src, u16* __restrict__ dst,
    const float* __restrict__ mu, const float* __restrict__ rsig,
    const float* __restrict__ pg, const float* __restrict__ pb){
  int bo = blockIdx.x;
  int b = bo>>9, o = bo&511, bg = b*NGRP + (o>>6);
  float m = mu[bg], r = rsig[bg], g = pg[o], be = pb[o];
  const uint4* ps = (const uint4*)(src + (size_t)bo*HWW);
  uint4* pd = (uint4*)(dst + (size_t)bo*HWW);
  for (int i=threadIdx.x;i<NV8;i+=256){
    float f[8]; up8(ps[i], f);
    #pragma unroll
    for (int j=0;j<8;j++){
      float gh = fmaf((f[j]-m)*r, g, be);
      f[j] = FAST ? gelu_fast(gh) : gelu_f(gh);
    }
    pd[i] = pk8(f);
  }
}

// ---------- y channel moments finalize ----------
__global__ void k_y_finalize(const float* cmsum, const float* cmsq,
    const float* rmf, const float* rvf, float* coefA, float* coefB){
  int c = threadIdx.x; if (c>=CC) return;
  float cm = cmsum[c]*(1.0f/NTOT);
  float cv = (cmsq[c] - (float)NTOT*cm*cm)*(1.0f/(NTOT-1));
  float rvp = rvf[c] + 1e-8f;
  float gcm = 0.2f*(cm - rmf[c])*(1.0f/CC);
  float gcv = 0.2f*(cv/rvp - 1.0f)/(rvp*(float)CC);
  coefA[c] = gcm*(1.0f/NTOT) - 2.0f*gcv*cm*(1.0f/(NTOT-1));
  coefB[c] = 2.0f*gcv*(1.0f/(NTOT-1));
}

// ---------- GroupNorm backward (fallback path only, when !h1p) ----------
__global__ void k_gn_bwd1(u16* __restrict__ dA, const u16* __restrict__ h1,
    const float* mu, const float* rsig, const float* pg, const float* pb,
    float* dGa, float* dBe, float* s1, float* s2){
  __shared__ float sm[4];
  int bo = blockIdx.x;
  int b = bo>>9, o = bo&511, bg = b*NGRP + (o>>6);
  float m = mu[bg], r = rsig[bg], g = pg[o], be = pb[o];
  uint4* pa = (uint4*)(dA + (size_t)bo*HWW);
  const uint4* ph = (const uint4*)(h1 + (size_t)bo*HWW);
  float sb=0, sg=0, t1=0, t2=0;
  for (int i=threadIdx.x;i<NV8;i+=256){
    float fa[8], fh[8]; up8(pa[i], fa); up8(ph[i], fh);
    #pragma unroll
    for (int j=0;j<8;j++){
      float hn = (fh[j]-m)*r;
      float ghat = fmaf(hn,g,be);
      float dgh = fa[j]*gelu_g_fast(ghat);
      float dhn = dgh*g;
      fa[j] = dhn;
      sb += dgh; sg = fmaf(dgh,hn,sg); t1 += dhn; t2 = fmaf(dhn,hn,t2);
    }
    pa[i] = pk8(fa);
  }
  float S;
  S = blk_sum(sb,sm); if (threadIdx.x==0) atomicAdd(&dBe[o], S);
  S = blk_sum(sg,sm); if (threadIdx.x==0) atomicAdd(&dGa[o], S);
  S = blk_sum(t1,sm); if (threadIdx.x==0) atomicAdd(&s1[bg], S);
  S = blk_sum(t2,sm); if (threadIdx.x==0) atomicAdd(&s2[bg], S);
}
__global__ void k_gn_bwd2(u16* __restrict__ dA, const u16* __restrict__ h1,
    const float* mu, const float* rsig, const float* s1, const float* s2){
  int bo = blockIdx.x;
  int b = bo>>9, o = bo&511, bg = b*NGRP + (o>>6);
  float m = mu[bg], r = rsig[bg];
  float a1 = s1[bg]*(1.0f/GMSZ), a2 = s2[bg]*(1.0f/GMSZ);
  uint4* pa = (uint4*)(dA + (size_t)bo*HWW);
  const uint4* ph = (const uint4*)(h1 + (size_t)bo*HWW);
  for (int i=threadIdx.x;i<NV8;i+=256){
    float fa[8], fh[8]; up8(pa[i], fa); up8(ph[i], fh);
    #pragma unroll
    for (int j=0;j<8;j++){
      float hn = (fh[j]-m)*r;
      fa[j] = r*(fa[j] - a1 - hn*a2);
    }
    pa[i] = pk8(fa);
  }
}

__global__ void k_update(float* pw1, float* pw2, float* pg, float* pb,
    const float* dW1, const float* dW2, const float* dGa, const float* dBe){
  int i = blockIdx.x*256+threadIdx.x;
  if (i < HIDD*CC){ pw1[i] -= LRATE*dW1[i]; pw2[i] -= LRATE*dW2[i]; }
  if (i < HIDD){ pg[i] -= LRATE*dGa[i]; pb[i] -= LRATE*dBe[i]; }
}

// ---------- gate ----------
__global__ void k_pool(const void* __restrict__ xv, const int* __restrict__ dtf, float* pooled){
  __shared__ float sm[4];
  int bc = blockIdx.x;
  int isb = *dtf;
  float s=0;
  if (isb){
    const uint4* p = (const uint4*)((const u16*)xv + (size_t)bc*HWW);
    for (int i=threadIdx.x;i<NV8;i+=256){
      float f[8]; up8(p[i], f);
      #pragma unroll
      for (int j=0;j<8;j++) s+=f[j];
    }
  } else {
    const float4* p = (const float4*)((const float*)xv + (size_t)bc*HWW);
    for (int i=threadIdx.x;i<HWW/4;i+=256){
      float4 f = p[i];
      s += f.x+f.y+f.z+f.w;
    }
  }
  float S = blk_sum(s,sm);
  if (threadIdx.x==0) pooled[bc]=S*(1.0f/HWW);
}
__global__ void k_gate(const float* __restrict__ pooled, const float* __restrict__ gw1,
    const float* __restrict__ gb1, const float* __restrict__ gw2, const float* __restrict__ gb2,
    float* gate){
  int b = blockIdx.x, j = threadIdx.x;      // 64 threads = 1 wave
  float acc = gb1[j];
  const float* pr = pooled + b*CC;
  for (int c=0;c<CC;c++) acc = fmaf(pr[c], gw1[j*CC+c], acc);
  float v = gelu_f(acc)*gw2[j];
  #pragma unroll
  for (int o=32;o>0;o>>=1) v += __shfl_down(v,o);
  if (j==0) gate[b] = 1.0f/(1.0f+expf(-(v+gb2[0])));
}

// =======================================================================
extern "C" void kernel_launch(void* const* d_in, const int* in_sizes, int n_in,
                              void* d_out, int out_size, void* d_ws, size_t ws_size,
                              hipStream_t stream)
{
  const void* x_in   = d_in[0];
  const void* w1_in  = d_in[1];
  const void* g_in   = d_in[2];
  const void* b_in   = d_in[3];
  const void* w2_in  = d_in[4];
  const void* rw1_in = d_in[5];
  const void* rw2_in = d_in[6];
  const void* gw1_in = d_in[7];
  const void* gb1_in = d_in[8];
  const void* gw2_in = d_in[9];
  const void* gb2_in = d_in[10];
  const void* rs_in  = d_in[11];
  const void* rm_in  = d_in[12];
  const void* rv_in  = d_in[13];
  const void* mk_in  = d_in[14];
  (void)in_sizes; (void)n_in; (void)out_size;

  char* base = (char*)d_ws;
  size_t off = 0;
  auto alloc = [&](size_t bytes)->char*{
    char* p = base+off; off = (off+bytes+255)&~(size_t)255; return p;
  };
  u16* ybuf = (u16*)alloc((size_t)CC*NTOT*2);     // 25.7 MB  y / h1rc-lo / wgrad part
  u16* dY   = (u16*)alloc((size_t)CC*NTOT*2);     // 25.7 MB  dY / h1rc-hi
  u16* Ab   = (u16*)alloc((size_t)HIDD*NTOT*2);   // 51.4 MB  (fallback a) / dhn / final h1
  u16* t1b  = (u16*)alloc((size_t)C4*NTOT*2);     // 6.4 MB   t1
  u16* hb   = (u16*)alloc((size_t)C4*NTOT*2);     // 6.4 MB   h / dT1
  u16* h1rc = ybuf;                               // recompute overlay (fallback path)
  float* part = (float*)ybuf;                     // SKW*131072*4 = 16.8MB <= ybuf
  float* mfb  = (float*)alloc((size_t)2*NTOT*4);
  float* pw1  = (float*)alloc(131072*4);
  float* pw2  = (float*)alloc(131072*4);
  float* dW1  = (float*)alloc(131072*4);
  float* dW2  = (float*)alloc(131072*4);
  u16* wb1   = (u16*)alloc(131072*2);
  u16* wb2   = (u16*)alloc(131072*2);
  u16* wb2T  = (u16*)alloc(131072*2);
  u16* rwb1  = (u16*)alloc(16384*2);
  u16* rwb1T = (u16*)alloc(16384*2);
  u16* rwb2  = (u16*)alloc(16384*2);
  u16* rwb2T = (u16*)alloc(16384*2);
  float* pg   = (float*)alloc(512*4);   // pg+pb contiguous (GNB1 e2 / XGN-QGN pg)
  float* pb   = (float*)alloc(512*4);
  float* rw1f = (float*)alloc(16384*4);
  float* rw2f = (float*)alloc(16384*4);
  float* gw1f = (float*)alloc(16384*4);
  float* gb1f = (float*)alloc(64*4);
  float* gw2f = (float*)alloc(64*4);
  float* gb2f = (float*)alloc(256);
  float* rmf  = (float*)alloc(256*4);
  float* rvf  = (float*)alloc(256*4);
  float* rsf  = (float*)alloc(256);
  float* gsum   = (float*)alloc(512);   // gsum+gsumsq contiguous (EP_H1STAT o3)
  float* gsumsq = (float*)alloc(512);
  float* mu     = (float*)alloc(512);   // mu+rsig contiguous (GNB1 e1 / XGN-QGN mu)
  float* rsig   = (float*)alloc(512);
  float* cmsum  = (float*)alloc(1024);  // cmsum+cmsq contiguous (EP_YADDSTAT o3)
  float* cmsq   = (float*)alloc(1024);
  float* coefA  = (float*)alloc(1024);
  float* coefB  = (float*)alloc(1024);
  float* dGa    = (float*)alloc(2048);  // dGa+dBe+s1+s2 contiguous (GNB1 o3, wgrad red)
  float* dBe    = (float*)alloc(2048);
  float* s1     = (float*)alloc(512);
  float* s2     = (float*)alloc(512);
  float* pooled = (float*)alloc(16384);
  float* gate   = (float*)alloc(256);
  float* zc     = (float*)alloc(256);
  int*   dtf    = (int*)alloc(256);
  int*   mkf    = (int*)alloc(256);

  if (off > ws_size){
    k_report<<<1,64,0,stream>>>((u16*)d_out, (float)(ws_size>>20));
    return;
  }
  // adaptive: dedicated h1 buffer if ws allows (skips recompute GEMMs and
  // enables fused GNB1/GNB2/XGN/QGN paths). ws_size constant -> graph-safe.
  u16* h1p = nullptr;
  if (off + (size_t)HIDD*NTOT*2 <= ws_size)
    h1p = (u16*)alloc((size_t)HIDD*NTOT*2);       // +51.4 MB

  // ---- probes + param conversion ----
  k_detect_dtype<<<1,1,0,stream>>>((const u16*)x_in, dtf);
  k_detect_mask<<<1,1,0,stream>>>((const unsigned char*)mk_in, mkf);
  #define CVT(src,dst,n) k_cvt<<<((n)+255)/256,256,0,stream>>>(src,dst,(n),dtf)
  CVT(w1_in,  pw1,  131072);
  CVT(g_in,   pg,   512);
  CVT(b_in,   pb,   512);
  CVT(w2_in,  pw2,  131072);
  CVT(rw1_in, rw1f, 16384);
  CVT(rw2_in, rw2f, 16384);
  CVT(gw1_in, gw1f, 16384);
  CVT(gb1_in, gb1f, 64);
  CVT(gw2_in, gw2f, 64);
  CVT(gb2_in, gb2f, 1);
  CVT(rs_in,  rsf,  1);
  CVT(rm_in,  rmf,  256);
  CVT(rv_in,  rvf,  256);
  #undef CVT
  k_wcvt<<<512,256,0,stream>>>(pw1, wb1, 0,     HIDD, CC);
  k_wcvt<<<512,256,0,stream>>>(pw2, wb2, wb2T,  CC, HIDD);
  k_wcvt<<<64,256,0,stream>>>(rw1f, rwb1, rwb1T, C4, CC);
  k_wcvt<<<64,256,0,stream>>>(rw2f, rwb2, rwb2T, CC, C4);
  hipMemsetAsync(zc, 0, 8, stream);
  k_expand<<<392,256,0,stream>>>((const unsigned char*)mk_in, mkf, mfb, zc);

  // ---- 2 inner TTT steps ----
  for (int s=0; s<2; s++){
    const float* mfs = mfb + s*NTOT;
    u16* h1dst = h1p ? h1p : Ab;
    // h1 = w1 @ x  (+ fused GN stats)
    hipMemsetAsync(gsum, 0, 1024, stream);
    k_gemm_mfma<0,EP_H1STAT,1,0,0><<<dim3(392,8),256,0,stream>>>(wb1, x_in, h1dst, CC, dtf, 0,0,0,0,0, gsum, 0,0);
    k_gn_finalize<<<1,128,0,stream>>>(gsum, gsumsq, mu, rsig);
    hipMemsetAsync(cmsum, 0, 2048, stream);
    if (h1p){
      // y = w2 @ gelu(gn(h1)) + x — gn+gelu fused into X staging; 'a' never stored
      k_gemm_mfma<0,EP_YADDSTAT,0,1,1><<<dim3(392,4),256,0,stream>>>(wb2, h1p, ybuf, HIDD, dtf, 0, x_in, 0,0,0, cmsum, mu, pg);
    } else {
      k_gelu_fwd<1><<<BB*HIDD,256,0,stream>>>(Ab, Ab, mu, rsig, pg, pb);   // Ab = a (in place)
      k_gemm_mfma<0,EP_YADDSTAT,0,1,0><<<dim3(392,4),256,0,stream>>>(wb2, Ab, ybuf, HIDD, dtf, 0, x_in, 0,0,0, cmsum, 0,0);
    }
    k_y_finalize<<<1,256,0,stream>>>(cmsum, cmsq, rmf, rvf, coefA, coefB);
    // t1 = rw1 @ (y*mf); h = gelu(t1)
    k_gemm_mfma<1,EP_T1H,0,0,0><<<dim3(392,1),256,0,stream>>>(rwb1, ybuf, t1b, CC, dtf, mfs, 0,0,0, hb, 0, 0,0);
    // dY := g_rec = 2*(rec - y)*inv/D
    k_gemm_mfma<0,EP_DYREC,0,0,0><<<dim3(392,4),256,0,stream>>>(rwb2, hb, dY, C4, dtf, mfs, ybuf, zc+s, 0,0, 0, 0,0);
    // dT1 = (rw2^T @ g_rec) * gelu'(t1)
    k_gemm_mfma<0,EP_DT1,0,0,0><<<dim3(392,1),256,0,stream>>>(rwb2T, dY, hb, CC, dtf, 0, t1b, 0,0,0, 0, 0,0);
    // dY := mf*(rw1^T @ dT1) - g_rec + coefA + coefB*y
    k_gemm_mfma<0,EP_DYFIN,0,0,0><<<dim3(392,4),256,0,stream>>>(rwb1T, hb, dY, C4, dtf, mfs, ybuf, coefA, coefB, 0, 0, 0,0);
    // dW2[c,o] = sum_n dY[c,n]*a[o,n]   (part overlays ybuf: y dead)
    if (h1p){
      // a recomputed from h1 during Q staging (QGN=1, hoisted params)
      k_wgrad_mfma<0,0,1><<<dim3(32*SKW),256,0,stream>>>(dY, h1p, part, CC, HIDD, dtf, 4, 0, mu, 0, pg);
    } else {
      k_wgrad_mfma<0,0,0><<<dim3(32*SKW),256,0,stream>>>(dY, Ab, part, CC, HIDD, dtf, 4, 0,0,0,0);
    }
    k_wgrad_reduce<<<512,256,0,stream>>>(part, dW2, 131072);
    // dA = w2^T @ dY  (+ fused gn_bwd1 when h1 is resident)
    hipMemsetAsync(dGa, 0, 5120, stream);
    if (h1p){
      k_gemm_mfma<0,EP_GNB1,0,0,0><<<dim3(392,8),256,0,stream>>>(wb2T, dY, Ab, CC, dtf, 0, h1p, mu, pg, 0, dGa, 0,0);
      // dW1[o,c] = sum_n dH1[o,n]*x[c,n] with gn_bwd2 applied during staging
      k_wgrad_mfma<1,1,0><<<dim3(32*SKW),256,0,stream>>>(Ab, x_in, part, HIDD, CC, dtf, 8, h1p, mu, dGa, 0);
    } else {
      k_gemm_mfma<0,EP_STORE,0,0,0><<<dim3(392,8),256,0,stream>>>(wb2T, dY, Ab, CC, dtf, 0,0,0,0,0, 0, 0,0);
      k_gemm_mfma<0,EP_H1STAT,1,0,0><<<dim3(392,8),256,0,stream>>>(wb1, x_in, h1rc, CC, dtf, 0,0,0,0,0, gsum, 0,0);
      k_gn_bwd1<<<BB*HIDD,256,0,stream>>>(Ab, h1rc, mu, rsig, pg, pb, dGa, dBe, s1, s2);
      k_gn_bwd2<<<BB*HIDD,256,0,stream>>>(Ab, h1rc, mu, rsig, s1, s2);
      k_wgrad_mfma<1,0,0><<<dim3(32*SKW),256,0,stream>>>(Ab, x_in, part, HIDD, CC, dtf, 8, 0,0,0,0);
    }
    k_wgrad_reduce<<<512,256,0,stream>>>(part, dW1, 131072);
    // SGD update + refresh bf16 weight copies
    k_update<<<512,256,0,stream>>>(pw1, pw2, pg, pb, dW1, dW2, dGa, dBe);
    k_wcvt<<<512,256,0,stream>>>(pw1, wb1, 0,    HIDD, CC);
    k_wcvt<<<512,256,0,stream>>>(pw2, wb2, wb2T, CC, HIDD);
  }

  // ---- gate (x-only; hoisted before final GEMM for EP_OUT) ----
  k_pool<<<BB*CC,256,0,stream>>>(x_in, dtf, pooled);
  k_gate<<<BB,64,0,stream>>>(pooled, gw1f, gb1f, gw2f, gb2f, gate);

  // ---- final modifier forward with updated params ----
  hipMemsetAsync(gsum, 0, 1024, stream);
  k_gemm_mfma<0,EP_H1STAT,1,0,0><<<dim3(392,8),256,0,stream>>>(wb1, x_in, Ab, CC, dtf, 0,0,0,0,0, gsum, 0,0);
  k_gn_finalize<<<1,128,0,stream>>>(gsum, gsumsq, mu, rsig);
  // out = x + rsf*gate[b]*(w2 @ gelu(gn(h1)))  — gn+gelu fused into X staging,
  // residual merge fused into epilogue (no gelu pass, no k_out pass)
  k_gemm_mfma<0,EP_OUT,0,1,1><<<dim3(392,4),256,0,stream>>>(wb2, Ab, (u16*)d_out, HIDD, dtf, 0, x_in, gate, rsf, 0, 0, mu, pg);
}

// Round 9
// 1145.080 us; speedup vs baseline: 1.0887x; 1.0803x over previous
//
#include <hip/hip_runtime.h>
#include <math.h>

// SelfModifyingBlock (TTT inner loop) — round 13:
//  MT=2 m-tiling RESTORED with the ALIGNED stride 40 (80B). Round-5/6 isolated
//  the real r9 regression to stride 42 = 84B (misaligned b128 -> 4x b32 LDS ops);
//  under equal misalignment MT=2 was FASTER (157 vs 163us). MT=2 halves the 8x
//  X re-staging VALU + L2 re-fetch of the five ~120us M=512 GEMMs.
//  Keeps r12's hoisted XGN/QGN staging params and all fusions.

#define BB    16
#define CC    256
#define HWW   3136
#define NTOT  (BB*HWW)        // 50176
#define HIDD  512
#define NGRP  8
#define GMSZ  (64*HWW)        // 200704 elems per (b,group)
#define C4    64
#define LRATE 0.01f
#define SKW   32
#define CHUNK (NTOT/SKW)      // 1568
#define NV8   (HWW/8)         // 392 uint4 chunks per channel-row
#define FSTR  132             // fp32 LDS staging row stride (16B-aligned)

#define EP_STORE    0
#define EP_ADDFEAT  1
#define EP_T1H      2
#define EP_DYREC    3
#define EP_DT1      4
#define EP_DYFIN    5
#define EP_H1STAT   6
#define EP_YADDSTAT 7
#define EP_GNB1     8
#define EP_OUT      9

typedef unsigned short u16;
typedef __attribute__((ext_vector_type(8))) short bf16x8;
typedef __attribute__((ext_vector_type(4))) float f32x4;

__device__ __forceinline__ float bf2f(u16 u){
  return __uint_as_float(((unsigned)u)<<16);
}
__device__ __forceinline__ u16 f2bf(float f){
  unsigned u = __float_as_uint(f);
  u += 0x7FFFu + ((u>>16)&1u);
  return (u16)(u>>16);
}
// exact (gate only — tiny)
__device__ __forceinline__ float gelu_f(float x){
  return 0.5f*x*(1.0f+erff(x*0.70710678118654752f));
}
__device__ __forceinline__ float rcp_f(float x){ return __builtin_amdgcn_rcpf(x); }
// fast tanh-approx (max abs err ~1e-3 < bf16 quantum of O(1) values)
__device__ __forceinline__ float gelu_fast(float x){
  float x2 = x*x;
  float u = 0.7978845608f*x*fmaf(0.044715f, x2, 1.0f);
  float t = 1.0f - 2.0f*rcp_f(__expf(2.0f*u)+1.0f);
  return 0.5f*x*(1.0f+t);
}
__device__ __forceinline__ float gelu_g_fast(float x){
  float x2 = x*x;
  float u = 0.7978845608f*x*fmaf(0.044715f, x2, 1.0f);
  float t = 1.0f - 2.0f*rcp_f(__expf(2.0f*u)+1.0f);
  float du = 0.7978845608f*fmaf(0.134145f, x2, 1.0f);
  return fmaf(0.5f*x*(1.0f-t*t), du, 0.5f*(1.0f+t));
}
__device__ __forceinline__ float blk_sum(float v, float* sm){
  #pragma unroll
  for (int o=32;o>0;o>>=1) v += __shfl_down(v,o);
  if ((threadIdx.x & 63)==0) sm[threadIdx.x>>6] = v;
  __syncthreads();
  float r = sm[0]+sm[1]+sm[2]+sm[3];
  __syncthreads();
  return r;
}
__device__ __forceinline__ uint4 pack8(const ushort* e){
  uint4 v;
  v.x = (unsigned)e[0] | ((unsigned)e[1]<<16);
  v.y = (unsigned)e[2] | ((unsigned)e[3]<<16);
  v.z = (unsigned)e[4] | ((unsigned)e[5]<<16);
  v.w = (unsigned)e[6] | ((unsigned)e[7]<<16);
  return v;
}
__device__ __forceinline__ void up8(uint4 v, float* f){
  f[0]=bf2f((u16)(v.x&0xFFFFu)); f[1]=bf2f((u16)(v.x>>16));
  f[2]=bf2f((u16)(v.y&0xFFFFu)); f[3]=bf2f((u16)(v.y>>16));
  f[4]=bf2f((u16)(v.z&0xFFFFu)); f[5]=bf2f((u16)(v.z>>16));
  f[6]=bf2f((u16)(v.w&0xFFFFu)); f[7]=bf2f((u16)(v.w>>16));
}
__device__ __forceinline__ uint4 pk8(const float* f){
  uint4 v;
  v.x=(unsigned)f2bf(f[0])|((unsigned)f2bf(f[1])<<16);
  v.y=(unsigned)f2bf(f[2])|((unsigned)f2bf(f[3])<<16);
  v.z=(unsigned)f2bf(f[4])|((unsigned)f2bf(f[5])<<16);
  v.w=(unsigned)f2bf(f[6])|((unsigned)f2bf(f[7])<<16);
  return v;
}

// ---------- probes ----------
__global__ void k_detect_dtype(const u16* __restrict__ xs, int* flag){
  if (threadIdx.x || blockIdx.x) return;
  int plaus = 0;
  for (int i=0;i<256;i+=2){
    float f = bf2f(xs[i]);
    float a = fabsf(f);
    if (isfinite(f) && a < 32.0f && a > 1e-5f) plaus++;
  }
  *flag = (plaus >= 64) ? 1 : 0;   // 1 = bf16 inputs, 0 = fp32 inputs
}
__global__ void k_detect_mask(const unsigned char* __restrict__ m, int* flag){
  if (threadIdx.x || blockIdx.x) return;
  unsigned char mx=0; int nz0=0,nz1=0,nz2=0,nz3=0;
  for (int i=0;i<256;i++){
    unsigned char v=m[i]; if (v>mx) mx=v;
    if (v){ int r=i&3; if(r==0)nz0=1; else if(r==1)nz1=1; else if(r==2)nz2=1; else nz3=1; }
  }
  int f;
  if (mx<=1) f = (nz1|nz2|nz3) ? 0 : 1;
  else       f = (!nz0 && !nz1) ? 3 : 2;
  *flag=f;
}
__global__ void k_report(u16* out, float v){
  if (threadIdx.x==0 && blockIdx.x==0) out[0] = f2bf(v);
}

__global__ void k_cvt(const void* __restrict__ src, float* __restrict__ dst, int n,
                      const int* __restrict__ dtf){
  int i = blockIdx.x*256 + threadIdx.x;
  if (i>=n) return;
  if (*dtf) dst[i] = bf2f(((const u16*)src)[i]);
  else      dst[i] = ((const float*)src)[i];
}
__global__ void k_wcvt(const float* __restrict__ src, u16* __restrict__ d,
                       u16* __restrict__ dT, int R, int Cc){
  int i = blockIdx.x*256+threadIdx.x;
  if (i >= R*Cc) return;
  int r = i/Cc, c = i - r*Cc;
  u16 v = f2bf(src[i]);
  d[i] = v;
  if (dT) dT[(size_t)c*R + r] = v;
}

__global__ void k_expand(const unsigned char* __restrict__ mraw, const int* __restrict__ flag,
                         float* __restrict__ mf, float* __restrict__ zc){
  __shared__ float sm[4];
  int i = blockIdx.x*256 + threadIdx.x;     // grid 392 = 2*NTOT/256
  int f = *flag;
  float v;
  if (f==1)      v = (((const int*)mraw)[i] != 0) ? 1.f : 0.f;
  else if (f==0) v = (mraw[i] != 0) ? 1.f : 0.f;
  else if (f==2) v = (((const u16*)mraw)[i] != 0) ? 1.f : 0.f;
  else           v = (((const float*)mraw)[i] != 0.f) ? 1.f : 0.f;
  mf[i] = v;
  float S = blk_sum(1.f - v, sm);
  if (threadIdx.x==0) atomicAdd(&zc[blockIdx.x/196], S);
}

// ---------- MFMA GEMM: Out[m,n] = sum_k A[m,k]*X[k,n] ----------
// MT: 64*MT m-rows per block. LDS stride 40 u16 (80B, 16B-aligned).
// XGN=1: apply gn+gelu_fast during X staging (X = h1; xmu = mu w/ rsig@+128,
// xpg = pg w/ pb@+512), hoisted param loads. Unified vectorized epilogue.
template<int MASKX,int EPI,int XDYN,int E0DYN,int MT,int XGN>
__global__ __launch_bounds__(256) void k_gemm_mfma(
    const u16* __restrict__ A, const void* __restrict__ Xv, u16* __restrict__ Out,
    int K, const int* __restrict__ xdt, const float* __restrict__ mf,
    const void* __restrict__ e0, const float* __restrict__ e1,
    const float* __restrict__ e2, u16* __restrict__ o2, float* __restrict__ o3,
    const float* __restrict__ xmu, const float* __restrict__ xpg)
{
  constexpr int MROWS = 64*MT;
  constexpr int NMI   = 4*MT;
  __shared__ __align__(16) u16 Ws[MROWS*40];
  __shared__ __align__(16) u16 Xs[128*40];
  const int t = threadIdx.x;
  const int w = t >> 6, lane = t & 63;
  const int col = lane & 15, quad = lane >> 4;
  const int M = (int)gridDim.y * MROWS;
  const int m0 = blockIdx.y * MROWS, n0 = blockIdx.x << 7;
  const int isbx = XDYN ? *xdt : 1;
  const u16*   Xb = (const u16*)Xv;
  const float* Xf = (const float*)Xv;
  const int wrow = t >> 2, wkq = (t & 3) * 8;
  const int xn   = 2*(t & 63);
  const int xq   = t >> 6;
  const int gn0  = n0 + xn;
  const int xb_  = gn0 / HWW;
  const int xs_  = gn0 - xb_*HWW;

  f32x4 acc[NMI][2];
  #pragma unroll
  for (int i=0;i<NMI;i++){
    #pragma unroll
    for (int j=0;j<2;j++) acc[i][j] = (f32x4)(0.0f);
  }

  for (int k0=0; k0<K; k0+=32){
    if (MT==2){
      const u16* ap = A + (size_t)(m0 + (t>>1))*K + k0 + (t&1)*16;
      *(uint4*)(Ws + (t>>1)*40 + (t&1)*16)     = *(const uint4*)ap;
      *(uint4*)(Ws + (t>>1)*40 + (t&1)*16 + 8) = *(const uint4*)(ap+8);
    } else {
      uint4 v = *(const uint4*)(A + (size_t)(m0+wrow)*K + k0 + wkq);
      *(uint4*)(Ws + wrow*40 + wkq) = v;
    }
    {
      ushort e[16];
      size_t base = ((size_t)xb_*K + k0 + xq*8)*HWW + xs_;
      if (isbx){
        if (XGN){
          // ob is 8-aligned and the 8-block never straddles a 64-group
          const int ob = k0 + xq*8;
          const int bg = xb_*NGRP + (ob>>6);
          const float mu_ = xmu[bg], rs_ = xmu[128+bg];
          float4 ga0 = *(const float4*)(xpg+ob);
          float4 ga1 = *(const float4*)(xpg+ob+4);
          float4 be0 = *(const float4*)(xpg+512+ob);
          float4 be1 = *(const float4*)(xpg+512+ob+4);
          float ga[8] = {ga0.x,ga0.y,ga0.z,ga0.w,ga1.x,ga1.y,ga1.z,ga1.w};
          float be[8] = {be0.x,be0.y,be0.z,be0.w,be1.x,be1.y,be1.z,be1.w};
          #pragma unroll
          for (int j=0;j<8;j++){
            unsigned v = *(const unsigned*)(Xb + base + (size_t)j*HWW);
            float f0 = bf2f((u16)(v & 0xFFFFu));
            float f1 = bf2f((u16)(v >> 16));
            f0 = gelu_fast(fmaf((f0-mu_)*rs_, ga[j], be[j]));
            f1 = gelu_fast(fmaf((f1-mu_)*rs_, ga[j], be[j]));
            e[j]   = f2bf(f0);
            e[8+j] = f2bf(f1);
          }
        } else {
          #pragma unroll
          for (int j=0;j<8;j++){
            unsigned v = *(const unsigned*)(Xb + base + (size_t)j*HWW);
            e[j]   = (ushort)(v & 0xFFFFu);
            e[8+j] = (ushort)(v >> 16);
          }
        }
      } else {
        #pragma unroll
        for (int j=0;j<8;j++){
          float2 f = *(const float2*)(Xf + base + (size_t)j*HWW);
          e[j]   = f2bf(f.x);
          e[8+j] = f2bf(f.y);
        }
      }
      if (MASKX){
        if (mf[gn0]   == 0.f){
          #pragma unroll
          for (int j=0;j<8;j++) e[j] = 0;
        }
        if (mf[gn0+1] == 0.f){
          #pragma unroll
          for (int j=0;j<8;j++) e[8+j] = 0;
        }
      }
      *(uint4*)(Xs + xn*40     + xq*8) = pack8(e);
      *(uint4*)(Xs + (xn+1)*40 + xq*8) = pack8(e+8);
    }
    __syncthreads();
    bf16x8 bfr[2];
    #pragma unroll
    for (int nj=0;nj<2;nj++)
      bfr[nj] = *(const bf16x8*)(Xs + (w*32+nj*16+col)*40 + quad*8);
    #pragma unroll
    for (int mi=0;mi<NMI;mi++){
      bf16x8 af = *(const bf16x8*)(Ws + (mi*16+col)*40 + quad*8);
      acc[mi][0] = __builtin_amdgcn_mfma_f32_16x16x32_bf16(af, bfr[0], acc[mi][0], 0,0,0);
      acc[mi][1] = __builtin_amdgcn_mfma_f32_16x16x32_bf16(af, bfr[1], acc[mi][1], 0,0,0);
    }
    __syncthreads();
  }
  // ---- unified vectorized epilogue (Ws -> sred scratch, Xs -> fp32 staging) ----
  const int isb0 = E0DYN ? *xdt : 1;
  float* fst  = (float*)Xs;            // 16 x FSTR fp32 = 8448B <= 10240B
  float* sred = (float*)Ws;            // reduction scratch (<= 1056B)
  const int row16 = t >> 4;            // 0..15
  const int cb    = (t & 15) * 8;      // 0..120
  const int nb8   = n0 + cb;
  const int b8    = nb8 / HWW;         // all 8 cols same b (HWW%8==0, cb 8-aligned)
  const int sb8   = nb8 - b8*HWW;
  const int bA    = n0 / HWW, bB = (n0+127)/HWW;
  const int gbase = m0 >> 6;

  if (EPI==EP_H1STAT){ if (t < 4*MT) sred[t]=0.f; }
  if (EPI==EP_GNB1){ if (t < 4*MT) sred[2*NMI*16 + t]=0.f; }
  if (EPI==EP_H1STAT||EPI==EP_GNB1) __syncthreads();

  float dscale=0.f, gmul=0.f;
  if (EPI==EP_DYREC) dscale = 2.0f / (e1[0]*(float)CC + 1e-8f);
  if (EPI==EP_OUT)   gmul = e2[0]*e1[b8];
  // per-(group,b-slot) register accumulators (H1STAT: sum/sq; GNB1: s1/s2)
  float hs0[MT], hq0[MT], hs1[MT], hq1[MT];
  #pragma unroll
  for (int i=0;i<MT;i++){ hs0[i]=0.f; hq0[i]=0.f; hs1[i]=0.f; hq1[i]=0.f; }

  #pragma unroll
  for (int mi=0;mi<NMI;mi++){
    #pragma unroll
    for (int nj=0;nj<2;nj++){
      #pragma unroll
      for (int r=0;r<4;r++)
        fst[(quad*4+r)*FSTR + w*32 + nj*16 + col] = acc[mi][nj][r];
    }
    __syncthreads();
    const int m = m0 + mi*16 + row16;
    const size_t oidx = ((size_t)b8*M + m)*HWW + sb8;
    float v[8];
    {
      const float* frow = fst + row16*FSTR + cb;
      float4 p0 = *(const float4*)frow;
      float4 p1 = *(const float4*)(frow+4);
      v[0]=p0.x; v[1]=p0.y; v[2]=p0.z; v[3]=p0.w;
      v[4]=p1.x; v[5]=p1.y; v[6]=p1.z; v[7]=p1.w;
    }

    if (EPI==EP_STORE){
      *(uint4*)(Out+oidx) = pk8(v);
    }
    else if (EPI==EP_ADDFEAT){
      float xv[8];
      if (isb0) up8(*(const uint4*)((const u16*)e0+oidx), xv);
      else {
        float4 a0 = *(const float4*)((const float*)e0+oidx);
        float4 a1 = *(const float4*)((const float*)e0+oidx+4);
        xv[0]=a0.x; xv[1]=a0.y; xv[2]=a0.z; xv[3]=a0.w;
        xv[4]=a1.x; xv[5]=a1.y; xv[6]=a1.z; xv[7]=a1.w;
      }
      #pragma unroll
      for (int j=0;j<8;j++) v[j] += xv[j];
      *(uint4*)(Out+oidx) = pk8(v);
    }
    else if (EPI==EP_T1H){
      *(uint4*)(Out+oidx) = pk8(v);
      float gv[8];
      #pragma unroll
      for (int j=0;j<8;j++) gv[j] = gelu_fast(v[j]);
      *(uint4*)(o2+oidx) = pk8(gv);
    }
    else if (EPI==EP_DYREC){
      float yv[8], mfv[8];
      up8(*(const uint4*)((const u16*)e0+oidx), yv);
      float4 f0 = *(const float4*)(mf+nb8);
      float4 f1 = *(const float4*)(mf+nb8+4);
      mfv[0]=f0.x; mfv[1]=f0.y; mfv[2]=f0.z; mfv[3]=f0.w;
      mfv[4]=f1.x; mfv[5]=f1.y; mfv[6]=f1.z; mfv[7]=f1.w;
      #pragma unroll
      for (int j=0;j<8;j++) v[j] = (v[j]-yv[j])*(1.0f-mfv[j])*dscale;
      *(uint4*)(Out+oidx) = pk8(v);
    }
    else if (EPI==EP_DT1){
      float tv[8];
      up8(*(const uint4*)((const u16*)e0+oidx), tv);
      #pragma unroll
      for (int j=0;j<8;j++) v[j] = v[j]*gelu_g_fast(tv[j]);
      *(uint4*)(Out+oidx) = pk8(v);
    }
    else if (EPI==EP_DYFIN){
      float yv[8], dv[8], mfv[8];
      up8(*(const uint4*)((const u16*)e0+oidx), yv);
      up8(*(const uint4*)(Out+oidx), dv);
      float4 f0 = *(const float4*)(mf+nb8);
      float4 f1 = *(const float4*)(mf+nb8+4);
      mfv[0]=f0.x; mfv[1]=f0.y; mfv[2]=f0.z; mfv[3]=f0.w;
      mfv[4]=f1.x; mfv[5]=f1.y; mfv[6]=f1.z; mfv[7]=f1.w;
      const float c1 = e1[m], c2 = e2[m];
      #pragma unroll
      for (int j=0;j<8;j++) v[j] = mfv[j]*v[j] - dv[j] + c1 + c2*yv[j];
      *(uint4*)(Out+oidx) = pk8(v);
    }
    else if (EPI==EP_H1STAT){
      *(uint4*)(Out+oidx) = pk8(v);
      float s=0.f, q=0.f;
      #pragma unroll
      for (int j=0;j<8;j++){ s += v[j]; q = fmaf(v[j],v[j],q); }
      const bool inA = (b8==bA);
      hs0[mi>>2] += inA ? s : 0.f;  hq0[mi>>2] += inA ? q : 0.f;
      hs1[mi>>2] += inA ? 0.f : s;  hq1[mi>>2] += inA ? 0.f : q;
    }
    else if (EPI==EP_YADDSTAT){
      float xv[8];
      if (isb0) up8(*(const uint4*)((const u16*)e0+oidx), xv);
      else {
        float4 a0 = *(const float4*)((const float*)e0+oidx);
        float4 a1 = *(const float4*)((const float*)e0+oidx+4);
        xv[0]=a0.x; xv[1]=a0.y; xv[2]=a0.z; xv[3]=a0.w;
        xv[4]=a1.x; xv[5]=a1.y; xv[6]=a1.z; xv[7]=a1.w;
      }
      float s=0.f, q=0.f;
      #pragma unroll
      for (int j=0;j<8;j++){
        v[j] += xv[j];
        s += v[j]; q = fmaf(v[j],v[j],q);
      }
      *(uint4*)(Out+oidx) = pk8(v);
      #pragma unroll
      for (int o=1;o<16;o<<=1){ s += __shfl_xor(s,o); q += __shfl_xor(q,o); }
      if ((t&15)==0){
        sred[mi*16+row16]          = s;
        sred[NMI*16 + mi*16+row16] = q;
      }
    }
    else if (EPI==EP_GNB1){
      float hv[8];
      up8(*(const uint4*)((const u16*)e0+oidx), hv);
      const int gcur = gbase + (mi>>2);
      const float muT = e1[b8*NGRP+gcur], rT = e1[128+b8*NGRP+gcur];
      const float go = e2[m], beo = e2[HIDD+m];
      float dB=0.f, dG=0.f, sS=0.f, sQ=0.f;
      #pragma unroll
      for (int j=0;j<8;j++){
        float hn   = (hv[j]-muT)*rT;
        float ghat = fmaf(hn, go, beo);
        float dgh  = v[j]*gelu_g_fast(ghat);
        float dhn  = dgh*go;
        v[j] = dhn;
        dB += dgh; dG = fmaf(dgh,hn,dG);
        sS += dhn; sQ = fmaf(dhn,hn,sQ);
      }
      *(uint4*)(Out+oidx) = pk8(v);
      #pragma unroll
      for (int o=1;o<16;o<<=1){ dB += __shfl_xor(dB,o); dG += __shfl_xor(dG,o); }
      if ((t&15)==0){
        sred[mi*16+row16]          = dB;
        sred[NMI*16 + mi*16+row16] = dG;
      }
      const bool inA = (b8==bA);
      hs0[mi>>2] += inA ? sS : 0.f;  hq0[mi>>2] += inA ? sQ : 0.f;
      hs1[mi>>2] += inA ? 0.f : sS;  hq1[mi>>2] += inA ? 0.f : sQ;
    }
    else if (EPI==EP_OUT){
      float xv[8];
      if (isb0){
        up8(*(const uint4*)((const u16*)e0+oidx), xv);
        #pragma unroll
        for (int j=0;j<8;j++) v[j] = xv[j] + gmul*v[j];
        *(uint4*)(Out+oidx) = pk8(v);
      } else {
        float4 a0 = *(const float4*)((const float*)e0+oidx);
        float4 a1 = *(const float4*)((const float*)e0+oidx+4);
        float4 r0, r1;
        r0.x = a0.x + gmul*v[0]; r0.y = a0.y + gmul*v[1];
        r0.z = a0.z + gmul*v[2]; r0.w = a0.w + gmul*v[3];
        r1.x = a1.x + gmul*v[4]; r1.y = a1.y + gmul*v[5];
        r1.z = a1.z + gmul*v[6]; r1.w = a1.w + gmul*v[7];
        *(float4*)((float*)Out+oidx)   = r0;
        *(float4*)((float*)Out+oidx+4) = r1;
      }
    }
    __syncthreads();
  }

  // cross-wave (group,b) reductions for H1STAT / GNB1
  if (EPI==EP_H1STAT || EPI==EP_GNB1){
    const int soff = (EPI==EP_GNB1) ? 2*NMI*16 : 0;
    #pragma unroll
    for (int g2=0; g2<MT; g2++){
      float a0=hs0[g2], c0=hq0[g2], a1=hs1[g2], c1=hq1[g2];
      #pragma unroll
      for (int o=1;o<64;o<<=1){
        a0 += __shfl_xor(a0,o); c0 += __shfl_xor(c0,o);
        a1 += __shfl_xor(a1,o); c1 += __shfl_xor(c1,o);
      }
      if (lane==0){
        atomicAdd(&sred[soff+g2*4+0], a0);
        atomicAdd(&sred[soff+g2*4+1], c0);
        atomicAdd(&sred[soff+g2*4+2], a1);
        atomicAdd(&sred[soff+g2*4+3], c1);
      }
    }
    __syncthreads();
  }

  // final global reductions
  if (EPI==EP_H1STAT){
    if (t==0){
      #pragma unroll
      for (int g2=0; g2<MT; g2++){
        atomicAdd(&o3[bA*NGRP+gbase+g2],     sred[g2*4+0]);
        atomicAdd(&o3[128+bA*NGRP+gbase+g2], sred[g2*4+1]);
      }
    }
    if (t==1 && bB!=bA){
      #pragma unroll
      for (int g2=0; g2<MT; g2++){
        atomicAdd(&o3[bB*NGRP+gbase+g2],     sred[g2*4+2]);
        atomicAdd(&o3[128+bB*NGRP+gbase+g2], sred[g2*4+3]);
      }
    }
  }
  if (EPI==EP_YADDSTAT){
    if (t < NMI*16){
      atomicAdd(&o3[m0+t],    sred[t]);
      atomicAdd(&o3[CC+m0+t], sred[NMI*16+t]);
    }
  }
  if (EPI==EP_GNB1){
    if (t < NMI*16){
      atomicAdd(&o3[m0+t],     sred[NMI*16+t]);   // dGa
      atomicAdd(&o3[512+m0+t], sred[t]);          // dBe
    }
    if (t==NMI*16){
      #pragma unroll
      for (int g2=0; g2<MT; g2++){
        atomicAdd(&o3[1024+bA*NGRP+gbase+g2], sred[2*NMI*16+g2*4+0]);  // s1
        atomicAdd(&o3[1152+bA*NGRP+gbase+g2], sred[2*NMI*16+g2*4+1]);  // s2
      }
    }
    if (t==NMI*16+1 && bB!=bA){
      #pragma unroll
      for (int g2=0; g2<MT; g2++){
        atomicAdd(&o3[1024+bB*NGRP+gbase+g2], sred[2*NMI*16+g2*4+2]);
        atomicAdd(&o3[1152+bB*NGRP+gbase+g2], sred[2*NMI*16+g2*4+3]);
      }
    }
  }
}

// ---------- MFMA weight-grad: flattened grid, XCD-chunk swizzle ----------
// GNB2=1: apply GN-backward stage-2 (dH1 = r*(dhn - a1 - hn*a2)) while staging P.
// QGN=1:  apply gn+gelu_fast while staging Q (Q = h1; musig = mu w/ rsig@+128,
//         qpg = pg w/ pb@+512); gamma/beta hoisted out of the k-loop.
template<int QDYN, int GNB2, int QGN>
__global__ __launch_bounds__(256) void k_wgrad_mfma(
    const u16* __restrict__ P, const void* __restrict__ Qv, float* __restrict__ part,
    int CHP, int CHQ, const int* __restrict__ xdt, int ntx,
    const u16* __restrict__ h1, const float* __restrict__ musig,
    const float* __restrict__ red, const float* __restrict__ qpg)
{
  __shared__ __align__(16) u16 Ps[64*40];
  __shared__ __align__(16) u16 Qs[64*40];
  const int f = blockIdx.x;
  const int j = f >> 3;
  const int sk = (f & 7) + ((j >> 5) << 3);
  const int tile = j & 31;
  const int ty = tile / ntx;
  const int m0 = (tile - ty*ntx) << 6;
  const int n0 = ty << 6;
  const int t = threadIdx.x;
  const int w = t >> 6, lane = t & 63;
  const int col = lane & 15, quad = lane >> 4;
  const int isbq = QDYN ? *xdt : 1;
  const u16*   Qb = (const u16*)Qv;
  const float* Qf = (const float*)Qv;
  const int srow = (t & 127) >> 1;
  const int ssq  = ((t & 127) & 1) * 16;
  // QGN: per-thread row params, k-loop invariant
  float ga_q = 0.f, be_q = 0.f;
  if (QGN && t >= 128){
    ga_q = qpg[n0+srow];
    be_q = qpg[512+n0+srow];
  }
  f32x4 acc[2][2];
  #pragma unroll
  for (int i=0;i<2;i++){
    #pragma unroll
    for (int jj=0;jj<2;jj++) acc[i][jj] = (f32x4)(0.0f);
  }
  const int mbase = (w & 1)*32, nbase = (w >> 1)*32;

  for (int kb = sk*CHUNK; kb < sk*CHUNK + CHUNK; kb += 32){
    const int b = kb / HWW;
    const int s = kb - b*HWW;
    if (t < 128){
      size_t off = ((size_t)b*CHP + m0+srow)*HWW + s + ssq;
      uint4 v0 = *(const uint4*)(P + off);
      uint4 v1 = *(const uint4*)(P + off + 8);
      if (GNB2){
        const int bg = b*NGRP + (m0>>6);
        const float mu_ = musig[bg], r_ = musig[128+bg];
        const float a1 = red[1024+bg]*(1.0f/GMSZ);
        const float a2 = red[1152+bg]*(1.0f/GMSZ);
        uint4 h0 = *(const uint4*)(h1 + off);
        uint4 h1v = *(const uint4*)(h1 + off + 8);
        float fd[8], fh[8];
        up8(v0, fd); up8(h0, fh);
        #pragma unroll
        for (int q2=0;q2<8;q2++){ float hn=(fh[q2]-mu_)*r_; fd[q2]=r_*(fd[q2]-a1-hn*a2); }
        v0 = pk8(fd);
        up8(v1, fd); up8(h1v, fh);
        #pragma unroll
        for (int q2=0;q2<8;q2++){ float hn=(fh[q2]-mu_)*r_; fd[q2]=r_*(fd[q2]-a1-hn*a2); }
        v1 = pk8(fd);
      }
      *(uint4*)(Ps + srow*40 + ssq)     = v0;
      *(uint4*)(Ps + srow*40 + ssq + 8) = v1;
    } else {
      size_t off = ((size_t)b*CHQ + n0+srow)*HWW + s + ssq;
      if (isbq){
        uint4 v0 = *(const uint4*)(Qb + off);
        uint4 v1 = *(const uint4*)(Qb + off + 8);
        if (QGN){
          const int bg = b*NGRP + ((n0+srow)>>6);
          const float mu_ = musig[bg], rs_ = musig[128+bg];
          float fq[8];
          up8(v0, fq);
          #pragma unroll
          for (int q2=0;q2<8;q2++) fq[q2] = gelu_fast(fmaf((fq[q2]-mu_)*rs_, ga_q, be_q));
          v0 = pk8(fq);
          up8(v1, fq);
          #pragma unroll
          for (int q2=0;q2<8;q2++) fq[q2] = gelu_fast(fmaf((fq[q2]-mu_)*rs_, ga_q, be_q));
          v1 = pk8(fq);
        }
        *(uint4*)(Qs + srow*40 + ssq)     = v0;
        *(uint4*)(Qs + srow*40 + ssq + 8) = v1;
      } else {
        ushort e[16];
        #pragma unroll
        for (int g2=0; g2<4; g2++){
          float4 ff = *(const float4*)(Qf + off + g2*4);
          e[g2*4+0]=f2bf(ff.x); e[g2*4+1]=f2bf(ff.y); e[g2*4+2]=f2bf(ff.z); e[g2*4+3]=f2bf(ff.w);
        }
        *(uint4*)(Qs + srow*40 + ssq)     = pack8(e);
        *(uint4*)(Qs + srow*40 + ssq + 8) = pack8(e+8);
      }
    }
    __syncthreads();
    bf16x8 pa[2], qb[2];
    #pragma unroll
    for (int a=0;a<2;a++)
      pa[a] = *(const bf16x8*)(Ps + (mbase + a*16 + col)*40 + quad*8);
    #pragma unroll
    for (int bb=0;bb<2;bb++)
      qb[bb] = *(const bf16x8*)(Qs + (nbase + bb*16 + col)*40 + quad*8);
    #pragma unroll
    for (int a=0;a<2;a++){
      #pragma unroll
      for (int bb=0;bb<2;bb++)
        acc[a][bb] = __builtin_amdgcn_mfma_f32_16x16x32_bf16(pa[a], qb[bb], acc[a][bb], 0,0,0);
    }
    __syncthreads();
  }
  float* dst = part + (size_t)sk*CHP*CHQ;
  #pragma unroll
  for (int a=0;a<2;a++){
    #pragma unroll
    for (int bb=0;bb<2;bb++){
      #pragma unroll
      for (int r=0;r<4;r++){
        const int m = m0 + mbase + a*16 + quad*4 + r;
        const int n = n0 + nbase + bb*16 + col;
        dst[(size_t)m*CHQ + n] = acc[a][bb][r];
      }
    }
  }
}
__global__ void k_wgrad_reduce(const float* __restrict__ part, float* __restrict__ dW, int n){
  int i = blockIdx.x*256+threadIdx.x;
  if (i>=n) return;
  float s=0;
  #pragma unroll
  for (int k=0;k<SKW;k++) s += part[(size_t)k*n + i];
  dW[i]=s;
}

// ---------- GroupNorm fwd finalize + gelu (gelu pass = fallback only) ----------
__global__ void k_gn_finalize(const float* gsum, const float* gsumsq, float* mu, float* rsig){
  int i = threadIdx.x; if (i>=BB*NGRP) return;
  float m = gsum[i]*(1.0f/GMSZ);
  float v = gsumsq[i]*(1.0f/GMSZ) - m*m;
  v = fmaxf(v, 0.0f);
  mu[i]=m; rsig[i]=rsqrtf(v+1e-5f);
}
template<int FAST>
__global__ void k_gelu_fwd(const u16* __restrict__ src, u16* __restrict__ dst,
    const float* __restrict__ mu, const float* __restrict__ rsig,
    const float* __restrict__ pg, const float* __restrict__ pb){
  int bo = blockIdx.x;
  int b = bo>>9, o = bo&511, bg = b*NGRP + (o>>6);
  float m = mu[bg], r = rsig[bg], g = pg[o], be = pb[o];
  const uint4* ps = (const uint4*)(src + (size_t)bo*HWW);
  uint4* pd = (uint4*)(dst + (size_t)bo*HWW);
  for (int i=threadIdx.x;i<NV8;i+=256){
    float f[8]; up8(ps[i], f);
    #pragma unroll
    for (int j=0;j<8;j++){
      float gh = fmaf((f[j]-m)*r, g, be);
      f[j] = FAST ? gelu_fast(gh) : gelu_f(gh);
    }
    pd[i] = pk8(f);
  }
}

// ---------- y channel moments finalize ----------
__global__ void k_y_finalize(const float* cmsum, const float* cmsq,
    const float* rmf, const float* rvf, float* coefA, float* coefB){
  int c = threadIdx.x; if (c>=CC) return;
  float cm = cmsum[c]*(1.0f/NTOT);
  float cv = (cmsq[c] - (float)NTOT*cm*cm)*(1.0f/(NTOT-1));
  float rvp = rvf[c] + 1e-8f;
  float gcm = 0.2f*(cm - rmf[c])*(1.0f/CC);
  float gcv = 0.2f*(cv/rvp - 1.0f)/(rvp*(float)CC);
  coefA[c] = gcm*(1.0f/NTOT) - 2.0f*gcv*cm*(1.0f/(NTOT-1));
  coefB[c] = 2.0f*gcv*(1.0f/(NTOT-1));
}

// ---------- GroupNorm backward (fallback path only, when !h1p) ----------
__global__ void k_gn_bwd1(u16* __restrict__ dA, const u16* __restrict__ h1,
    const float* mu, const float* rsig, const float* pg, const float* pb,
    float* dGa, float* dBe, float* s1, float* s2){
  __shared__ float sm[4];
  int bo = blockIdx.x;
  int b = bo>>9, o = bo&511, bg = b*NGRP + (o>>6);
  float m = mu[bg], r = rsig[bg], g = pg[o], be = pb[o];
  uint4* pa = (uint4*)(dA + (size_t)bo*HWW);
  const uint4* ph = (const uint4*)(h1 + (size_t)bo*HWW);
  float sb=0, sg=0, t1=0, t2=0;
  for (int i=threadIdx.x;i<NV8;i+=256){
    float fa[8], fh[8]; up8(pa[i], fa); up8(ph[i], fh);
    #pragma unroll
    for (int j=0;j<8;j++){
      float hn = (fh[j]-m)*r;
      float ghat = fmaf(hn,g,be);
      float dgh = fa[j]*gelu_g_fast(ghat);
      float dhn = dgh*g;
      fa[j] = dhn;
      sb += dgh; sg = fmaf(dgh,hn,sg); t1 += dhn; t2 = fmaf(dhn,hn,t2);
    }
    pa[i] = pk8(fa);
  }
  float S;
  S = blk_sum(sb,sm); if (threadIdx.x==0) atomicAdd(&dBe[o], S);
  S = blk_sum(sg,sm); if (threadIdx.x==0) atomicAdd(&dGa[o], S);
  S = blk_sum(t1,sm); if (threadIdx.x==0) atomicAdd(&s1[bg], S);
  S = blk_sum(t2,sm); if (threadIdx.x==0) atomicAdd(&s2[bg], S);
}
__global__ void k_gn_bwd2(u16* __restrict__ dA, const u16* __restrict__ h1,
    const float* mu, const float* rsig, const float* s1, const float* s2){
  int bo = blockIdx.x;
  int b = bo>>9, o = bo&511, bg = b*NGRP + (o>>6);
  float m = mu[bg], r = rsig[bg];
  float a1 = s1[bg]*(1.0f/GMSZ), a2 = s2[bg]*(1.0f/GMSZ);
  uint4* pa = (uint4*)(dA + (size_t)bo*HWW);
  const uint4* ph = (const uint4*)(h1 + (size_t)bo*HWW);
  for (int i=threadIdx.x;i<NV8;i+=256){
    float fa[8], fh[8]; up8(pa[i], fa); up8(ph[i], fh);
    #pragma unroll
    for (int j=0;j<8;j++){
      float hn = (fh[j]-m)*r;
      fa[j] = r*(fa[j] - a1 - hn*a2);
    }
    pa[i] = pk8(fa);
  }
}

__global__ void k_update(float* pw1, float* pw2, float* pg, float* pb,
    const float* dW1, const float* dW2, const float* dGa, const float* dBe){
  int i = blockIdx.x*256+threadIdx.x;
  if (i < HIDD*CC){ pw1[i] -= LRATE*dW1[i]; pw2[i] -= LRATE*dW2[i]; }
  if (i < HIDD){ pg[i] -= LRATE*dGa[i]; pb[i] -= LRATE*dBe[i]; }
}

// ---------- gate ----------
__global__ void k_pool(const void* __restrict__ xv, const int* __restrict__ dtf, float* pooled){
  __shared__ float sm[4];
  int bc = blockIdx.x;
  int isb = *dtf;
  float s=0;
  if (isb){
    const uint4* p = (const uint4*)((const u16*)xv + (size_t)bc*HWW);
    for (int i=threadIdx.x;i<NV8;i+=256){
      float f[8]; up8(p[i], f);
      #pragma unroll
      for (int j=0;j<8;j++) s+=f[j];
    }
  } else {
    const float4* p = (const float4*)((const float*)xv + (size_t)bc*HWW);
    for (int i=threadIdx.x;i<HWW/4;i+=256){
      float4 f = p[i];
      s += f.x+f.y+f.z+f.w;
    }
  }
  float S = blk_sum(s,sm);
  if (threadIdx.x==0) pooled[bc]=S*(1.0f/HWW);
}
__global__ void k_gate(const float* __restrict__ pooled, const float* __restrict__ gw1,
    const float* __restrict__ gb1, const float* __restrict__ gw2, const float* __restrict__ gb2,
    float* gate){
  int b = blockIdx.x, j = threadIdx.x;      // 64 threads = 1 wave
  float acc = gb1[j];
  const float* pr = pooled + b*CC;
  for (int c=0;c<CC;c++) acc = fmaf(pr[c], gw1[j*CC+c], acc);
  float v = gelu_f(acc)*gw2[j];
  #pragma unroll
  for (int o=32;o>0;o>>=1) v += __shfl_down(v,o);
  if (j==0) gate[b] = 1.0f/(1.0f+expf(-(v+gb2[0])));
}

// =======================================================================
extern "C" void kernel_launch(void* const* d_in, const int* in_sizes, int n_in,
                              void* d_out, int out_size, void* d_ws, size_t ws_size,
                              hipStream_t stream)
{
  const void* x_in   = d_in[0];
  const void* w1_in  = d_in[1];
  const void* g_in   = d_in[2];
  const void* b_in   = d_in[3];
  const void* w2_in  = d_in[4];
  const void* rw1_in = d_in[5];
  const void* rw2_in = d_in[6];
  const void* gw1_in = d_in[7];
  const void* gb1_in = d_in[8];
  const void* gw2_in = d_in[9];
  const void* gb2_in = d_in[10];
  const void* rs_in  = d_in[11];
  const void* rm_in  = d_in[12];
  const void* rv_in  = d_in[13];
  const void* mk_in  = d_in[14];
  (void)in_sizes; (void)n_in; (void)out_size;

  char* base = (char*)d_ws;
  size_t off = 0;
  auto alloc = [&](size_t bytes)->char*{
    char* p = base+off; off = (off+bytes+255)&~(size_t)255; return p;
  };
  u16* ybuf = (u16*)alloc((size_t)CC*NTOT*2);     // 25.7 MB  y / h1rc-lo / wgrad part
  u16* dY   = (u16*)alloc((size_t)CC*NTOT*2);     // 25.7 MB  dY / h1rc-hi
  u16* Ab   = (u16*)alloc((size_t)HIDD*NTOT*2);   // 51.4 MB  (fallback a) / dhn / final h1
  u16* t1b  = (u16*)alloc((size_t)C4*NTOT*2);     // 6.4 MB   t1
  u16* hb   = (u16*)alloc((size_t)C4*NTOT*2);     // 6.4 MB   h / dT1
  u16* h1rc = ybuf;                               // recompute overlay (fallback path)
  float* part = (float*)ybuf;                     // SKW*131072*4 = 16.8MB <= ybuf
  float* mfb  = (float*)alloc((size_t)2*NTOT*4);
  float* pw1  = (float*)alloc(131072*4);
  float* pw2  = (float*)alloc(131072*4);
  float* dW1  = (float*)alloc(131072*4);
  float* dW2  = (float*)alloc(131072*4);
  u16* wb1   = (u16*)alloc(131072*2);
  u16* wb2   = (u16*)alloc(131072*2);
  u16* wb2T  = (u16*)alloc(131072*2);
  u16* rwb1  = (u16*)alloc(16384*2);
  u16* rwb1T = (u16*)alloc(16384*2);
  u16* rwb2  = (u16*)alloc(16384*2);
  u16* rwb2T = (u16*)alloc(16384*2);
  float* pg   = (float*)alloc(512*4);   // pg+pb contiguous (GNB1 e2 / XGN-QGN pg)
  float* pb   = (float*)alloc(512*4);
  float* rw1f = (float*)alloc(16384*4);
  float* rw2f = (float*)alloc(16384*4);
  float* gw1f = (float*)alloc(16384*4);
  float* gb1f = (float*)alloc(64*4);
  float* gw2f = (float*)alloc(64*4);
  float* gb2f = (float*)alloc(256);
  float* rmf  = (float*)alloc(256*4);
  float* rvf  = (float*)alloc(256*4);
  float* rsf  = (float*)alloc(256);
  float* gsum   = (float*)alloc(512);   // gsum+gsumsq contiguous (EP_H1STAT o3)
  float* gsumsq = (float*)alloc(512);
  float* mu     = (float*)alloc(512);   // mu+rsig contiguous (GNB1 e1 / XGN-QGN mu)
  float* rsig   = (float*)alloc(512);
  float* cmsum  = (float*)alloc(1024);  // cmsum+cmsq contiguous (EP_YADDSTAT o3)
  float* cmsq   = (float*)alloc(1024);
  float* coefA  = (float*)alloc(1024);
  float* coefB  = (float*)alloc(1024);
  float* dGa    = (float*)alloc(2048);  // dGa+dBe+s1+s2 contiguous (GNB1 o3, wgrad red)
  float* dBe    = (float*)alloc(2048);
  float* s1     = (float*)alloc(512);
  float* s2     = (float*)alloc(512);
  float* pooled = (float*)alloc(16384);
  float* gate   = (float*)alloc(256);
  float* zc     = (float*)alloc(256);
  int*   dtf    = (int*)alloc(256);
  int*   mkf    = (int*)alloc(256);

  if (off > ws_size){
    k_report<<<1,64,0,stream>>>((u16*)d_out, (float)(ws_size>>20));
    return;
  }
  // adaptive: dedicated h1 buffer if ws allows (skips recompute GEMMs and
  // enables fused GNB1/GNB2/XGN/QGN paths). ws_size constant -> graph-safe.
  u16* h1p = nullptr;
  if (off + (size_t)HIDD*NTOT*2 <= ws_size)
    h1p = (u16*)alloc((size_t)HIDD*NTOT*2);       // +51.4 MB

  // ---- probes + param conversion ----
  k_detect_dtype<<<1,1,0,stream>>>((const u16*)x_in, dtf);
  k_detect_mask<<<1,1,0,stream>>>((const unsigned char*)mk_in, mkf);
  #define CVT(src,dst,n) k_cvt<<<((n)+255)/256,256,0,stream>>>(src,dst,(n),dtf)
  CVT(w1_in,  pw1,  131072);
  CVT(g_in,   pg,   512);
  CVT(b_in,   pb,   512);
  CVT(w2_in,  pw2,  131072);
  CVT(rw1_in, rw1f, 16384);
  CVT(rw2_in, rw2f, 16384);
  CVT(gw1_in, gw1f, 16384);
  CVT(gb1_in, gb1f, 64);
  CVT(gw2_in, gw2f, 64);
  CVT(gb2_in, gb2f, 1);
  CVT(rs_in,  rsf,  1);
  CVT(rm_in,  rmf,  256);
  CVT(rv_in,  rvf,  256);
  #undef CVT
  k_wcvt<<<512,256,0,stream>>>(pw1, wb1, 0,     HIDD, CC);
  k_wcvt<<<512,256,0,stream>>>(pw2, wb2, wb2T,  CC, HIDD);
  k_wcvt<<<64,256,0,stream>>>(rw1f, rwb1, rwb1T, C4, CC);
  k_wcvt<<<64,256,0,stream>>>(rw2f, rwb2, rwb2T, CC, C4);
  hipMemsetAsync(zc, 0, 8, stream);
  k_expand<<<392,256,0,stream>>>((const unsigned char*)mk_in, mkf, mfb, zc);

  // ---- 2 inner TTT steps ----
  for (int s=0; s<2; s++){
    const float* mfs = mfb + s*NTOT;
    u16* h1dst = h1p ? h1p : Ab;
    // h1 = w1 @ x  (+ fused GN stats)
    hipMemsetAsync(gsum, 0, 1024, stream);
    k_gemm_mfma<0,EP_H1STAT,1,0,2,0><<<dim3(392,4),256,0,stream>>>(wb1, x_in, h1dst, CC, dtf, 0,0,0,0,0, gsum, 0,0);
    k_gn_finalize<<<1,128,0,stream>>>(gsum, gsumsq, mu, rsig);
    hipMemsetAsync(cmsum, 0, 2048, stream);
    if (h1p){
      // y = w2 @ gelu(gn(h1)) + x — gn+gelu fused into X staging; 'a' never stored
      k_gemm_mfma<0,EP_YADDSTAT,0,1,2,1><<<dim3(392,2),256,0,stream>>>(wb2, h1p, ybuf, HIDD, dtf, 0, x_in, 0,0,0, cmsum, mu, pg);
    } else {
      k_gelu_fwd<1><<<BB*HIDD,256,0,stream>>>(Ab, Ab, mu, rsig, pg, pb);   // Ab = a (in place)
      k_gemm_mfma<0,EP_YADDSTAT,0,1,2,0><<<dim3(392,2),256,0,stream>>>(wb2, Ab, ybuf, HIDD, dtf, 0, x_in, 0,0,0, cmsum, 0,0);
    }
    k_y_finalize<<<1,256,0,stream>>>(cmsum, cmsq, rmf, rvf, coefA, coefB);
    // t1 = rw1 @ (y*mf); h = gelu(t1)
    k_gemm_mfma<1,EP_T1H,0,0,1,0><<<dim3(392,1),256,0,stream>>>(rwb1, ybuf, t1b, CC, dtf, mfs, 0,0,0, hb, 0, 0,0);
    // dY := g_rec = 2*(rec - y)*inv/D
    k_gemm_mfma<0,EP_DYREC,0,0,2,0><<<dim3(392,2),256,0,stream>>>(rwb2, hb, dY, C4, dtf, mfs, ybuf, zc+s, 0,0, 0, 0,0);
    // dT1 = (rw2^T @ g_rec) * gelu'(t1)
    k_gemm_mfma<0,EP_DT1,0,0,1,0><<<dim3(392,1),256,0,stream>>>(rwb2T, dY, hb, CC, dtf, 0, t1b, 0,0,0, 0, 0,0);
    // dY := mf*(rw1^T @ dT1) - g_rec + coefA + coefB*y
    k_gemm_mfma<0,EP_DYFIN,0,0,2,0><<<dim3(392,2),256,0,stream>>>(rwb1T, hb, dY, C4, dtf, mfs, ybuf, coefA, coefB, 0, 0, 0,0);
    // dW2[c,o] = sum_n dY[c,n]*a[o,n]   (part overlays ybuf: y dead)
    if (h1p){
      // a recomputed from h1 during Q staging (QGN=1, hoisted params)
      k_wgrad_mfma<0,0,1><<<dim3(32*SKW),256,0,stream>>>(dY, h1p, part, CC, HIDD, dtf, 4, 0, mu, 0, pg);
    } else {
      k_wgrad_mfma<0,0,0><<<dim3(32*SKW),256,0,stream>>>(dY, Ab, part, CC, HIDD, dtf, 4, 0,0,0,0);
    }
    k_wgrad_reduce<<<512,256,0,stream>>>(part, dW2, 131072);
    // dA = w2^T @ dY  (+ fused gn_bwd1 when h1 is resident)
    hipMemsetAsync(dGa, 0, 5120, stream);
    if (h1p){
      k_gemm_mfma<0,EP_GNB1,0,0,2,0><<<dim3(392,4),256,0,stream>>>(wb2T, dY, Ab, CC, dtf, 0, h1p, mu, pg, 0, dGa, 0,0);
      // dW1[o,c] = sum_n dH1[o,n]*x[c,n] with gn_bwd2 applied during staging
      k_wgrad_mfma<1,1,0><<<dim3(32*SKW),256,0,stream>>>(Ab, x_in, part, HIDD, CC, dtf, 8, h1p, mu, dGa, 0);
    } else {
      k_gemm_mfma<0,EP_STORE,0,0,2,0><<<dim3(392,4),256,0,stream>>>(wb2T, dY, Ab, CC, dtf, 0,0,0,0,0, 0, 0,0);
      k_gemm_mfma<0,EP_H1STAT,1,0,2,0><<<dim3(392,4),256,0,stream>>>(wb1, x_in, h1rc, CC, dtf, 0,0,0,0,0, gsum, 0,0);
      k_gn_bwd1<<<BB*HIDD,256,0,stream>>>(Ab, h1rc, mu, rsig, pg, pb, dGa, dBe, s1, s2);
      k_gn_bwd2<<<BB*HIDD,256,0,stream>>>(Ab, h1rc, mu, rsig, s1, s2);
      k_wgrad_mfma<1,0,0><<<dim3(32*SKW),256,0,stream>>>(Ab, x_in, part, HIDD, CC, dtf, 8, 0,0,0,0);
    }
    k_wgrad_reduce<<<512,256,0,stream>>>(part, dW1, 131072);
    // SGD update + refresh bf16 weight copies
    k_update<<<512,256,0,stream>>>(pw1, pw2, pg, pb, dW1, dW2, dGa, dBe);
    k_wcvt<<<512,256,0,stream>>>(pw1, wb1, 0,    HIDD, CC);
    k_wcvt<<<512,256,0,stream>>>(pw2, wb2, wb2T, CC, HIDD);
  }

  // ---- gate (x-only; hoisted before final GEMM for EP_OUT) ----
  k_pool<<<BB*CC,256,0,stream>>>(x_in, dtf, pooled);
  k_gate<<<BB,64,0,stream>>>(pooled, gw1f, gb1f, gw2f, gb2f, gate);

  // ---- final modifier forward with updated params ----
  hipMemsetAsync(gsum, 0, 1024, stream);
  k_gemm_mfma<0,EP_H1STAT,1,0,2,0><<<dim3(392,4),256,0,stream>>>(wb1, x_in, Ab, CC, dtf, 0,0,0,0,0, gsum, 0,0);
  k_gn_finalize<<<1,128,0,stream>>>(gsum, gsumsq, mu, rsig);
  // out = x + rsf*gate[b]*(w2 @ gelu(gn(h1)))  — gn+gelu fused into X staging,
  // residual merge fused into epilogue (no gelu pass, no k_out pass)
  k_gemm_mfma<0,EP_OUT,0,1,2,1><<<dim3(392,2),256,0,stream>>>(wb2, Ab, (u16*)d_out, HIDD, dtf, 0, x_in, gate, rsf, 0, 0, mu, pg);
}

// Round 10
// 1075.275 us; speedup vs baseline: 1.1593x; 1.0649x over previous
//
#include <hip/hip_runtime.h>
#include <math.h>

// SelfModifyingBlock (TTT inner loop) — round 14:
//  r13 (MT=2 aligned) + AST: the Y-GEMM's XGN staging already computes a =
//  gelu(gn(h1)) packed as bf16; store it to Ab (blockIdx.y==0 only) and run
//  dW2-wgrad with plain staging (QGN=0). Removes the 4x-redundant per-element
//  gelu recompute that made the dW2-wgrad dispatches 58% VALU-bound (~90us).

#define BB    16
#define CC    256
#define HWW   3136
#define NTOT  (BB*HWW)        // 50176
#define HIDD  512
#define NGRP  8
#define GMSZ  (64*HWW)        // 200704 elems per (b,group)
#define C4    64
#define LRATE 0.01f
#define SKW   32
#define CHUNK (NTOT/SKW)      // 1568
#define NV8   (HWW/8)         // 392 uint4 chunks per channel-row
#define FSTR  132             // fp32 LDS staging row stride (16B-aligned)

#define EP_STORE    0
#define EP_ADDFEAT  1
#define EP_T1H      2
#define EP_DYREC    3
#define EP_DT1      4
#define EP_DYFIN    5
#define EP_H1STAT   6
#define EP_YADDSTAT 7
#define EP_GNB1     8
#define EP_OUT      9

typedef unsigned short u16;
typedef __attribute__((ext_vector_type(8))) short bf16x8;
typedef __attribute__((ext_vector_type(4))) float f32x4;

__device__ __forceinline__ float bf2f(u16 u){
  return __uint_as_float(((unsigned)u)<<16);
}
__device__ __forceinline__ u16 f2bf(float f){
  unsigned u = __float_as_uint(f);
  u += 0x7FFFu + ((u>>16)&1u);
  return (u16)(u>>16);
}
// exact (gate only — tiny)
__device__ __forceinline__ float gelu_f(float x){
  return 0.5f*x*(1.0f+erff(x*0.70710678118654752f));
}
__device__ __forceinline__ float rcp_f(float x){ return __builtin_amdgcn_rcpf(x); }
// fast tanh-approx (max abs err ~1e-3 < bf16 quantum of O(1) values)
__device__ __forceinline__ float gelu_fast(float x){
  float x2 = x*x;
  float u = 0.7978845608f*x*fmaf(0.044715f, x2, 1.0f);
  float t = 1.0f - 2.0f*rcp_f(__expf(2.0f*u)+1.0f);
  return 0.5f*x*(1.0f+t);
}
__device__ __forceinline__ float gelu_g_fast(float x){
  float x2 = x*x;
  float u = 0.7978845608f*x*fmaf(0.044715f, x2, 1.0f);
  float t = 1.0f - 2.0f*rcp_f(__expf(2.0f*u)+1.0f);
  float du = 0.7978845608f*fmaf(0.134145f, x2, 1.0f);
  return fmaf(0.5f*x*(1.0f-t*t), du, 0.5f*(1.0f+t));
}
__device__ __forceinline__ float blk_sum(float v, float* sm){
  #pragma unroll
  for (int o=32;o>0;o>>=1) v += __shfl_down(v,o);
  if ((threadIdx.x & 63)==0) sm[threadIdx.x>>6] = v;
  __syncthreads();
  float r = sm[0]+sm[1]+sm[2]+sm[3];
  __syncthreads();
  return r;
}
__device__ __forceinline__ uint4 pack8(const ushort* e){
  uint4 v;
  v.x = (unsigned)e[0] | ((unsigned)e[1]<<16);
  v.y = (unsigned)e[2] | ((unsigned)e[3]<<16);
  v.z = (unsigned)e[4] | ((unsigned)e[5]<<16);
  v.w = (unsigned)e[6] | ((unsigned)e[7]<<16);
  return v;
}
__device__ __forceinline__ void up8(uint4 v, float* f){
  f[0]=bf2f((u16)(v.x&0xFFFFu)); f[1]=bf2f((u16)(v.x>>16));
  f[2]=bf2f((u16)(v.y&0xFFFFu)); f[3]=bf2f((u16)(v.y>>16));
  f[4]=bf2f((u16)(v.z&0xFFFFu)); f[5]=bf2f((u16)(v.z>>16));
  f[6]=bf2f((u16)(v.w&0xFFFFu)); f[7]=bf2f((u16)(v.w>>16));
}
__device__ __forceinline__ uint4 pk8(const float* f){
  uint4 v;
  v.x=(unsigned)f2bf(f[0])|((unsigned)f2bf(f[1])<<16);
  v.y=(unsigned)f2bf(f[2])|((unsigned)f2bf(f[3])<<16);
  v.z=(unsigned)f2bf(f[4])|((unsigned)f2bf(f[5])<<16);
  v.w=(unsigned)f2bf(f[6])|((unsigned)f2bf(f[7])<<16);
  return v;
}

// ---------- probes ----------
__global__ void k_detect_dtype(const u16* __restrict__ xs, int* flag){
  if (threadIdx.x || blockIdx.x) return;
  int plaus = 0;
  for (int i=0;i<256;i+=2){
    float f = bf2f(xs[i]);
    float a = fabsf(f);
    if (isfinite(f) && a < 32.0f && a > 1e-5f) plaus++;
  }
  *flag = (plaus >= 64) ? 1 : 0;   // 1 = bf16 inputs, 0 = fp32 inputs
}
__global__ void k_detect_mask(const unsigned char* __restrict__ m, int* flag){
  if (threadIdx.x || blockIdx.x) return;
  unsigned char mx=0; int nz0=0,nz1=0,nz2=0,nz3=0;
  for (int i=0;i<256;i++){
    unsigned char v=m[i]; if (v>mx) mx=v;
    if (v){ int r=i&3; if(r==0)nz0=1; else if(r==1)nz1=1; else if(r==2)nz2=1; else nz3=1; }
  }
  int f;
  if (mx<=1) f = (nz1|nz2|nz3) ? 0 : 1;
  else       f = (!nz0 && !nz1) ? 3 : 2;
  *flag=f;
}
__global__ void k_report(u16* out, float v){
  if (threadIdx.x==0 && blockIdx.x==0) out[0] = f2bf(v);
}

__global__ void k_cvt(const void* __restrict__ src, float* __restrict__ dst, int n,
                      const int* __restrict__ dtf){
  int i = blockIdx.x*256 + threadIdx.x;
  if (i>=n) return;
  if (*dtf) dst[i] = bf2f(((const u16*)src)[i]);
  else      dst[i] = ((const float*)src)[i];
}
__global__ void k_wcvt(const float* __restrict__ src, u16* __restrict__ d,
                       u16* __restrict__ dT, int R, int Cc){
  int i = blockIdx.x*256+threadIdx.x;
  if (i >= R*Cc) return;
  int r = i/Cc, c = i - r*Cc;
  u16 v = f2bf(src[i]);
  d[i] = v;
  if (dT) dT[(size_t)c*R + r] = v;
}

__global__ void k_expand(const unsigned char* __restrict__ mraw, const int* __restrict__ flag,
                         float* __restrict__ mf, float* __restrict__ zc){
  __shared__ float sm[4];
  int i = blockIdx.x*256 + threadIdx.x;     // grid 392 = 2*NTOT/256
  int f = *flag;
  float v;
  if (f==1)      v = (((const int*)mraw)[i] != 0) ? 1.f : 0.f;
  else if (f==0) v = (mraw[i] != 0) ? 1.f : 0.f;
  else if (f==2) v = (((const u16*)mraw)[i] != 0) ? 1.f : 0.f;
  else           v = (((const float*)mraw)[i] != 0.f) ? 1.f : 0.f;
  mf[i] = v;
  float S = blk_sum(1.f - v, sm);
  if (threadIdx.x==0) atomicAdd(&zc[blockIdx.x/196], S);
}

// ---------- MFMA GEMM: Out[m,n] = sum_k A[m,k]*X[k,n] ----------
// MT: 64*MT m-rows per block. LDS stride 40 u16 (80B, 16B-aligned).
// XGN=1: apply gn+gelu_fast during X staging (X = h1; xmu = mu w/ rsig@+128,
// xpg = pg w/ pb@+512), hoisted param loads.
// AST=1 (with XGN): store the staged a values to o2 (blockIdx.y==0 blocks only).
template<int MASKX,int EPI,int XDYN,int E0DYN,int MT,int XGN,int AST>
__global__ __launch_bounds__(256) void k_gemm_mfma(
    const u16* __restrict__ A, const void* __restrict__ Xv, u16* __restrict__ Out,
    int K, const int* __restrict__ xdt, const float* __restrict__ mf,
    const void* __restrict__ e0, const float* __restrict__ e1,
    const float* __restrict__ e2, u16* __restrict__ o2, float* __restrict__ o3,
    const float* __restrict__ xmu, const float* __restrict__ xpg)
{
  constexpr int MROWS = 64*MT;
  constexpr int NMI   = 4*MT;
  __shared__ __align__(16) u16 Ws[MROWS*40];
  __shared__ __align__(16) u16 Xs[128*40];
  const int t = threadIdx.x;
  const int w = t >> 6, lane = t & 63;
  const int col = lane & 15, quad = lane >> 4;
  const int M = (int)gridDim.y * MROWS;
  const int m0 = blockIdx.y * MROWS, n0 = blockIdx.x << 7;
  const int isbx = XDYN ? *xdt : 1;
  const u16*   Xb = (const u16*)Xv;
  const float* Xf = (const float*)Xv;
  const int wrow = t >> 2, wkq = (t & 3) * 8;
  const int xn   = 2*(t & 63);
  const int xq   = t >> 6;
  const int gn0  = n0 + xn;
  const int xb_  = gn0 / HWW;
  const int xs_  = gn0 - xb_*HWW;
  const bool do_ast = AST && (blockIdx.y==0);

  f32x4 acc[NMI][2];
  #pragma unroll
  for (int i=0;i<NMI;i++){
    #pragma unroll
    for (int j=0;j<2;j++) acc[i][j] = (f32x4)(0.0f);
  }

  for (int k0=0; k0<K; k0+=32){
    if (MT==2){
      const u16* ap = A + (size_t)(m0 + (t>>1))*K + k0 + (t&1)*16;
      *(uint4*)(Ws + (t>>1)*40 + (t&1)*16)     = *(const uint4*)ap;
      *(uint4*)(Ws + (t>>1)*40 + (t&1)*16 + 8) = *(const uint4*)(ap+8);
    } else {
      uint4 v = *(const uint4*)(A + (size_t)(m0+wrow)*K + k0 + wkq);
      *(uint4*)(Ws + wrow*40 + wkq) = v;
    }
    {
      ushort e[16];
      size_t base = ((size_t)xb_*K + k0 + xq*8)*HWW + xs_;
      if (isbx){
        if (XGN){
          // ob is 8-aligned and the 8-block never straddles a 64-group
          const int ob = k0 + xq*8;
          const int bg = xb_*NGRP + (ob>>6);
          const float mu_ = xmu[bg], rs_ = xmu[128+bg];
          float4 ga0 = *(const float4*)(xpg+ob);
          float4 ga1 = *(const float4*)(xpg+ob+4);
          float4 be0 = *(const float4*)(xpg+512+ob);
          float4 be1 = *(const float4*)(xpg+512+ob+4);
          float ga[8] = {ga0.x,ga0.y,ga0.z,ga0.w,ga1.x,ga1.y,ga1.z,ga1.w};
          float be[8] = {be0.x,be0.y,be0.z,be0.w,be1.x,be1.y,be1.z,be1.w};
          #pragma unroll
          for (int j=0;j<8;j++){
            unsigned v = *(const unsigned*)(Xb + base + (size_t)j*HWW);
            float f0 = bf2f((u16)(v & 0xFFFFu));
            float f1 = bf2f((u16)(v >> 16));
            f0 = gelu_fast(fmaf((f0-mu_)*rs_, ga[j], be[j]));
            f1 = gelu_fast(fmaf((f1-mu_)*rs_, ga[j], be[j]));
            e[j]   = f2bf(f0);
            e[8+j] = f2bf(f1);
            if (AST){
              if (do_ast){
                unsigned av = (unsigned)e[j] | ((unsigned)e[8+j]<<16);
                *(unsigned*)(o2 + base + (size_t)j*HWW) = av;
              }
            }
          }
        } else {
          #pragma unroll
          for (int j=0;j<8;j++){
            unsigned v = *(const unsigned*)(Xb + base + (size_t)j*HWW);
            e[j]   = (ushort)(v & 0xFFFFu);
            e[8+j] = (ushort)(v >> 16);
          }
        }
      } else {
        #pragma unroll
        for (int j=0;j<8;j++){
          float2 f = *(const float2*)(Xf + base + (size_t)j*HWW);
          e[j]   = f2bf(f.x);
          e[8+j] = f2bf(f.y);
        }
      }
      if (MASKX){
        if (mf[gn0]   == 0.f){
          #pragma unroll
          for (int j=0;j<8;j++) e[j] = 0;
        }
        if (mf[gn0+1] == 0.f){
          #pragma unroll
          for (int j=0;j<8;j++) e[8+j] = 0;
        }
      }
      *(uint4*)(Xs + xn*40     + xq*8) = pack8(e);
      *(uint4*)(Xs + (xn+1)*40 + xq*8) = pack8(e+8);
    }
    __syncthreads();
    bf16x8 bfr[2];
    #pragma unroll
    for (int nj=0;nj<2;nj++)
      bfr[nj] = *(const bf16x8*)(Xs + (w*32+nj*16+col)*40 + quad*8);
    #pragma unroll
    for (int mi=0;mi<NMI;mi++){
      bf16x8 af = *(const bf16x8*)(Ws + (mi*16+col)*40 + quad*8);
      acc[mi][0] = __builtin_amdgcn_mfma_f32_16x16x32_bf16(af, bfr[0], acc[mi][0], 0,0,0);
      acc[mi][1] = __builtin_amdgcn_mfma_f32_16x16x32_bf16(af, bfr[1], acc[mi][1], 0,0,0);
    }
    __syncthreads();
  }
  // ---- unified vectorized epilogue (Ws -> sred scratch, Xs -> fp32 staging) ----
  const int isb0 = E0DYN ? *xdt : 1;
  float* fst  = (float*)Xs;            // 16 x FSTR fp32 = 8448B <= 10240B
  float* sred = (float*)Ws;            // reduction scratch (<= 1056B)
  const int row16 = t >> 4;            // 0..15
  const int cb    = (t & 15) * 8;      // 0..120
  const int nb8   = n0 + cb;
  const int b8    = nb8 / HWW;         // all 8 cols same b (HWW%8==0, cb 8-aligned)
  const int sb8   = nb8 - b8*HWW;
  const int bA    = n0 / HWW, bB = (n0+127)/HWW;
  const int gbase = m0 >> 6;

  if (EPI==EP_H1STAT){ if (t < 4*MT) sred[t]=0.f; }
  if (EPI==EP_GNB1){ if (t < 4*MT) sred[2*NMI*16 + t]=0.f; }
  if (EPI==EP_H1STAT||EPI==EP_GNB1) __syncthreads();

  float dscale=0.f, gmul=0.f;
  if (EPI==EP_DYREC) dscale = 2.0f / (e1[0]*(float)CC + 1e-8f);
  if (EPI==EP_OUT)   gmul = e2[0]*e1[b8];
  // per-(group,b-slot) register accumulators (H1STAT: sum/sq; GNB1: s1/s2)
  float hs0[MT], hq0[MT], hs1[MT], hq1[MT];
  #pragma unroll
  for (int i=0;i<MT;i++){ hs0[i]=0.f; hq0[i]=0.f; hs1[i]=0.f; hq1[i]=0.f; }

  #pragma unroll
  for (int mi=0;mi<NMI;mi++){
    #pragma unroll
    for (int nj=0;nj<2;nj++){
      #pragma unroll
      for (int r=0;r<4;r++)
        fst[(quad*4+r)*FSTR + w*32 + nj*16 + col] = acc[mi][nj][r];
    }
    __syncthreads();
    const int m = m0 + mi*16 + row16;
    const size_t oidx = ((size_t)b8*M + m)*HWW + sb8;
    float v[8];
    {
      const float* frow = fst + row16*FSTR + cb;
      float4 p0 = *(const float4*)frow;
      float4 p1 = *(const float4*)(frow+4);
      v[0]=p0.x; v[1]=p0.y; v[2]=p0.z; v[3]=p0.w;
      v[4]=p1.x; v[5]=p1.y; v[6]=p1.z; v[7]=p1.w;
    }

    if (EPI==EP_STORE){
      *(uint4*)(Out+oidx) = pk8(v);
    }
    else if (EPI==EP_ADDFEAT){
      float xv[8];
      if (isb0) up8(*(const uint4*)((const u16*)e0+oidx), xv);
      else {
        float4 a0 = *(const float4*)((const float*)e0+oidx);
        float4 a1 = *(const float4*)((const float*)e0+oidx+4);
        xv[0]=a0.x; xv[1]=a0.y; xv[2]=a0.z; xv[3]=a0.w;
        xv[4]=a1.x; xv[5]=a1.y; xv[6]=a1.z; xv[7]=a1.w;
      }
      #pragma unroll
      for (int j=0;j<8;j++) v[j] += xv[j];
      *(uint4*)(Out+oidx) = pk8(v);
    }
    else if (EPI==EP_T1H){
      *(uint4*)(Out+oidx) = pk8(v);
      float gv[8];
      #pragma unroll
      for (int j=0;j<8;j++) gv[j] = gelu_fast(v[j]);
      *(uint4*)(o2+oidx) = pk8(gv);
    }
    else if (EPI==EP_DYREC){
      float yv[8], mfv[8];
      up8(*(const uint4*)((const u16*)e0+oidx), yv);
      float4 f0 = *(const float4*)(mf+nb8);
      float4 f1 = *(const float4*)(mf+nb8+4);
      mfv[0]=f0.x; mfv[1]=f0.y; mfv[2]=f0.z; mfv[3]=f0.w;
      mfv[4]=f1.x; mfv[5]=f1.y; mfv[6]=f1.z; mfv[7]=f1.w;
      #pragma unroll
      for (int j=0;j<8;j++) v[j] = (v[j]-yv[j])*(1.0f-mfv[j])*dscale;
      *(uint4*)(Out+oidx) = pk8(v);
    }
    else if (EPI==EP_DT1){
      float tv[8];
      up8(*(const uint4*)((const u16*)e0+oidx), tv);
      #pragma unroll
      for (int j=0;j<8;j++) v[j] = v[j]*gelu_g_fast(tv[j]);
      *(uint4*)(Out+oidx) = pk8(v);
    }
    else if (EPI==EP_DYFIN){
      float yv[8], dv[8], mfv[8];
      up8(*(const uint4*)((const u16*)e0+oidx), yv);
      up8(*(const uint4*)(Out+oidx), dv);
      float4 f0 = *(const float4*)(mf+nb8);
      float4 f1 = *(const float4*)(mf+nb8+4);
      mfv[0]=f0.x; mfv[1]=f0.y; mfv[2]=f0.z; mfv[3]=f0.w;
      mfv[4]=f1.x; mfv[5]=f1.y; mfv[6]=f1.z; mfv[7]=f1.w;
      const float c1 = e1[m], c2 = e2[m];
      #pragma unroll
      for (int j=0;j<8;j++) v[j] = mfv[j]*v[j] - dv[j] + c1 + c2*yv[j];
      *(uint4*)(Out+oidx) = pk8(v);
    }
    else if (EPI==EP_H1STAT){
      *(uint4*)(Out+oidx) = pk8(v);
      float s=0.f, q=0.f;
      #pragma unroll
      for (int j=0;j<8;j++){ s += v[j]; q = fmaf(v[j],v[j],q); }
      const bool inA = (b8==bA);
      hs0[mi>>2] += inA ? s : 0.f;  hq0[mi>>2] += inA ? q : 0.f;
      hs1[mi>>2] += inA ? 0.f : s;  hq1[mi>>2] += inA ? 0.f : q;
    }
    else if (EPI==EP_YADDSTAT){
      float xv[8];
      if (isb0) up8(*(const uint4*)((const u16*)e0+oidx), xv);
      else {
        float4 a0 = *(const float4*)((const float*)e0+oidx);
        float4 a1 = *(const float4*)((const float*)e0+oidx+4);
        xv[0]=a0.x; xv[1]=a0.y; xv[2]=a0.z; xv[3]=a0.w;
        xv[4]=a1.x; xv[5]=a1.y; xv[6]=a1.z; xv[7]=a1.w;
      }
      float s=0.f, q=0.f;
      #pragma unroll
      for (int j=0;j<8;j++){
        v[j] += xv[j];
        s += v[j]; q = fmaf(v[j],v[j],q);
      }
      *(uint4*)(Out+oidx) = pk8(v);
      #pragma unroll
      for (int o=1;o<16;o<<=1){ s += __shfl_xor(s,o); q += __shfl_xor(q,o); }
      if ((t&15)==0){
        sred[mi*16+row16]          = s;
        sred[NMI*16 + mi*16+row16] = q;
      }
    }
    else if (EPI==EP_GNB1){
      float hv[8];
      up8(*(const uint4*)((const u16*)e0+oidx), hv);
      const int gcur = gbase + (mi>>2);
      const float muT = e1[b8*NGRP+gcur], rT = e1[128+b8*NGRP+gcur];
      const float go = e2[m], beo = e2[HIDD+m];
      float dB=0.f, dG=0.f, sS=0.f, sQ=0.f;
      #pragma unroll
      for (int j=0;j<8;j++){
        float hn   = (hv[j]-muT)*rT;
        float ghat = fmaf(hn, go, beo);
        float dgh  = v[j]*gelu_g_fast(ghat);
        float dhn  = dgh*go;
        v[j] = dhn;
        dB += dgh; dG = fmaf(dgh,hn,dG);
        sS += dhn; sQ = fmaf(dhn,hn,sQ);
      }
      *(uint4*)(Out+oidx) = pk8(v);
      #pragma unroll
      for (int o=1;o<16;o<<=1){ dB += __shfl_xor(dB,o); dG += __shfl_xor(dG,o); }
      if ((t&15)==0){
        sred[mi*16+row16]          = dB;
        sred[NMI*16 + mi*16+row16] = dG;
      }
      const bool inA = (b8==bA);
      hs0[mi>>2] += inA ? sS : 0.f;  hq0[mi>>2] += inA ? sQ : 0.f;
      hs1[mi>>2] += inA ? 0.f : sS;  hq1[mi>>2] += inA ? 0.f : sQ;
    }
    else if (EPI==EP_OUT){
      float xv[8];
      if (isb0){
        up8(*(const uint4*)((const u16*)e0+oidx), xv);
        #pragma unroll
        for (int j=0;j<8;j++) v[j] = xv[j] + gmul*v[j];
        *(uint4*)(Out+oidx) = pk8(v);
      } else {
        float4 a0 = *(const float4*)((const float*)e0+oidx);
        float4 a1 = *(const float4*)((const float*)e0+oidx+4);
        float4 r0, r1;
        r0.x = a0.x + gmul*v[0]; r0.y = a0.y + gmul*v[1];
        r0.z = a0.z + gmul*v[2]; r0.w = a0.w + gmul*v[3];
        r1.x = a1.x + gmul*v[4]; r1.y = a1.y + gmul*v[5];
        r1.z = a1.z + gmul*v[6]; r1.w = a1.w + gmul*v[7];
        *(float4*)((float*)Out+oidx)   = r0;
        *(float4*)((float*)Out+oidx+4) = r1;
      }
    }
    __syncthreads();
  }

  // cross-wave (group,b) reductions for H1STAT / GNB1
  if (EPI==EP_H1STAT || EPI==EP_GNB1){
    const int soff = (EPI==EP_GNB1) ? 2*NMI*16 : 0;
    #pragma unroll
    for (int g2=0; g2<MT; g2++){
      float a0=hs0[g2], c0=hq0[g2], a1=hs1[g2], c1=hq1[g2];
      #pragma unroll
      for (int o=1;o<64;o<<=1){
        a0 += __shfl_xor(a0,o); c0 += __shfl_xor(c0,o);
        a1 += __shfl_xor(a1,o); c1 += __shfl_xor(c1,o);
      }
      if (lane==0){
        atomicAdd(&sred[soff+g2*4+0], a0);
        atomicAdd(&sred[soff+g2*4+1], c0);
        atomicAdd(&sred[soff+g2*4+2], a1);
        atomicAdd(&sred[soff+g2*4+3], c1);
      }
    }
    __syncthreads();
  }

  // final global reductions
  if (EPI==EP_H1STAT){
    if (t==0){
      #pragma unroll
      for (int g2=0; g2<MT; g2++){
        atomicAdd(&o3[bA*NGRP+gbase+g2],     sred[g2*4+0]);
        atomicAdd(&o3[128+bA*NGRP+gbase+g2], sred[g2*4+1]);
      }
    }
    if (t==1 && bB!=bA){
      #pragma unroll
      for (int g2=0; g2<MT; g2++){
        atomicAdd(&o3[bB*NGRP+gbase+g2],     sred[g2*4+2]);
        atomicAdd(&o3[128+bB*NGRP+gbase+g2], sred[g2*4+3]);
      }
    }
  }
  if (EPI==EP_YADDSTAT){
    if (t < NMI*16){
      atomicAdd(&o3[m0+t],    sred[t]);
      atomicAdd(&o3[CC+m0+t], sred[NMI*16+t]);
    }
  }
  if (EPI==EP_GNB1){
    if (t < NMI*16){
      atomicAdd(&o3[m0+t],     sred[NMI*16+t]);   // dGa
      atomicAdd(&o3[512+m0+t], sred[t]);          // dBe
    }
    if (t==NMI*16){
      #pragma unroll
      for (int g2=0; g2<MT; g2++){
        atomicAdd(&o3[1024+bA*NGRP+gbase+g2], sred[2*NMI*16+g2*4+0]);  // s1
        atomicAdd(&o3[1152+bA*NGRP+gbase+g2], sred[2*NMI*16+g2*4+1]);  // s2
      }
    }
    if (t==NMI*16+1 && bB!=bA){
      #pragma unroll
      for (int g2=0; g2<MT; g2++){
        atomicAdd(&o3[1024+bB*NGRP+gbase+g2], sred[2*NMI*16+g2*4+2]);
        atomicAdd(&o3[1152+bB*NGRP+gbase+g2], sred[2*NMI*16+g2*4+3]);
      }
    }
  }
}

// ---------- MFMA weight-grad: flattened grid, XCD-chunk swizzle ----------
// GNB2=1: apply GN-backward stage-2 (dH1 = r*(dhn - a1 - hn*a2)) while staging P.
// QGN=1:  apply gn+gelu_fast while staging Q (kept for fallback flexibility).
template<int QDYN, int GNB2, int QGN>
__global__ __launch_bounds__(256) void k_wgrad_mfma(
    const u16* __restrict__ P, const void* __restrict__ Qv, float* __restrict__ part,
    int CHP, int CHQ, const int* __restrict__ xdt, int ntx,
    const u16* __restrict__ h1, const float* __restrict__ musig,
    const float* __restrict__ red, const float* __restrict__ qpg)
{
  __shared__ __align__(16) u16 Ps[64*40];
  __shared__ __align__(16) u16 Qs[64*40];
  const int f = blockIdx.x;
  const int j = f >> 3;
  const int sk = (f & 7) + ((j >> 5) << 3);
  const int tile = j & 31;
  const int ty = tile / ntx;
  const int m0 = (tile - ty*ntx) << 6;
  const int n0 = ty << 6;
  const int t = threadIdx.x;
  const int w = t >> 6, lane = t & 63;
  const int col = lane & 15, quad = lane >> 4;
  const int isbq = QDYN ? *xdt : 1;
  const u16*   Qb = (const u16*)Qv;
  const float* Qf = (const float*)Qv;
  const int srow = (t & 127) >> 1;
  const int ssq  = ((t & 127) & 1) * 16;
  // QGN: per-thread row params, k-loop invariant
  float ga_q = 0.f, be_q = 0.f;
  if (QGN && t >= 128){
    ga_q = qpg[n0+srow];
    be_q = qpg[512+n0+srow];
  }
  f32x4 acc[2][2];
  #pragma unroll
  for (int i=0;i<2;i++){
    #pragma unroll
    for (int jj=0;jj<2;jj++) acc[i][jj] = (f32x4)(0.0f);
  }
  const int mbase = (w & 1)*32, nbase = (w >> 1)*32;

  for (int kb = sk*CHUNK; kb < sk*CHUNK + CHUNK; kb += 32){
    const int b = kb / HWW;
    const int s = kb - b*HWW;
    if (t < 128){
      size_t off = ((size_t)b*CHP + m0+srow)*HWW + s + ssq;
      uint4 v0 = *(const uint4*)(P + off);
      uint4 v1 = *(const uint4*)(P + off + 8);
      if (GNB2){
        const int bg = b*NGRP + (m0>>6);
        const float mu_ = musig[bg], r_ = musig[128+bg];
        const float a1 = red[1024+bg]*(1.0f/GMSZ);
        const float a2 = red[1152+bg]*(1.0f/GMSZ);
        uint4 h0 = *(const uint4*)(h1 + off);
        uint4 h1v = *(const uint4*)(h1 + off + 8);
        float fd[8], fh[8];
        up8(v0, fd); up8(h0, fh);
        #pragma unroll
        for (int q2=0;q2<8;q2++){ float hn=(fh[q2]-mu_)*r_; fd[q2]=r_*(fd[q2]-a1-hn*a2); }
        v0 = pk8(fd);
        up8(v1, fd); up8(h1v, fh);
        #pragma unroll
        for (int q2=0;q2<8;q2++){ float hn=(fh[q2]-mu_)*r_; fd[q2]=r_*(fd[q2]-a1-hn*a2); }
        v1 = pk8(fd);
      }
      *(uint4*)(Ps + srow*40 + ssq)     = v0;
      *(uint4*)(Ps + srow*40 + ssq + 8) = v1;
    } else {
      size_t off = ((size_t)b*CHQ + n0+srow)*HWW + s + ssq;
      if (isbq){
        uint4 v0 = *(const uint4*)(Qb + off);
        uint4 v1 = *(const uint4*)(Qb + off + 8);
        if (QGN){
          const int bg = b*NGRP + ((n0+srow)>>6);
          const float mu_ = musig[bg], rs_ = musig[128+bg];
          float fq[8];
          up8(v0, fq);
          #pragma unroll
          for (int q2=0;q2<8;q2++) fq[q2] = gelu_fast(fmaf((fq[q2]-mu_)*rs_, ga_q, be_q));
          v0 = pk8(fq);
          up8(v1, fq);
          #pragma unroll
          for (int q2=0;q2<8;q2++) fq[q2] = gelu_fast(fmaf((fq[q2]-mu_)*rs_, ga_q, be_q));
          v1 = pk8(fq);
        }
        *(uint4*)(Qs + srow*40 + ssq)     = v0;
        *(uint4*)(Qs + srow*40 + ssq + 8) = v1;
      } else {
        ushort e[16];
        #pragma unroll
        for (int g2=0; g2<4; g2++){
          float4 ff = *(const float4*)(Qf + off + g2*4);
          e[g2*4+0]=f2bf(ff.x); e[g2*4+1]=f2bf(ff.y); e[g2*4+2]=f2bf(ff.z); e[g2*4+3]=f2bf(ff.w);
        }
        *(uint4*)(Qs + srow*40 + ssq)     = pack8(e);
        *(uint4*)(Qs + srow*40 + ssq + 8) = pack8(e+8);
      }
    }
    __syncthreads();
    bf16x8 pa[2], qb[2];
    #pragma unroll
    for (int a=0;a<2;a++)
      pa[a] = *(const bf16x8*)(Ps + (mbase + a*16 + col)*40 + quad*8);
    #pragma unroll
    for (int bb=0;bb<2;bb++)
      qb[bb] = *(const bf16x8*)(Qs + (nbase + bb*16 + col)*40 + quad*8);
    #pragma unroll
    for (int a=0;a<2;a++){
      #pragma unroll
      for (int bb=0;bb<2;bb++)
        acc[a][bb] = __builtin_amdgcn_mfma_f32_16x16x32_bf16(pa[a], qb[bb], acc[a][bb], 0,0,0);
    }
    __syncthreads();
  }
  float* dst = part + (size_t)sk*CHP*CHQ;
  #pragma unroll
  for (int a=0;a<2;a++){
    #pragma unroll
    for (int bb=0;bb<2;bb++){
      #pragma unroll
      for (int r=0;r<4;r++){
        const int m = m0 + mbase + a*16 + quad*4 + r;
        const int n = n0 + nbase + bb*16 + col;
        dst[(size_t)m*CHQ + n] = acc[a][bb][r];
      }
    }
  }
}
__global__ void k_wgrad_reduce(const float* __restrict__ part, float* __restrict__ dW, int n){
  int i = blockIdx.x*256+threadIdx.x;
  if (i>=n) return;
  float s=0;
  #pragma unroll
  for (int k=0;k<SKW;k++) s += part[(size_t)k*n + i];
  dW[i]=s;
}

// ---------- GroupNorm fwd finalize + gelu (gelu pass = fallback only) ----------
__global__ void k_gn_finalize(const float* gsum, const float* gsumsq, float* mu, float* rsig){
  int i = threadIdx.x; if (i>=BB*NGRP) return;
  float m = gsum[i]*(1.0f/GMSZ);
  float v = gsumsq[i]*(1.0f/GMSZ) - m*m;
  v = fmaxf(v, 0.0f);
  mu[i]=m; rsig[i]=rsqrtf(v+1e-5f);
}
template<int FAST>
__global__ void k_gelu_fwd(const u16* __restrict__ src, u16* __restrict__ dst,
    const float* __restrict__ mu, const float* __restrict__ rsig,
    const float* __restrict__ pg, const float* __restrict__ pb){
  int bo = blockIdx.x;
  int b = bo>>9, o = bo&511, bg = b*NGRP + (o>>6);
  float m = mu[bg], r = rsig[bg], g = pg[o], be = pb[o];
  const uint4* ps = (const uint4*)(src + (size_t)bo*HWW);
  uint4* pd = (uint4*)(dst + (size_t)bo*HWW);
  for (int i=threadIdx.x;i<NV8;i+=256){
    float f[8]; up8(ps[i], f);
    #pragma unroll
    for (int j=0;j<8;j++){
      float gh = fmaf((f[j]-m)*r, g, be);
      f[j] = FAST ? gelu_fast(gh) : gelu_f(gh);
    }
    pd[i] = pk8(f);
  }
}

// ---------- y channel moments finalize ----------
__global__ void k_y_finalize(const float* cmsum, const float* cmsq,
    const float* rmf, const float* rvf, float* coefA, float* coefB){
  int c = threadIdx.x; if (c>=CC) return;
  float cm = cmsum[c]*(1.0f/NTOT);
  float cv = (cmsq[c] - (float)NTOT*cm*cm)*(1.0f/(NTOT-1));
  float rvp = rvf[c] + 1e-8f;
  float gcm = 0.2f*(cm - rmf[c])*(1.0f/CC);
  float gcv = 0.2f*(cv/rvp - 1.0f)/(rvp*(float)CC);
  coefA[c] = gcm*(1.0f/NTOT) - 2.0f*gcv*cm*(1.0f/(NTOT-1));
  coefB[c] = 2.0f*gcv*(1.0f/(NTOT-1));
}

// ---------- GroupNorm backward (fallback path only, when !h1p) ----------
__global__ void k_gn_bwd1(u16* __restrict__ dA, const u16* __restrict__ h1,
    const float* mu, const float* rsig, const float* pg, const float* pb,
    float* dGa, float* dBe, float* s1, float* s2){
  __shared__ float sm[4];
  int bo = blockIdx.x;
  int b = bo>>9, o = bo&511, bg = b*NGRP + (o>>6);
  float m = mu[bg], r = rsig[bg], g = pg[o], be = pb[o];
  uint4* pa = (uint4*)(dA + (size_t)bo*HWW);
  const uint4* ph = (const uint4*)(h1 + (size_t)bo*HWW);
  float sb=0, sg=0, t1=0, t2=0;
  for (int i=threadIdx.x;i<NV8;i+=256){
    float fa[8], fh[8]; up8(pa[i], fa); up8(ph[i], fh);
    #pragma unroll
    for (int j=0;j<8;j++){
      float hn = (fh[j]-m)*r;
      float ghat = fmaf(hn,g,be);
      float dgh = fa[j]*gelu_g_fast(ghat);
      float dhn = dgh*g;
      fa[j] = dhn;
      sb += dgh; sg = fmaf(dgh,hn,sg); t1 += dhn; t2 = fmaf(dhn,hn,t2);
    }
    pa[i] = pk8(fa);
  }
  float S;
  S = blk_sum(sb,sm); if (threadIdx.x==0) atomicAdd(&dBe[o], S);
  S = blk_sum(sg,sm); if (threadIdx.x==0) atomicAdd(&dGa[o], S);
  S = blk_sum(t1,sm); if (threadIdx.x==0) atomicAdd(&s1[bg], S);
  S = blk_sum(t2,sm); if (threadIdx.x==0) atomicAdd(&s2[bg], S);
}
__global__ void k_gn_bwd2(u16* __restrict__ dA, const u16* __restrict__ h1,
    const float* mu, const float* rsig, const float* s1, const float* s2){
  int bo = blockIdx.x;
  int b = bo>>9, o = bo&511, bg = b*NGRP + (o>>6);
  float m = mu[bg], r = rsig[bg];
  float a1 = s1[bg]*(1.0f/GMSZ), a2 = s2[bg]*(1.0f/GMSZ);
  uint4* pa = (uint4*)(dA + (size_t)bo*HWW);
  const uint4* ph = (const uint4*)(h1 + (size_t)bo*HWW);
  for (int i=threadIdx.x;i<NV8;i+=256){
    float fa[8], fh[8]; up8(pa[i], fa); up8(ph[i], fh);
    #pragma unroll
    for (int j=0;j<8;j++){
      float hn = (fh[j]-m)*r;
      fa[j] = r*(fa[j] - a1 - hn*a2);
    }
    pa[i] = pk8(fa);
  }
}

__global__ void k_update(float* pw1, float* pw2, float* pg, float* pb,
    const float* dW1, const float* dW2, const float* dGa, const float* dBe){
  int i = blockIdx.x*256+threadIdx.x;
  if (i < HIDD*CC){ pw1[i] -= LRATE*dW1[i]; pw2[i] -= LRATE*dW2[i]; }
  if (i < HIDD){ pg[i] -= LRATE*dGa[i]; pb[i] -= LRATE*dBe[i]; }
}

// ---------- gate ----------
__global__ void k_pool(const void* __restrict__ xv, const int* __restrict__ dtf, float* pooled){
  __shared__ float sm[4];
  int bc = blockIdx.x;
  int isb = *dtf;
  float s=0;
  if (isb){
    const uint4* p = (const uint4*)((const u16*)xv + (size_t)bc*HWW);
    for (int i=threadIdx.x;i<NV8;i+=256){
      float f[8]; up8(p[i], f);
      #pragma unroll
      for (int j=0;j<8;j++) s+=f[j];
    }
  } else {
    const float4* p = (const float4*)((const float*)xv + (size_t)bc*HWW);
    for (int i=threadIdx.x;i<HWW/4;i+=256){
      float4 f = p[i];
      s += f.x+f.y+f.z+f.w;
    }
  }
  float S = blk_sum(s,sm);
  if (threadIdx.x==0) pooled[bc]=S*(1.0f/HWW);
}
__global__ void k_gate(const float* __restrict__ pooled, const float* __restrict__ gw1,
    const float* __restrict__ gb1, const float* __restrict__ gw2, const float* __restrict__ gb2,
    float* gate){
  int b = blockIdx.x, j = threadIdx.x;      // 64 threads = 1 wave
  float acc = gb1[j];
  const float* pr = pooled + b*CC;
  for (int c=0;c<CC;c++) acc = fmaf(pr[c], gw1[j*CC+c], acc);
  float v = gelu_f(acc)*gw2[j];
  #pragma unroll
  for (int o=32;o>0;o>>=1) v += __shfl_down(v,o);
  if (j==0) gate[b] = 1.0f/(1.0f+expf(-(v+gb2[0])));
}

// =======================================================================
extern "C" void kernel_launch(void* const* d_in, const int* in_sizes, int n_in,
                              void* d_out, int out_size, void* d_ws, size_t ws_size,
                              hipStream_t stream)
{
  const void* x_in   = d_in[0];
  const void* w1_in  = d_in[1];
  const void* g_in   = d_in[2];
  const void* b_in   = d_in[3];
  const void* w2_in  = d_in[4];
  const void* rw1_in = d_in[5];
  const void* rw2_in = d_in[6];
  const void* gw1_in = d_in[7];
  const void* gb1_in = d_in[8];
  const void* gw2_in = d_in[9];
  const void* gb2_in = d_in[10];
  const void* rs_in  = d_in[11];
  const void* rm_in  = d_in[12];
  const void* rv_in  = d_in[13];
  const void* mk_in  = d_in[14];
  (void)in_sizes; (void)n_in; (void)out_size;

  char* base = (char*)d_ws;
  size_t off = 0;
  auto alloc = [&](size_t bytes)->char*{
    char* p = base+off; off = (off+bytes+255)&~(size_t)255; return p;
  };
  u16* ybuf = (u16*)alloc((size_t)CC*NTOT*2);     // 25.7 MB  y / h1rc-lo / wgrad part
  u16* dY   = (u16*)alloc((size_t)CC*NTOT*2);     // 25.7 MB  dY / h1rc-hi
  u16* Ab   = (u16*)alloc((size_t)HIDD*NTOT*2);   // 51.4 MB  a (AST) -> dhn / fallback a
  u16* t1b  = (u16*)alloc((size_t)C4*NTOT*2);     // 6.4 MB   t1
  u16* hb   = (u16*)alloc((size_t)C4*NTOT*2);     // 6.4 MB   h / dT1
  u16* h1rc = ybuf;                               // recompute overlay (fallback path)
  float* part = (float*)ybuf;                     // SKW*131072*4 = 16.8MB <= ybuf
  float* mfb  = (float*)alloc((size_t)2*NTOT*4);
  float* pw1  = (float*)alloc(131072*4);
  float* pw2  = (float*)alloc(131072*4);
  float* dW1  = (float*)alloc(131072*4);
  float* dW2  = (float*)alloc(131072*4);
  u16* wb1   = (u16*)alloc(131072*2);
  u16* wb2   = (u16*)alloc(131072*2);
  u16* wb2T  = (u16*)alloc(131072*2);
  u16* rwb1  = (u16*)alloc(16384*2);
  u16* rwb1T = (u16*)alloc(16384*2);
  u16* rwb2  = (u16*)alloc(16384*2);
  u16* rwb2T = (u16*)alloc(16384*2);
  float* pg   = (float*)alloc(512*4);   // pg+pb contiguous (GNB1 e2 / XGN-QGN pg)
  float* pb   = (float*)alloc(512*4);
  float* rw1f = (float*)alloc(16384*4);
  float* rw2f = (float*)alloc(16384*4);
  float* gw1f = (float*)alloc(16384*4);
  float* gb1f = (float*)alloc(64*4);
  float* gw2f = (float*)alloc(64*4);
  float* gb2f = (float*)alloc(256);
  float* rmf  = (float*)alloc(256*4);
  float* rvf  = (float*)alloc(256*4);
  float* rsf  = (float*)alloc(256);
  float* gsum   = (float*)alloc(512);   // gsum+gsumsq contiguous (EP_H1STAT o3)
  float* gsumsq = (float*)alloc(512);
  float* mu     = (float*)alloc(512);   // mu+rsig contiguous (GNB1 e1 / XGN-QGN mu)
  float* rsig   = (float*)alloc(512);
  float* cmsum  = (float*)alloc(1024);  // cmsum+cmsq contiguous (EP_YADDSTAT o3)
  float* cmsq   = (float*)alloc(1024);
  float* coefA  = (float*)alloc(1024);
  float* coefB  = (float*)alloc(1024);
  float* dGa    = (float*)alloc(2048);  // dGa+dBe+s1+s2 contiguous (GNB1 o3, wgrad red)
  float* dBe    = (float*)alloc(2048);
  float* s1     = (float*)alloc(512);
  float* s2     = (float*)alloc(512);
  float* pooled = (float*)alloc(16384);
  float* gate   = (float*)alloc(256);
  float* zc     = (float*)alloc(256);
  int*   dtf    = (int*)alloc(256);
  int*   mkf    = (int*)alloc(256);

  if (off > ws_size){
    k_report<<<1,64,0,stream>>>((u16*)d_out, (float)(ws_size>>20));
    return;
  }
  // adaptive: dedicated h1 buffer if ws allows (skips recompute GEMMs and
  // enables fused GNB1/GNB2/XGN/AST paths). ws_size constant -> graph-safe.
  u16* h1p = nullptr;
  if (off + (size_t)HIDD*NTOT*2 <= ws_size)
    h1p = (u16*)alloc((size_t)HIDD*NTOT*2);       // +51.4 MB

  // ---- probes + param conversion ----
  k_detect_dtype<<<1,1,0,stream>>>((const u16*)x_in, dtf);
  k_detect_mask<<<1,1,0,stream>>>((const unsigned char*)mk_in, mkf);
  #define CVT(src,dst,n) k_cvt<<<((n)+255)/256,256,0,stream>>>(src,dst,(n),dtf)
  CVT(w1_in,  pw1,  131072);
  CVT(g_in,   pg,   512);
  CVT(b_in,   pb,   512);
  CVT(w2_in,  pw2,  131072);
  CVT(rw1_in, rw1f, 16384);
  CVT(rw2_in, rw2f, 16384);
  CVT(gw1_in, gw1f, 16384);
  CVT(gb1_in, gb1f, 64);
  CVT(gw2_in, gw2f, 64);
  CVT(gb2_in, gb2f, 1);
  CVT(rs_in,  rsf,  1);
  CVT(rm_in,  rmf,  256);
  CVT(rv_in,  rvf,  256);
  #undef CVT
  k_wcvt<<<512,256,0,stream>>>(pw1, wb1, 0,     HIDD, CC);
  k_wcvt<<<512,256,0,stream>>>(pw2, wb2, wb2T,  CC, HIDD);
  k_wcvt<<<64,256,0,stream>>>(rw1f, rwb1, rwb1T, C4, CC);
  k_wcvt<<<64,256,0,stream>>>(rw2f, rwb2, rwb2T, CC, C4);
  hipMemsetAsync(zc, 0, 8, stream);
  k_expand<<<392,256,0,stream>>>((const unsigned char*)mk_in, mkf, mfb, zc);

  // ---- 2 inner TTT steps ----
  for (int s=0; s<2; s++){
    const float* mfs = mfb + s*NTOT;
    u16* h1dst = h1p ? h1p : Ab;
    // h1 = w1 @ x  (+ fused GN stats)
    hipMemsetAsync(gsum, 0, 1024, stream);
    k_gemm_mfma<0,EP_H1STAT,1,0,2,0,0><<<dim3(392,4),256,0,stream>>>(wb1, x_in, h1dst, CC, dtf, 0,0,0,0,0, gsum, 0,0);
    k_gn_finalize<<<1,128,0,stream>>>(gsum, gsumsq, mu, rsig);
    hipMemsetAsync(cmsum, 0, 2048, stream);
    if (h1p){
      // y = w2 @ gelu(gn(h1)) + x — gn+gelu fused into X staging; a stored to Ab
      k_gemm_mfma<0,EP_YADDSTAT,0,1,2,1,1><<<dim3(392,2),256,0,stream>>>(wb2, h1p, ybuf, HIDD, dtf, 0, x_in, 0,0, Ab, cmsum, mu, pg);
    } else {
      k_gelu_fwd<1><<<BB*HIDD,256,0,stream>>>(Ab, Ab, mu, rsig, pg, pb);   // Ab = a (in place)
      k_gemm_mfma<0,EP_YADDSTAT,0,1,2,0,0><<<dim3(392,2),256,0,stream>>>(wb2, Ab, ybuf, HIDD, dtf, 0, x_in, 0,0,0, cmsum, 0,0);
    }
    k_y_finalize<<<1,256,0,stream>>>(cmsum, cmsq, rmf, rvf, coefA, coefB);
    // t1 = rw1 @ (y*mf); h = gelu(t1)
    k_gemm_mfma<1,EP_T1H,0,0,1,0,0><<<dim3(392,1),256,0,stream>>>(rwb1, ybuf, t1b, CC, dtf, mfs, 0,0,0, hb, 0, 0,0);
    // dY := g_rec = 2*(rec - y)*inv/D
    k_gemm_mfma<0,EP_DYREC,0,0,2,0,0><<<dim3(392,2),256,0,stream>>>(rwb2, hb, dY, C4, dtf, mfs, ybuf, zc+s, 0,0, 0, 0,0);
    // dT1 = (rw2^T @ g_rec) * gelu'(t1)
    k_gemm_mfma<0,EP_DT1,0,0,1,0,0><<<dim3(392,1),256,0,stream>>>(rwb2T, dY, hb, CC, dtf, 0, t1b, 0,0,0, 0, 0,0);
    // dY := mf*(rw1^T @ dT1) - g_rec + coefA + coefB*y
    k_gemm_mfma<0,EP_DYFIN,0,0,2,0,0><<<dim3(392,2),256,0,stream>>>(rwb1T, hb, dY, C4, dtf, mfs, ybuf, coefA, coefB, 0, 0, 0,0);
    // dW2[c,o] = sum_n dY[c,n]*a[o,n]   (a materialized in Ab; part overlays ybuf)
    k_wgrad_mfma<0,0,0><<<dim3(32*SKW),256,0,stream>>>(dY, Ab, part, CC, HIDD, dtf, 4, 0,0,0,0);
    k_wgrad_reduce<<<512,256,0,stream>>>(part, dW2, 131072);
    // dA = w2^T @ dY  (+ fused gn_bwd1 when h1 is resident)
    hipMemsetAsync(dGa, 0, 5120, stream);
    if (h1p){
      k_gemm_mfma<0,EP_GNB1,0,0,2,0,0><<<dim3(392,4),256,0,stream>>>(wb2T, dY, Ab, CC, dtf, 0, h1p, mu, pg, 0, dGa, 0,0);
      // dW1[o,c] = sum_n dH1[o,n]*x[c,n] with gn_bwd2 applied during staging
      k_wgrad_mfma<1,1,0><<<dim3(32*SKW),256,0,stream>>>(Ab, x_in, part, HIDD, CC, dtf, 8, h1p, mu, dGa, 0);
    } else {
      k_gemm_mfma<0,EP_STORE,0,0,2,0,0><<<dim3(392,4),256,0,stream>>>(wb2T, dY, Ab, CC, dtf, 0,0,0,0,0, 0, 0,0);
      k_gemm_mfma<0,EP_H1STAT,1,0,2,0,0><<<dim3(392,4),256,0,stream>>>(wb1, x_in, h1rc, CC, dtf, 0,0,0,0,0, gsum, 0,0);
      k_gn_bwd1<<<BB*HIDD,256,0,stream>>>(Ab, h1rc, mu, rsig, pg, pb, dGa, dBe, s1, s2);
      k_gn_bwd2<<<BB*HIDD,256,0,stream>>>(Ab, h1rc, mu, rsig, s1, s2);
      k_wgrad_mfma<1,0,0><<<dim3(32*SKW),256,0,stream>>>(Ab, x_in, part, HIDD, CC, dtf, 8, 0,0,0,0);
    }
    k_wgrad_reduce<<<512,256,0,stream>>>(part, dW1, 131072);
    // SGD update + refresh bf16 weight copies
    k_update<<<512,256,0,stream>>>(pw1, pw2, pg, pb, dW1, dW2, dGa, dBe);
    k_wcvt<<<512,256,0,stream>>>(pw1, wb1, 0,    HIDD, CC);
    k_wcvt<<<512,256,0,stream>>>(pw2, wb2, wb2T, CC, HIDD);
  }

  // ---- gate (x-only; hoisted before final GEMM for EP_OUT) ----
  k_pool<<<BB*CC,256,0,stream>>>(x_in, dtf, pooled);
  k_gate<<<BB,64,0,stream>>>(pooled, gw1f, gb1f, gw2f, gb2f, gate);

  // ---- final modifier forward with updated params ----
  hipMemsetAsync(gsum, 0, 1024, stream);
  k_gemm_mfma<0,EP_H1STAT,1,0,2,0,0><<<dim3(392,4),256,0,stream>>>(wb1, x_in, Ab, CC, dtf, 0,0,0,0,0, gsum, 0,0);
  k_gn_finalize<<<1,128,0,stream>>>(gsum, gsumsq, mu, rsig);
  // out = x + rsf*gate[b]*(w2 @ gelu(gn(h1)))  — gn+gelu fused into X staging,
  // residual merge fused into epilogue (no gelu pass, no k_out pass)
  k_gemm_mfma<0,EP_OUT,0,1,2,1,0><<<dim3(392,2),256,0,stream>>>(wb2, Ab, (u16*)d_out, HIDD, dtf, 0, x_in, gate, rsf, 0, 0, mu, pg);
}

// Round 11
// 1057.162 us; speedup vs baseline: 1.1792x; 1.0171x over previous
//
#include <hip/hip_runtime.h>
#include <math.h>

// SelfModifyingBlock (TTT inner loop) — round 15:
//  r14 + XCD-aware bijective swizzle on all MT=2 GEMMs: the MY m-blocks sharing
//  an X panel were 392 dispatch-slots apart (panel evicted from the 4MB XCD-L2
//  between them -> FETCH 65.5MB vs 26MB unique). Flat grid, bid -> (xcd=bid&7,
//  nloc, mblk) puts panel-sharing blocks ADJACENT on the SAME XCD. 392=8*49 ->
//  bijective. AST guard now m0==0 (blockIdx.y is dead).

#define BB    16
#define CC    256
#define HWW   3136
#define NTOT  (BB*HWW)        // 50176
#define HIDD  512
#define NGRP  8
#define GMSZ  (64*HWW)        // 200704 elems per (b,group)
#define C4    64
#define LRATE 0.01f
#define SKW   32
#define CHUNK (NTOT/SKW)      // 1568
#define NV8   (HWW/8)         // 392 uint4 chunks per channel-row
#define FSTR  132             // fp32 LDS staging row stride (16B-aligned)

#define EP_STORE    0
#define EP_ADDFEAT  1
#define EP_T1H      2
#define EP_DYREC    3
#define EP_DT1      4
#define EP_DYFIN    5
#define EP_H1STAT   6
#define EP_YADDSTAT 7
#define EP_GNB1     8
#define EP_OUT      9

typedef unsigned short u16;
typedef __attribute__((ext_vector_type(8))) short bf16x8;
typedef __attribute__((ext_vector_type(4))) float f32x4;

__device__ __forceinline__ float bf2f(u16 u){
  return __uint_as_float(((unsigned)u)<<16);
}
__device__ __forceinline__ u16 f2bf(float f){
  unsigned u = __float_as_uint(f);
  u += 0x7FFFu + ((u>>16)&1u);
  return (u16)(u>>16);
}
// exact (gate only — tiny)
__device__ __forceinline__ float gelu_f(float x){
  return 0.5f*x*(1.0f+erff(x*0.70710678118654752f));
}
__device__ __forceinline__ float rcp_f(float x){ return __builtin_amdgcn_rcpf(x); }
// fast tanh-approx (max abs err ~1e-3 < bf16 quantum of O(1) values)
__device__ __forceinline__ float gelu_fast(float x){
  float x2 = x*x;
  float u = 0.7978845608f*x*fmaf(0.044715f, x2, 1.0f);
  float t = 1.0f - 2.0f*rcp_f(__expf(2.0f*u)+1.0f);
  return 0.5f*x*(1.0f+t);
}
__device__ __forceinline__ float gelu_g_fast(float x){
  float x2 = x*x;
  float u = 0.7978845608f*x*fmaf(0.044715f, x2, 1.0f);
  float t = 1.0f - 2.0f*rcp_f(__expf(2.0f*u)+1.0f);
  float du = 0.7978845608f*fmaf(0.134145f, x2, 1.0f);
  return fmaf(0.5f*x*(1.0f-t*t), du, 0.5f*(1.0f+t));
}
__device__ __forceinline__ float blk_sum(float v, float* sm){
  #pragma unroll
  for (int o=32;o>0;o>>=1) v += __shfl_down(v,o);
  if ((threadIdx.x & 63)==0) sm[threadIdx.x>>6] = v;
  __syncthreads();
  float r = sm[0]+sm[1]+sm[2]+sm[3];
  __syncthreads();
  return r;
}
__device__ __forceinline__ uint4 pack8(const ushort* e){
  uint4 v;
  v.x = (unsigned)e[0] | ((unsigned)e[1]<<16);
  v.y = (unsigned)e[2] | ((unsigned)e[3]<<16);
  v.z = (unsigned)e[4] | ((unsigned)e[5]<<16);
  v.w = (unsigned)e[6] | ((unsigned)e[7]<<16);
  return v;
}
__device__ __forceinline__ void up8(uint4 v, float* f){
  f[0]=bf2f((u16)(v.x&0xFFFFu)); f[1]=bf2f((u16)(v.x>>16));
  f[2]=bf2f((u16)(v.y&0xFFFFu)); f[3]=bf2f((u16)(v.y>>16));
  f[4]=bf2f((u16)(v.z&0xFFFFu)); f[5]=bf2f((u16)(v.z>>16));
  f[6]=bf2f((u16)(v.w&0xFFFFu)); f[7]=bf2f((u16)(v.w>>16));
}
__device__ __forceinline__ uint4 pk8(const float* f){
  uint4 v;
  v.x=(unsigned)f2bf(f[0])|((unsigned)f2bf(f[1])<<16);
  v.y=(unsigned)f2bf(f[2])|((unsigned)f2bf(f[3])<<16);
  v.z=(unsigned)f2bf(f[4])|((unsigned)f2bf(f[5])<<16);
  v.w=(unsigned)f2bf(f[6])|((unsigned)f2bf(f[7])<<16);
  return v;
}

// ---------- probes ----------
__global__ void k_detect_dtype(const u16* __restrict__ xs, int* flag){
  if (threadIdx.x || blockIdx.x) return;
  int plaus = 0;
  for (int i=0;i<256;i+=2){
    float f = bf2f(xs[i]);
    float a = fabsf(f);
    if (isfinite(f) && a < 32.0f && a > 1e-5f) plaus++;
  }
  *flag = (plaus >= 64) ? 1 : 0;   // 1 = bf16 inputs, 0 = fp32 inputs
}
__global__ void k_detect_mask(const unsigned char* __restrict__ m, int* flag){
  if (threadIdx.x || blockIdx.x) return;
  unsigned char mx=0; int nz0=0,nz1=0,nz2=0,nz3=0;
  for (int i=0;i<256;i++){
    unsigned char v=m[i]; if (v>mx) mx=v;
    if (v){ int r=i&3; if(r==0)nz0=1; else if(r==1)nz1=1; else if(r==2)nz2=1; else nz3=1; }
  }
  int f;
  if (mx<=1) f = (nz1|nz2|nz3) ? 0 : 1;
  else       f = (!nz0 && !nz1) ? 3 : 2;
  *flag=f;
}
__global__ void k_report(u16* out, float v){
  if (threadIdx.x==0 && blockIdx.x==0) out[0] = f2bf(v);
}

__global__ void k_cvt(const void* __restrict__ src, float* __restrict__ dst, int n,
                      const int* __restrict__ dtf){
  int i = blockIdx.x*256 + threadIdx.x;
  if (i>=n) return;
  if (*dtf) dst[i] = bf2f(((const u16*)src)[i]);
  else      dst[i] = ((const float*)src)[i];
}
__global__ void k_wcvt(const float* __restrict__ src, u16* __restrict__ d,
                       u16* __restrict__ dT, int R, int Cc){
  int i = blockIdx.x*256+threadIdx.x;
  if (i >= R*Cc) return;
  int r = i/Cc, c = i - r*Cc;
  u16 v = f2bf(src[i]);
  d[i] = v;
  if (dT) dT[(size_t)c*R + r] = v;
}

__global__ void k_expand(const unsigned char* __restrict__ mraw, const int* __restrict__ flag,
                         float* __restrict__ mf, float* __restrict__ zc){
  __shared__ float sm[4];
  int i = blockIdx.x*256 + threadIdx.x;     // grid 392 = 2*NTOT/256
  int f = *flag;
  float v;
  if (f==1)      v = (((const int*)mraw)[i] != 0) ? 1.f : 0.f;
  else if (f==0) v = (mraw[i] != 0) ? 1.f : 0.f;
  else if (f==2) v = (((const u16*)mraw)[i] != 0) ? 1.f : 0.f;
  else           v = (((const float*)mraw)[i] != 0.f) ? 1.f : 0.f;
  mf[i] = v;
  float S = blk_sum(1.f - v, sm);
  if (threadIdx.x==0) atomicAdd(&zc[blockIdx.x/196], S);
}

// ---------- MFMA GEMM: Out[m,n] = sum_k A[m,k]*X[k,n] ----------
// MT: 64*MT m-rows per block. MY: number of m-blocks (M = MY*64*MT).
// MY>1: flat grid of 392*MY blocks, XCD-swizzled so the MY m-blocks sharing an
// X panel are adjacent on one XCD (n0=(xcd*49+nloc)*128).
// XGN=1: gn+gelu_fast during X staging (hoisted params). AST=1: store staged a
// to o2 from the m0==0 blocks. LDS stride 40 u16 (80B, 16B-aligned).
template<int MASKX,int EPI,int XDYN,int E0DYN,int MT,int XGN,int AST,int MY>
__global__ __launch_bounds__(256) void k_gemm_mfma(
    const u16* __restrict__ A, const void* __restrict__ Xv, u16* __restrict__ Out,
    int K, const int* __restrict__ xdt, const float* __restrict__ mf,
    const void* __restrict__ e0, const float* __restrict__ e1,
    const float* __restrict__ e2, u16* __restrict__ o2, float* __restrict__ o3,
    const float* __restrict__ xmu, const float* __restrict__ xpg)
{
  constexpr int MROWS = 64*MT;
  constexpr int NMI   = 4*MT;
  constexpr int M     = MY*MROWS;
  __shared__ __align__(16) u16 Ws[MROWS*40];
  __shared__ __align__(16) u16 Xs[128*40];
  const int t = threadIdx.x;
  const int w = t >> 6, lane = t & 63;
  const int col = lane & 15, quad = lane >> 4;
  int m0, n0;
  if (MY>1){
    const int bid = (int)blockIdx.x;
    const int xcd = bid & 7, idx = bid >> 3;
    const int nloc = idx / MY;
    const int mblk = idx - nloc*MY;
    m0 = mblk * MROWS;
    n0 = (xcd*49 + nloc) << 7;
  } else {
    m0 = blockIdx.y * MROWS;
    n0 = blockIdx.x << 7;
  }
  const int isbx = XDYN ? *xdt : 1;
  const u16*   Xb = (const u16*)Xv;
  const float* Xf = (const float*)Xv;
  const int wrow = t >> 2, wkq = (t & 3) * 8;
  const int xn   = 2*(t & 63);
  const int xq   = t >> 6;
  const int gn0  = n0 + xn;
  const int xb_  = gn0 / HWW;
  const int xs_  = gn0 - xb_*HWW;
  const bool do_ast = AST && (m0==0);

  f32x4 acc[NMI][2];
  #pragma unroll
  for (int i=0;i<NMI;i++){
    #pragma unroll
    for (int j=0;j<2;j++) acc[i][j] = (f32x4)(0.0f);
  }

  for (int k0=0; k0<K; k0+=32){
    if (MT==2){
      const u16* ap = A + (size_t)(m0 + (t>>1))*K + k0 + (t&1)*16;
      *(uint4*)(Ws + (t>>1)*40 + (t&1)*16)     = *(const uint4*)ap;
      *(uint4*)(Ws + (t>>1)*40 + (t&1)*16 + 8) = *(const uint4*)(ap+8);
    } else {
      uint4 v = *(const uint4*)(A + (size_t)(m0+wrow)*K + k0 + wkq);
      *(uint4*)(Ws + wrow*40 + wkq) = v;
    }
    {
      ushort e[16];
      size_t base = ((size_t)xb_*K + k0 + xq*8)*HWW + xs_;
      if (isbx){
        if (XGN){
          // ob is 8-aligned and the 8-block never straddles a 64-group
          const int ob = k0 + xq*8;
          const int bg = xb_*NGRP + (ob>>6);
          const float mu_ = xmu[bg], rs_ = xmu[128+bg];
          float4 ga0 = *(const float4*)(xpg+ob);
          float4 ga1 = *(const float4*)(xpg+ob+4);
          float4 be0 = *(const float4*)(xpg+512+ob);
          float4 be1 = *(const float4*)(xpg+512+ob+4);
          float ga[8] = {ga0.x,ga0.y,ga0.z,ga0.w,ga1.x,ga1.y,ga1.z,ga1.w};
          float be[8] = {be0.x,be0.y,be0.z,be0.w,be1.x,be1.y,be1.z,be1.w};
          #pragma unroll
          for (int j=0;j<8;j++){
            unsigned v = *(const unsigned*)(Xb + base + (size_t)j*HWW);
            float f0 = bf2f((u16)(v & 0xFFFFu));
            float f1 = bf2f((u16)(v >> 16));
            f0 = gelu_fast(fmaf((f0-mu_)*rs_, ga[j], be[j]));
            f1 = gelu_fast(fmaf((f1-mu_)*rs_, ga[j], be[j]));
            e[j]   = f2bf(f0);
            e[8+j] = f2bf(f1);
            if (AST){
              if (do_ast){
                unsigned av = (unsigned)e[j] | ((unsigned)e[8+j]<<16);
                *(unsigned*)(o2 + base + (size_t)j*HWW) = av;
              }
            }
          }
        } else {
          #pragma unroll
          for (int j=0;j<8;j++){
            unsigned v = *(const unsigned*)(Xb + base + (size_t)j*HWW);
            e[j]   = (ushort)(v & 0xFFFFu);
            e[8+j] = (ushort)(v >> 16);
          }
        }
      } else {
        #pragma unroll
        for (int j=0;j<8;j++){
          float2 f = *(const float2*)(Xf + base + (size_t)j*HWW);
          e[j]   = f2bf(f.x);
          e[8+j] = f2bf(f.y);
        }
      }
      if (MASKX){
        if (mf[gn0]   == 0.f){
          #pragma unroll
          for (int j=0;j<8;j++) e[j] = 0;
        }
        if (mf[gn0+1] == 0.f){
          #pragma unroll
          for (int j=0;j<8;j++) e[8+j] = 0;
        }
      }
      *(uint4*)(Xs + xn*40     + xq*8) = pack8(e);
      *(uint4*)(Xs + (xn+1)*40 + xq*8) = pack8(e+8);
    }
    __syncthreads();
    bf16x8 bfr[2];
    #pragma unroll
    for (int nj=0;nj<2;nj++)
      bfr[nj] = *(const bf16x8*)(Xs + (w*32+nj*16+col)*40 + quad*8);
    #pragma unroll
    for (int mi=0;mi<NMI;mi++){
      bf16x8 af = *(const bf16x8*)(Ws + (mi*16+col)*40 + quad*8);
      acc[mi][0] = __builtin_amdgcn_mfma_f32_16x16x32_bf16(af, bfr[0], acc[mi][0], 0,0,0);
      acc[mi][1] = __builtin_amdgcn_mfma_f32_16x16x32_bf16(af, bfr[1], acc[mi][1], 0,0,0);
    }
    __syncthreads();
  }
  // ---- unified vectorized epilogue (Ws -> sred scratch, Xs -> fp32 staging) ----
  const int isb0 = E0DYN ? *xdt : 1;
  float* fst  = (float*)Xs;            // 16 x FSTR fp32 = 8448B <= 10240B
  float* sred = (float*)Ws;            // reduction scratch (<= 1056B)
  const int row16 = t >> 4;            // 0..15
  const int cb    = (t & 15) * 8;      // 0..120
  const int nb8   = n0 + cb;
  const int b8    = nb8 / HWW;         // all 8 cols same b (HWW%8==0, cb 8-aligned)
  const int sb8   = nb8 - b8*HWW;
  const int bA    = n0 / HWW, bB = (n0+127)/HWW;
  const int gbase = m0 >> 6;

  if (EPI==EP_H1STAT){ if (t < 4*MT) sred[t]=0.f; }
  if (EPI==EP_GNB1){ if (t < 4*MT) sred[2*NMI*16 + t]=0.f; }
  if (EPI==EP_H1STAT||EPI==EP_GNB1) __syncthreads();

  float dscale=0.f, gmul=0.f;
  if (EPI==EP_DYREC) dscale = 2.0f / (e1[0]*(float)CC + 1e-8f);
  if (EPI==EP_OUT)   gmul = e2[0]*e1[b8];
  // per-(group,b-slot) register accumulators (H1STAT: sum/sq; GNB1: s1/s2)
  float hs0[MT], hq0[MT], hs1[MT], hq1[MT];
  #pragma unroll
  for (int i=0;i<MT;i++){ hs0[i]=0.f; hq0[i]=0.f; hs1[i]=0.f; hq1[i]=0.f; }

  #pragma unroll
  for (int mi=0;mi<NMI;mi++){
    #pragma unroll
    for (int nj=0;nj<2;nj++){
      #pragma unroll
      for (int r=0;r<4;r++)
        fst[(quad*4+r)*FSTR + w*32 + nj*16 + col] = acc[mi][nj][r];
    }
    __syncthreads();
    const int m = m0 + mi*16 + row16;
    const size_t oidx = ((size_t)b8*M + m)*HWW + sb8;
    float v[8];
    {
      const float* frow = fst + row16*FSTR + cb;
      float4 p0 = *(const float4*)frow;
      float4 p1 = *(const float4*)(frow+4);
      v[0]=p0.x; v[1]=p0.y; v[2]=p0.z; v[3]=p0.w;
      v[4]=p1.x; v[5]=p1.y; v[6]=p1.z; v[7]=p1.w;
    }

    if (EPI==EP_STORE){
      *(uint4*)(Out+oidx) = pk8(v);
    }
    else if (EPI==EP_ADDFEAT){
      float xv[8];
      if (isb0) up8(*(const uint4*)((const u16*)e0+oidx), xv);
      else {
        float4 a0 = *(const float4*)((const float*)e0+oidx);
        float4 a1 = *(const float4*)((const float*)e0+oidx+4);
        xv[0]=a0.x; xv[1]=a0.y; xv[2]=a0.z; xv[3]=a0.w;
        xv[4]=a1.x; xv[5]=a1.y; xv[6]=a1.z; xv[7]=a1.w;
      }
      #pragma unroll
      for (int j=0;j<8;j++) v[j] += xv[j];
      *(uint4*)(Out+oidx) = pk8(v);
    }
    else if (EPI==EP_T1H){
      *(uint4*)(Out+oidx) = pk8(v);
      float gv[8];
      #pragma unroll
      for (int j=0;j<8;j++) gv[j] = gelu_fast(v[j]);
      *(uint4*)(o2+oidx) = pk8(gv);
    }
    else if (EPI==EP_DYREC){
      float yv[8], mfv[8];
      up8(*(const uint4*)((const u16*)e0+oidx), yv);
      float4 f0 = *(const float4*)(mf+nb8);
      float4 f1 = *(const float4*)(mf+nb8+4);
      mfv[0]=f0.x; mfv[1]=f0.y; mfv[2]=f0.z; mfv[3]=f0.w;
      mfv[4]=f1.x; mfv[5]=f1.y; mfv[6]=f1.z; mfv[7]=f1.w;
      #pragma unroll
      for (int j=0;j<8;j++) v[j] = (v[j]-yv[j])*(1.0f-mfv[j])*dscale;
      *(uint4*)(Out+oidx) = pk8(v);
    }
    else if (EPI==EP_DT1){
      float tv[8];
      up8(*(const uint4*)((const u16*)e0+oidx), tv);
      #pragma unroll
      for (int j=0;j<8;j++) v[j] = v[j]*gelu_g_fast(tv[j]);
      *(uint4*)(Out+oidx) = pk8(v);
    }
    else if (EPI==EP_DYFIN){
      float yv[8], dv[8], mfv[8];
      up8(*(const uint4*)((const u16*)e0+oidx), yv);
      up8(*(const uint4*)(Out+oidx), dv);
      float4 f0 = *(const float4*)(mf+nb8);
      float4 f1 = *(const float4*)(mf+nb8+4);
      mfv[0]=f0.x; mfv[1]=f0.y; mfv[2]=f0.z; mfv[3]=f0.w;
      mfv[4]=f1.x; mfv[5]=f1.y; mfv[6]=f1.z; mfv[7]=f1.w;
      const float c1 = e1[m], c2 = e2[m];
      #pragma unroll
      for (int j=0;j<8;j++) v[j] = mfv[j]*v[j] - dv[j] + c1 + c2*yv[j];
      *(uint4*)(Out+oidx) = pk8(v);
    }
    else if (EPI==EP_H1STAT){
      *(uint4*)(Out+oidx) = pk8(v);
      float s=0.f, q=0.f;
      #pragma unroll
      for (int j=0;j<8;j++){ s += v[j]; q = fmaf(v[j],v[j],q); }
      const bool inA = (b8==bA);
      hs0[mi>>2] += inA ? s : 0.f;  hq0[mi>>2] += inA ? q : 0.f;
      hs1[mi>>2] += inA ? 0.f : s;  hq1[mi>>2] += inA ? 0.f : q;
    }
    else if (EPI==EP_YADDSTAT){
      float xv[8];
      if (isb0) up8(*(const uint4*)((const u16*)e0+oidx), xv);
      else {
        float4 a0 = *(const float4*)((const float*)e0+oidx);
        float4 a1 = *(const float4*)((const float*)e0+oidx+4);
        xv[0]=a0.x; xv[1]=a0.y; xv[2]=a0.z; xv[3]=a0.w;
        xv[4]=a1.x; xv[5]=a1.y; xv[6]=a1.z; xv[7]=a1.w;
      }
      float s=0.f, q=0.f;
      #pragma unroll
      for (int j=0;j<8;j++){
        v[j] += xv[j];
        s += v[j]; q = fmaf(v[j],v[j],q);
      }
      *(uint4*)(Out+oidx) = pk8(v);
      #pragma unroll
      for (int o=1;o<16;o<<=1){ s += __shfl_xor(s,o); q += __shfl_xor(q,o); }
      if ((t&15)==0){
        sred[mi*16+row16]          = s;
        sred[NMI*16 + mi*16+row16] = q;
      }
    }
    else if (EPI==EP_GNB1){
      float hv[8];
      up8(*(const uint4*)((const u16*)e0+oidx), hv);
      const int gcur = gbase + (mi>>2);
      const float muT = e1[b8*NGRP+gcur], rT = e1[128+b8*NGRP+gcur];
      const float go = e2[m], beo = e2[HIDD+m];
      float dB=0.f, dG=0.f, sS=0.f, sQ=0.f;
      #pragma unroll
      for (int j=0;j<8;j++){
        float hn   = (hv[j]-muT)*rT;
        float ghat = fmaf(hn, go, beo);
        float dgh  = v[j]*gelu_g_fast(ghat);
        float dhn  = dgh*go;
        v[j] = dhn;
        dB += dgh; dG = fmaf(dgh,hn,dG);
        sS += dhn; sQ = fmaf(dhn,hn,sQ);
      }
      *(uint4*)(Out+oidx) = pk8(v);
      #pragma unroll
      for (int o=1;o<16;o<<=1){ dB += __shfl_xor(dB,o); dG += __shfl_xor(dG,o); }
      if ((t&15)==0){
        sred[mi*16+row16]          = dB;
        sred[NMI*16 + mi*16+row16] = dG;
      }
      const bool inA = (b8==bA);
      hs0[mi>>2] += inA ? sS : 0.f;  hq0[mi>>2] += inA ? sQ : 0.f;
      hs1[mi>>2] += inA ? 0.f : sS;  hq1[mi>>2] += inA ? 0.f : sQ;
    }
    else if (EPI==EP_OUT){
      float xv[8];
      if (isb0){
        up8(*(const uint4*)((const u16*)e0+oidx), xv);
        #pragma unroll
        for (int j=0;j<8;j++) v[j] = xv[j] + gmul*v[j];
        *(uint4*)(Out+oidx) = pk8(v);
      } else {
        float4 a0 = *(const float4*)((const float*)e0+oidx);
        float4 a1 = *(const float4*)((const float*)e0+oidx+4);
        float4 r0, r1;
        r0.x = a0.x + gmul*v[0]; r0.y = a0.y + gmul*v[1];
        r0.z = a0.z + gmul*v[2]; r0.w = a0.w + gmul*v[3];
        r1.x = a1.x + gmul*v[4]; r1.y = a1.y + gmul*v[5];
        r1.z = a1.z + gmul*v[6]; r1.w = a1.w + gmul*v[7];
        *(float4*)((float*)Out+oidx)   = r0;
        *(float4*)((float*)Out+oidx+4) = r1;
      }
    }
    __syncthreads();
  }

  // cross-wave (group,b) reductions for H1STAT / GNB1
  if (EPI==EP_H1STAT || EPI==EP_GNB1){
    const int soff = (EPI==EP_GNB1) ? 2*NMI*16 : 0;
    #pragma unroll
    for (int g2=0; g2<MT; g2++){
      float a0=hs0[g2], c0=hq0[g2], a1=hs1[g2], c1=hq1[g2];
      #pragma unroll
      for (int o=1;o<64;o<<=1){
        a0 += __shfl_xor(a0,o); c0 += __shfl_xor(c0,o);
        a1 += __shfl_xor(a1,o); c1 += __shfl_xor(c1,o);
      }
      if (lane==0){
        atomicAdd(&sred[soff+g2*4+0], a0);
        atomicAdd(&sred[soff+g2*4+1], c0);
        atomicAdd(&sred[soff+g2*4+2], a1);
        atomicAdd(&sred[soff+g2*4+3], c1);
      }
    }
    __syncthreads();
  }

  // final global reductions
  if (EPI==EP_H1STAT){
    if (t==0){
      #pragma unroll
      for (int g2=0; g2<MT; g2++){
        atomicAdd(&o3[bA*NGRP+gbase+g2],     sred[g2*4+0]);
        atomicAdd(&o3[128+bA*NGRP+gbase+g2], sred[g2*4+1]);
      }
    }
    if (t==1 && bB!=bA){
      #pragma unroll
      for (int g2=0; g2<MT; g2++){
        atomicAdd(&o3[bB*NGRP+gbase+g2],     sred[g2*4+2]);
        atomicAdd(&o3[128+bB*NGRP+gbase+g2], sred[g2*4+3]);
      }
    }
  }
  if (EPI==EP_YADDSTAT){
    if (t < NMI*16){
      atomicAdd(&o3[m0+t],    sred[t]);
      atomicAdd(&o3[CC+m0+t], sred[NMI*16+t]);
    }
  }
  if (EPI==EP_GNB1){
    if (t < NMI*16){
      atomicAdd(&o3[m0+t],     sred[NMI*16+t]);   // dGa
      atomicAdd(&o3[512+m0+t], sred[t]);          // dBe
    }
    if (t==NMI*16){
      #pragma unroll
      for (int g2=0; g2<MT; g2++){
        atomicAdd(&o3[1024+bA*NGRP+gbase+g2], sred[2*NMI*16+g2*4+0]);  // s1
        atomicAdd(&o3[1152+bA*NGRP+gbase+g2], sred[2*NMI*16+g2*4+1]);  // s2
      }
    }
    if (t==NMI*16+1 && bB!=bA){
      #pragma unroll
      for (int g2=0; g2<MT; g2++){
        atomicAdd(&o3[1024+bB*NGRP+gbase+g2], sred[2*NMI*16+g2*4+2]);
        atomicAdd(&o3[1152+bB*NGRP+gbase+g2], sred[2*NMI*16+g2*4+3]);
      }
    }
  }
}

// ---------- MFMA weight-grad: flattened grid, XCD-chunk swizzle ----------
// GNB2=1: apply GN-backward stage-2 (dH1 = r*(dhn - a1 - hn*a2)) while staging P.
// QGN=1:  apply gn+gelu_fast while staging Q (kept for fallback flexibility).
template<int QDYN, int GNB2, int QGN>
__global__ __launch_bounds__(256) void k_wgrad_mfma(
    const u16* __restrict__ P, const void* __restrict__ Qv, float* __restrict__ part,
    int CHP, int CHQ, const int* __restrict__ xdt, int ntx,
    const u16* __restrict__ h1, const float* __restrict__ musig,
    const float* __restrict__ red, const float* __restrict__ qpg)
{
  __shared__ __align__(16) u16 Ps[64*40];
  __shared__ __align__(16) u16 Qs[64*40];
  const int f = blockIdx.x;
  const int j = f >> 3;
  const int sk = (f & 7) + ((j >> 5) << 3);
  const int tile = j & 31;
  const int ty = tile / ntx;
  const int m0 = (tile - ty*ntx) << 6;
  const int n0 = ty << 6;
  const int t = threadIdx.x;
  const int w = t >> 6, lane = t & 63;
  const int col = lane & 15, quad = lane >> 4;
  const int isbq = QDYN ? *xdt : 1;
  const u16*   Qb = (const u16*)Qv;
  const float* Qf = (const float*)Qv;
  const int srow = (t & 127) >> 1;
  const int ssq  = ((t & 127) & 1) * 16;
  // QGN: per-thread row params, k-loop invariant
  float ga_q = 0.f, be_q = 0.f;
  if (QGN && t >= 128){
    ga_q = qpg[n0+srow];
    be_q = qpg[512+n0+srow];
  }
  f32x4 acc[2][2];
  #pragma unroll
  for (int i=0;i<2;i++){
    #pragma unroll
    for (int jj=0;jj<2;jj++) acc[i][jj] = (f32x4)(0.0f);
  }
  const int mbase = (w & 1)*32, nbase = (w >> 1)*32;

  for (int kb = sk*CHUNK; kb < sk*CHUNK + CHUNK; kb += 32){
    const int b = kb / HWW;
    const int s = kb - b*HWW;
    if (t < 128){
      size_t off = ((size_t)b*CHP + m0+srow)*HWW + s + ssq;
      uint4 v0 = *(const uint4*)(P + off);
      uint4 v1 = *(const uint4*)(P + off + 8);
      if (GNB2){
        const int bg = b*NGRP + (m0>>6);
        const float mu_ = musig[bg], r_ = musig[128+bg];
        const float a1 = red[1024+bg]*(1.0f/GMSZ);
        const float a2 = red[1152+bg]*(1.0f/GMSZ);
        uint4 h0 = *(const uint4*)(h1 + off);
        uint4 h1v = *(const uint4*)(h1 + off + 8);
        float fd[8], fh[8];
        up8(v0, fd); up8(h0, fh);
        #pragma unroll
        for (int q2=0;q2<8;q2++){ float hn=(fh[q2]-mu_)*r_; fd[q2]=r_*(fd[q2]-a1-hn*a2); }
        v0 = pk8(fd);
        up8(v1, fd); up8(h1v, fh);
        #pragma unroll
        for (int q2=0;q2<8;q2++){ float hn=(fh[q2]-mu_)*r_; fd[q2]=r_*(fd[q2]-a1-hn*a2); }
        v1 = pk8(fd);
      }
      *(uint4*)(Ps + srow*40 + ssq)     = v0;
      *(uint4*)(Ps + srow*40 + ssq + 8) = v1;
    } else {
      size_t off = ((size_t)b*CHQ + n0+srow)*HWW + s + ssq;
      if (isbq){
        uint4 v0 = *(const uint4*)(Qb + off);
        uint4 v1 = *(const uint4*)(Qb + off + 8);
        if (QGN){
          const int bg = b*NGRP + ((n0+srow)>>6);
          const float mu_ = musig[bg], rs_ = musig[128+bg];
          float fq[8];
          up8(v0, fq);
          #pragma unroll
          for (int q2=0;q2<8;q2++) fq[q2] = gelu_fast(fmaf((fq[q2]-mu_)*rs_, ga_q, be_q));
          v0 = pk8(fq);
          up8(v1, fq);
          #pragma unroll
          for (int q2=0;q2<8;q2++) fq[q2] = gelu_fast(fmaf((fq[q2]-mu_)*rs_, ga_q, be_q));
          v1 = pk8(fq);
        }
        *(uint4*)(Qs + srow*40 + ssq)     = v0;
        *(uint4*)(Qs + srow*40 + ssq + 8) = v1;
      } else {
        ushort e[16];
        #pragma unroll
        for (int g2=0; g2<4; g2++){
          float4 ff = *(const float4*)(Qf + off + g2*4);
          e[g2*4+0]=f2bf(ff.x); e[g2*4+1]=f2bf(ff.y); e[g2*4+2]=f2bf(ff.z); e[g2*4+3]=f2bf(ff.w);
        }
        *(uint4*)(Qs + srow*40 + ssq)     = pack8(e);
        *(uint4*)(Qs + srow*40 + ssq + 8) = pack8(e+8);
      }
    }
    __syncthreads();
    bf16x8 pa[2], qb[2];
    #pragma unroll
    for (int a=0;a<2;a++)
      pa[a] = *(const bf16x8*)(Ps + (mbase + a*16 + col)*40 + quad*8);
    #pragma unroll
    for (int bb=0;bb<2;bb++)
      qb[bb] = *(const bf16x8*)(Qs + (nbase + bb*16 + col)*40 + quad*8);
    #pragma unroll
    for (int a=0;a<2;a++){
      #pragma unroll
      for (int bb=0;bb<2;bb++)
        acc[a][bb] = __builtin_amdgcn_mfma_f32_16x16x32_bf16(pa[a], qb[bb], acc[a][bb], 0,0,0);
    }
    __syncthreads();
  }
  float* dst = part + (size_t)sk*CHP*CHQ;
  #pragma unroll
  for (int a=0;a<2;a++){
    #pragma unroll
    for (int bb=0;bb<2;bb++){
      #pragma unroll
      for (int r=0;r<4;r++){
        const int m = m0 + mbase + a*16 + quad*4 + r;
        const int n = n0 + nbase + bb*16 + col;
        dst[(size_t)m*CHQ + n] = acc[a][bb][r];
      }
    }
  }
}
__global__ void k_wgrad_reduce(const float* __restrict__ part, float* __restrict__ dW, int n){
  int i = blockIdx.x*256+threadIdx.x;
  if (i>=n) return;
  float s=0;
  #pragma unroll
  for (int k=0;k<SKW;k++) s += part[(size_t)k*n + i];
  dW[i]=s;
}

// ---------- GroupNorm fwd finalize + gelu (gelu pass = fallback only) ----------
__global__ void k_gn_finalize(const float* gsum, const float* gsumsq, float* mu, float* rsig){
  int i = threadIdx.x; if (i>=BB*NGRP) return;
  float m = gsum[i]*(1.0f/GMSZ);
  float v = gsumsq[i]*(1.0f/GMSZ) - m*m;
  v = fmaxf(v, 0.0f);
  mu[i]=m; rsig[i]=rsqrtf(v+1e-5f);
}
template<int FAST>
__global__ void k_gelu_fwd(const u16* __restrict__ src, u16* __restrict__ dst,
    const float* __restrict__ mu, const float* __restrict__ rsig,
    const float* __restrict__ pg, const float* __restrict__ pb){
  int bo = blockIdx.x;
  int b = bo>>9, o = bo&511, bg = b*NGRP + (o>>6);
  float m = mu[bg], r = rsig[bg], g = pg[o], be = pb[o];
  const uint4* ps = (const uint4*)(src + (size_t)bo*HWW);
  uint4* pd = (uint4*)(dst + (size_t)bo*HWW);
  for (int i=threadIdx.x;i<NV8;i+=256){
    float f[8]; up8(ps[i], f);
    #pragma unroll
    for (int j=0;j<8;j++){
      float gh = fmaf((f[j]-m)*r, g, be);
      f[j] = FAST ? gelu_fast(gh) : gelu_f(gh);
    }
    pd[i] = pk8(f);
  }
}

// ---------- y channel moments finalize ----------
__global__ void k_y_finalize(const float* cmsum, const float* cmsq,
    const float* rmf, const float* rvf, float* coefA, float* coefB){
  int c = threadIdx.x; if (c>=CC) return;
  float cm = cmsum[c]*(1.0f/NTOT);
  float cv = (cmsq[c] - (float)NTOT*cm*cm)*(1.0f/(NTOT-1));
  float rvp = rvf[c] + 1e-8f;
  float gcm = 0.2f*(cm - rmf[c])*(1.0f/CC);
  float gcv = 0.2f*(cv/rvp - 1.0f)/(rvp*(float)CC);
  coefA[c] = gcm*(1.0f/NTOT) - 2.0f*gcv*cm*(1.0f/(NTOT-1));
  coefB[c] = 2.0f*gcv*(1.0f/(NTOT-1));
}

// ---------- GroupNorm backward (fallback path only, when !h1p) ----------
__global__ void k_gn_bwd1(u16* __restrict__ dA, const u16* __restrict__ h1,
    const float* mu, const float* rsig, const float* pg, const float* pb,
    float* dGa, float* dBe, float* s1, float* s2){
  __shared__ float sm[4];
  int bo = blockIdx.x;
  int b = bo>>9, o = bo&511, bg = b*NGRP + (o>>6);
  float m = mu[bg], r = rsig[bg], g = pg[o], be = pb[o];
  uint4* pa = (uint4*)(dA + (size_t)bo*HWW);
  const uint4* ph = (const uint4*)(h1 + (size_t)bo*HWW);
  float sb=0, sg=0, t1=0, t2=0;
  for (int i=threadIdx.x;i<NV8;i+=256){
    float fa[8], fh[8]; up8(pa[i], fa); up8(ph[i], fh);
    #pragma unroll
    for (int j=0;j<8;j++){
      float hn = (fh[j]-m)*r;
      float ghat = fmaf(hn,g,be);
      float dgh = fa[j]*gelu_g_fast(ghat);
      float dhn = dgh*g;
      fa[j] = dhn;
      sb += dgh; sg = fmaf(dgh,hn,sg); t1 += dhn; t2 = fmaf(dhn,hn,t2);
    }
    pa[i] = pk8(fa);
  }
  float S;
  S = blk_sum(sb,sm); if (threadIdx.x==0) atomicAdd(&dBe[o], S);
  S = blk_sum(sg,sm); if (threadIdx.x==0) atomicAdd(&dGa[o], S);
  S = blk_sum(t1,sm); if (threadIdx.x==0) atomicAdd(&s1[bg], S);
  S = blk_sum(t2,sm); if (threadIdx.x==0) atomicAdd(&s2[bg], S);
}
__global__ void k_gn_bwd2(u16* __restrict__ dA, const u16* __restrict__ h1,
    const float* mu, const float* rsig, const float* s1, const float* s2){
  int bo = blockIdx.x;
  int b = bo>>9, o = bo&511, bg = b*NGRP + (o>>6);
  float m = mu[bg], r = rsig[bg];
  float a1 = s1[bg]*(1.0f/GMSZ), a2 = s2[bg]*(1.0f/GMSZ);
  uint4* pa = (uint4*)(dA + (size_t)bo*HWW);
  const uint4* ph = (const uint4*)(h1 + (size_t)bo*HWW);
  for (int i=threadIdx.x;i<NV8;i+=256){
    float fa[8], fh[8]; up8(pa[i], fa); up8(ph[i], fh);
    #pragma unroll
    for (int j=0;j<8;j++){
      float hn = (fh[j]-m)*r;
      fa[j] = r*(fa[j] - a1 - hn*a2);
    }
    pa[i] = pk8(fa);
  }
}

__global__ void k_update(float* pw1, float* pw2, float* pg, float* pb,
    const float* dW1, const float* dW2, const float* dGa, const float* dBe){
  int i = blockIdx.x*256+threadIdx.x;
  if (i < HIDD*CC){ pw1[i] -= LRATE*dW1[i]; pw2[i] -= LRATE*dW2[i]; }
  if (i < HIDD){ pg[i] -= LRATE*dGa[i]; pb[i] -= LRATE*dBe[i]; }
}

// ---------- gate ----------
__global__ void k_pool(const void* __restrict__ xv, const int* __restrict__ dtf, float* pooled){
  __shared__ float sm[4];
  int bc = blockIdx.x;
  int isb = *dtf;
  float s=0;
  if (isb){
    const uint4* p = (const uint4*)((const u16*)xv + (size_t)bc*HWW);
    for (int i=threadIdx.x;i<NV8;i+=256){
      float f[8]; up8(p[i], f);
      #pragma unroll
      for (int j=0;j<8;j++) s+=f[j];
    }
  } else {
    const float4* p = (const float4*)((const float*)xv + (size_t)bc*HWW);
    for (int i=threadIdx.x;i<HWW/4;i+=256){
      float4 f = p[i];
      s += f.x+f.y+f.z+f.w;
    }
  }
  float S = blk_sum(s,sm);
  if (threadIdx.x==0) pooled[bc]=S*(1.0f/HWW);
}
__global__ void k_gate(const float* __restrict__ pooled, const float* __restrict__ gw1,
    const float* __restrict__ gb1, const float* __restrict__ gw2, const float* __restrict__ gb2,
    float* gate){
  int b = blockIdx.x, j = threadIdx.x;      // 64 threads = 1 wave
  float acc = gb1[j];
  const float* pr = pooled + b*CC;
  for (int c=0;c<CC;c++) acc = fmaf(pr[c], gw1[j*CC+c], acc);
  float v = gelu_f(acc)*gw2[j];
  #pragma unroll
  for (int o=32;o>0;o>>=1) v += __shfl_down(v,o);
  if (j==0) gate[b] = 1.0f/(1.0f+expf(-(v+gb2[0])));
}

// =======================================================================
extern "C" void kernel_launch(void* const* d_in, const int* in_sizes, int n_in,
                              void* d_out, int out_size, void* d_ws, size_t ws_size,
                              hipStream_t stream)
{
  const void* x_in   = d_in[0];
  const void* w1_in  = d_in[1];
  const void* g_in   = d_in[2];
  const void* b_in   = d_in[3];
  const void* w2_in  = d_in[4];
  const void* rw1_in = d_in[5];
  const void* rw2_in = d_in[6];
  const void* gw1_in = d_in[7];
  const void* gb1_in = d_in[8];
  const void* gw2_in = d_in[9];
  const void* gb2_in = d_in[10];
  const void* rs_in  = d_in[11];
  const void* rm_in  = d_in[12];
  const void* rv_in  = d_in[13];
  const void* mk_in  = d_in[14];
  (void)in_sizes; (void)n_in; (void)out_size;

  char* base = (char*)d_ws;
  size_t off = 0;
  auto alloc = [&](size_t bytes)->char*{
    char* p = base+off; off = (off+bytes+255)&~(size_t)255; return p;
  };
  u16* ybuf = (u16*)alloc((size_t)CC*NTOT*2);     // 25.7 MB  y / h1rc-lo / wgrad part
  u16* dY   = (u16*)alloc((size_t)CC*NTOT*2);     // 25.7 MB  dY / h1rc-hi
  u16* Ab   = (u16*)alloc((size_t)HIDD*NTOT*2);   // 51.4 MB  a (AST) -> dhn / fallback a
  u16* t1b  = (u16*)alloc((size_t)C4*NTOT*2);     // 6.4 MB   t1
  u16* hb   = (u16*)alloc((size_t)C4*NTOT*2);     // 6.4 MB   h / dT1
  u16* h1rc = ybuf;                               // recompute overlay (fallback path)
  float* part = (float*)ybuf;                     // SKW*131072*4 = 16.8MB <= ybuf
  float* mfb  = (float*)alloc((size_t)2*NTOT*4);
  float* pw1  = (float*)alloc(131072*4);
  float* pw2  = (float*)alloc(131072*4);
  float* dW1  = (float*)alloc(131072*4);
  float* dW2  = (float*)alloc(131072*4);
  u16* wb1   = (u16*)alloc(131072*2);
  u16* wb2   = (u16*)alloc(131072*2);
  u16* wb2T  = (u16*)alloc(131072*2);
  u16* rwb1  = (u16*)alloc(16384*2);
  u16* rwb1T = (u16*)alloc(16384*2);
  u16* rwb2  = (u16*)alloc(16384*2);
  u16* rwb2T = (u16*)alloc(16384*2);
  float* pg   = (float*)alloc(512*4);   // pg+pb contiguous (GNB1 e2 / XGN-QGN pg)
  float* pb   = (float*)alloc(512*4);
  float* rw1f = (float*)alloc(16384*4);
  float* rw2f = (float*)alloc(16384*4);
  float* gw1f = (float*)alloc(16384*4);
  float* gb1f = (float*)alloc(64*4);
  float* gw2f = (float*)alloc(64*4);
  float* gb2f = (float*)alloc(256);
  float* rmf  = (float*)alloc(256*4);
  float* rvf  = (float*)alloc(256*4);
  float* rsf  = (float*)alloc(256);
  float* gsum   = (float*)alloc(512);   // gsum+gsumsq contiguous (EP_H1STAT o3)
  float* gsumsq = (float*)alloc(512);
  float* mu     = (float*)alloc(512);   // mu+rsig contiguous (GNB1 e1 / XGN-QGN mu)
  float* rsig   = (float*)alloc(512);
  float* cmsum  = (float*)alloc(1024);  // cmsum+cmsq contiguous (EP_YADDSTAT o3)
  float* cmsq   = (float*)alloc(1024);
  float* coefA  = (float*)alloc(1024);
  float* coefB  = (float*)alloc(1024);
  float* dGa    = (float*)alloc(2048);  // dGa+dBe+s1+s2 contiguous (GNB1 o3, wgrad red)
  float* dBe    = (float*)alloc(2048);
  float* s1     = (float*)alloc(512);
  float* s2     = (float*)alloc(512);
  float* pooled = (float*)alloc(16384);
  float* gate   = (float*)alloc(256);
  float* zc     = (float*)alloc(256);
  int*   dtf    = (int*)alloc(256);
  int*   mkf    = (int*)alloc(256);

  if (off > ws_size){
    k_report<<<1,64,0,stream>>>((u16*)d_out, (float)(ws_size>>20));
    return;
  }
  // adaptive: dedicated h1 buffer if ws allows (skips recompute GEMMs and
  // enables fused GNB1/GNB2/XGN/AST paths). ws_size constant -> graph-safe.
  u16* h1p = nullptr;
  if (off + (size_t)HIDD*NTOT*2 <= ws_size)
    h1p = (u16*)alloc((size_t)HIDD*NTOT*2);       // +51.4 MB

  // ---- probes + param conversion ----
  k_detect_dtype<<<1,1,0,stream>>>((const u16*)x_in, dtf);
  k_detect_mask<<<1,1,0,stream>>>((const unsigned char*)mk_in, mkf);
  #define CVT(src,dst,n) k_cvt<<<((n)+255)/256,256,0,stream>>>(src,dst,(n),dtf)
  CVT(w1_in,  pw1,  131072);
  CVT(g_in,   pg,   512);
  CVT(b_in,   pb,   512);
  CVT(w2_in,  pw2,  131072);
  CVT(rw1_in, rw1f, 16384);
  CVT(rw2_in, rw2f, 16384);
  CVT(gw1_in, gw1f, 16384);
  CVT(gb1_in, gb1f, 64);
  CVT(gw2_in, gw2f, 64);
  CVT(gb2_in, gb2f, 1);
  CVT(rs_in,  rsf,  1);
  CVT(rm_in,  rmf,  256);
  CVT(rv_in,  rvf,  256);
  #undef CVT
  k_wcvt<<<512,256,0,stream>>>(pw1, wb1, 0,     HIDD, CC);
  k_wcvt<<<512,256,0,stream>>>(pw2, wb2, wb2T,  CC, HIDD);
  k_wcvt<<<64,256,0,stream>>>(rw1f, rwb1, rwb1T, C4, CC);
  k_wcvt<<<64,256,0,stream>>>(rw2f, rwb2, rwb2T, CC, C4);
  hipMemsetAsync(zc, 0, 8, stream);
  k_expand<<<392,256,0,stream>>>((const unsigned char*)mk_in, mkf, mfb, zc);

  // ---- 2 inner TTT steps ----
  for (int s=0; s<2; s++){
    const float* mfs = mfb + s*NTOT;
    u16* h1dst = h1p ? h1p : Ab;
    // h1 = w1 @ x  (+ fused GN stats)
    hipMemsetAsync(gsum, 0, 1024, stream);
    k_gemm_mfma<0,EP_H1STAT,1,0,2,0,0,4><<<dim3(1568),256,0,stream>>>(wb1, x_in, h1dst, CC, dtf, 0,0,0,0,0, gsum, 0,0);
    k_gn_finalize<<<1,128,0,stream>>>(gsum, gsumsq, mu, rsig);
    hipMemsetAsync(cmsum, 0, 2048, stream);
    if (h1p){
      // y = w2 @ gelu(gn(h1)) + x — gn+gelu fused into X staging; a stored to Ab
      k_gemm_mfma<0,EP_YADDSTAT,0,1,2,1,1,2><<<dim3(784),256,0,stream>>>(wb2, h1p, ybuf, HIDD, dtf, 0, x_in, 0,0, Ab, cmsum, mu, pg);
    } else {
      k_gelu_fwd<1><<<BB*HIDD,256,0,stream>>>(Ab, Ab, mu, rsig, pg, pb);   // Ab = a (in place)
      k_gemm_mfma<0,EP_YADDSTAT,0,1,2,0,0,2><<<dim3(784),256,0,stream>>>(wb2, Ab, ybuf, HIDD, dtf, 0, x_in, 0,0,0, cmsum, 0,0);
    }
    k_y_finalize<<<1,256,0,stream>>>(cmsum, cmsq, rmf, rvf, coefA, coefB);
    // t1 = rw1 @ (y*mf); h = gelu(t1)
    k_gemm_mfma<1,EP_T1H,0,0,1,0,0,1><<<dim3(392,1),256,0,stream>>>(rwb1, ybuf, t1b, CC, dtf, mfs, 0,0,0, hb, 0, 0,0);
    // dY := g_rec = 2*(rec - y)*inv/D
    k_gemm_mfma<0,EP_DYREC,0,0,2,0,0,2><<<dim3(784),256,0,stream>>>(rwb2, hb, dY, C4, dtf, mfs, ybuf, zc+s, 0,0, 0, 0,0);
    // dT1 = (rw2^T @ g_rec) * gelu'(t1)
    k_gemm_mfma<0,EP_DT1,0,0,1,0,0,1><<<dim3(392,1),256,0,stream>>>(rwb2T, dY, hb, CC, dtf, 0, t1b, 0,0,0, 0, 0,0);
    // dY := mf*(rw1^T @ dT1) - g_rec + coefA + coefB*y
    k_gemm_mfma<0,EP_DYFIN,0,0,2,0,0,2><<<dim3(784),256,0,stream>>>(rwb1T, hb, dY, C4, dtf, mfs, ybuf, coefA, coefB, 0, 0, 0,0);
    // dW2[c,o] = sum_n dY[c,n]*a[o,n]   (a materialized in Ab; part overlays ybuf)
    k_wgrad_mfma<0,0,0><<<dim3(32*SKW),256,0,stream>>>(dY, Ab, part, CC, HIDD, dtf, 4, 0,0,0,0);
    k_wgrad_reduce<<<512,256,0,stream>>>(part, dW2, 131072);
    // dA = w2^T @ dY  (+ fused gn_bwd1 when h1 is resident)
    hipMemsetAsync(dGa, 0, 5120, stream);
    if (h1p){
      k_gemm_mfma<0,EP_GNB1,0,0,2,0,0,4><<<dim3(1568),256,0,stream>>>(wb2T, dY, Ab, CC, dtf, 0, h1p, mu, pg, 0, dGa, 0,0);
      // dW1[o,c] = sum_n dH1[o,n]*x[c,n] with gn_bwd2 applied during staging
      k_wgrad_mfma<1,1,0><<<dim3(32*SKW),256,0,stream>>>(Ab, x_in, part, HIDD, CC, dtf, 8, h1p, mu, dGa, 0);
    } else {
      k_gemm_mfma<0,EP_STORE,0,0,2,0,0,4><<<dim3(1568),256,0,stream>>>(wb2T, dY, Ab, CC, dtf, 0,0,0,0,0, 0, 0,0);
      k_gemm_mfma<0,EP_H1STAT,1,0,2,0,0,4><<<dim3(1568),256,0,stream>>>(wb1, x_in, h1rc, CC, dtf, 0,0,0,0,0, gsum, 0,0);
      k_gn_bwd1<<<BB*HIDD,256,0,stream>>>(Ab, h1rc, mu, rsig, pg, pb, dGa, dBe, s1, s2);
      k_gn_bwd2<<<BB*HIDD,256,0,stream>>>(Ab, h1rc, mu, rsig, s1, s2);
      k_wgrad_mfma<1,0,0><<<dim3(32*SKW),256,0,stream>>>(Ab, x_in, part, HIDD, CC, dtf, 8, 0,0,0,0);
    }
    k_wgrad_reduce<<<512,256,0,stream>>>(part, dW1, 131072);
    // SGD update + refresh bf16 weight copies
    k_update<<<512,256,0,stream>>>(pw1, pw2, pg, pb, dW1, dW2, dGa, dBe);
    k_wcvt<<<512,256,0,stream>>>(pw1, wb1, 0,    HIDD, CC);
    k_wcvt<<<512,256,0,stream>>>(pw2, wb2, wb2T, CC, HIDD);
  }

  // ---- gate (x-only; hoisted before final GEMM for EP_OUT) ----
  k_pool<<<BB*CC,256,0,stream>>>(x_in, dtf, pooled);
  k_gate<<<BB,64,0,stream>>>(pooled, gw1f, gb1f, gw2f, gb2f, gate);

  // ---- final modifier forward with updated params ----
  hipMemsetAsync(gsum, 0, 1024, stream);
  k_gemm_mfma<0,EP_H1STAT,1,0,2,0,0,4><<<dim3(1568),256,0,stream>>>(wb1, x_in, Ab, CC, dtf, 0,0,0,0,0, gsum, 0,0);
  k_gn_finalize<<<1,128,0,stream>>>(gsum, gsumsq, mu, rsig);
  // out = x + rsf*gate[b]*(w2 @ gelu(gn(h1)))  — gn+gelu fused into X staging,
  // residual merge fused into epilogue (no gelu pass, no k_out pass)
  k_gemm_mfma<0,EP_OUT,0,1,2,1,0,2><<<dim3(784),256,0,stream>>>(wb2, Ab, (u16*)d_out, HIDD, dtf, 0, x_in, gate, rsf, 0, 0, mu, pg);
}